// Round 1
// baseline (2999.169 us; speedup 1.0000x reference)
//
#include <hip/hip_runtime.h>

#define SEQ   8192
#define DIM   1280
#define HEADS 16
#define HD    80
#define NSEG  8
#define LSEG  1024
#define QKVD  3840
#define HDP   84   // padded HD for LDS tiles (keeps float4 alignment, spreads banks)

// ---------------------------------------------------------------------------
// Tiled fp32 GEMM: C[M,N] = A[M,K] @ B[K,N] + bias[N]
// BM=BN=64, BK=16, 256 threads, 4x4 microtile per thread.
// ---------------------------------------------------------------------------
__global__ __launch_bounds__(256) void gemm_bias_kernel(
    const float* __restrict__ A, const float* __restrict__ B,
    const float* __restrict__ bias, float* __restrict__ C,
    int M, int N, int K) {
  __shared__ float As[16][64];  // As[k][m]
  __shared__ float Bs[16][64];  // Bs[k][n]

  const int tid = threadIdx.x;
  const int tx = tid & 15;      // 0..15 -> col group
  const int ty = tid >> 4;      // 0..15 -> row group
  const int col0 = blockIdx.x * 64;
  const int row0 = blockIdx.y * 64;

  float acc[4][4];
#pragma unroll
  for (int i = 0; i < 4; ++i)
#pragma unroll
    for (int j = 0; j < 4; ++j) acc[i][j] = 0.f;

  // A-staging indices: thread loads A[row0 + tid/4][k0 + (tid%4)*4 .. +3]
  const int ar = tid >> 2;
  const int ak = (tid & 3) << 2;
  // B-staging: thread loads B[k0 + tid/16][col0 + (tid%16)*4 .. +3]
  const int bk = tid >> 4;
  const int bc = (tid & 15) << 2;

  for (int k0 = 0; k0 < K; k0 += 16) {
    float4 av = *reinterpret_cast<const float4*>(&A[(size_t)(row0 + ar) * K + k0 + ak]);
    float4 bv = *reinterpret_cast<const float4*>(&B[(size_t)(k0 + bk) * N + col0 + bc]);
    __syncthreads();  // protect previous iteration's reads
    As[ak + 0][ar] = av.x;
    As[ak + 1][ar] = av.y;
    As[ak + 2][ar] = av.z;
    As[ak + 3][ar] = av.w;
    *reinterpret_cast<float4*>(&Bs[bk][bc]) = bv;
    __syncthreads();
#pragma unroll
    for (int k = 0; k < 16; ++k) {
      float a[4], b[4];
      *reinterpret_cast<float4*>(a) = *reinterpret_cast<const float4*>(&As[k][ty << 2]);
      *reinterpret_cast<float4*>(b) = *reinterpret_cast<const float4*>(&Bs[k][tx << 2]);
#pragma unroll
      for (int i = 0; i < 4; ++i)
#pragma unroll
        for (int j = 0; j < 4; ++j) acc[i][j] += a[i] * b[j];
    }
  }

  float bb[4];
#pragma unroll
  for (int j = 0; j < 4; ++j) bb[j] = bias[col0 + (tx << 2) + j];

#pragma unroll
  for (int i = 0; i < 4; ++i) {
    float4 o;
    o.x = acc[i][0] + bb[0];
    o.y = acc[i][1] + bb[1];
    o.z = acc[i][2] + bb[2];
    o.w = acc[i][3] + bb[3];
    *reinterpret_cast<float4*>(&C[(size_t)(row0 + (ty << 2) + i) * N + col0 + (tx << 2)]) = o;
  }
}

// ---------------------------------------------------------------------------
// RoPE in-place on q,k halves of qkv. One thread per rotation pair (d, d+40).
// ---------------------------------------------------------------------------
__global__ __launch_bounds__(256) void rope_kernel(
    float* __restrict__ qkv, const float* __restrict__ cosb,
    const float* __restrict__ sinb) {
  int idx = blockIdx.x * 256 + threadIdx.x;  // SEQ*HEADS*2*40 threads exactly
  const int d = idx % 40;
  int t = idx / 40;
  const int h = t % HEADS;
  t /= HEADS;
  const int qk = t & 1;
  const int s = t >> 1;
  float* base = qkv + (size_t)s * QKVD + qk * DIM + h * HD;
  const float x1 = base[d];
  const float x2 = base[d + 40];
  const float c1 = cosb[s * HD + d];
  const float s1 = sinb[s * HD + d];
  const float c2 = cosb[s * HD + d + 40];
  const float s2 = sinb[s * HD + d + 40];
  base[d]      = x1 * c1 - x2 * s1;
  base[d + 40] = x2 * c2 + x1 * s2;
}

// ---------------------------------------------------------------------------
// Flash attention fp32. Block = (16-row q-tile, head). 256 threads = 4 waves.
// Each wave owns an interleaved quarter of the 1024 keys with an independent
// online softmax; merged at the end through LDS. K/V staged in LDS chunks of
// 64 rows (row stride HDP=84 -> conflict-free float4 reads).
// Lane l: r = l&15 (q row), dg = l>>4 (k-subgroup in score phase; 20-dim
// output slice in PV phase).
// ---------------------------------------------------------------------------
__global__ __launch_bounds__(256) void attn_kernel(
    const float* __restrict__ qkv, float* __restrict__ out) {
  const int qt = blockIdx.x;  // 0..511
  const int h = blockIdx.y;   // 0..15
  const int s0 = qt * 16;
  const int seg = s0 / LSEG;
  const int k0g = seg * LSEG;

  const int tid = threadIdx.x;
  const int w = tid >> 6;
  const int l = tid & 63;
  const int r = l & 15;
  const int dg = l >> 4;

  __shared__ float Qt[16][HDP];
  __shared__ float Kt[64][HDP];
  __shared__ float Vt[64][HDP];
  __shared__ float Mw[4][16];
  __shared__ float Lw[4][16];
  __shared__ float Ow[4][16][80];

  for (int idx = tid; idx < 16 * 80; idx += 256) {
    int rr = idx / 80, d = idx % 80;
    Qt[rr][d] = qkv[(size_t)(s0 + rr) * QKVD + h * HD + d];
  }

  float m_run = -1e30f, l_run = 0.f;
  float oacc[20];
#pragma unroll
  for (int i = 0; i < 20; ++i) oacc[i] = 0.f;

  const float scale = 0.11180339887498949f;  // 1/sqrt(80)

  for (int c = 0; c < LSEG / 64; ++c) {
    __syncthreads();  // previous Kt/Vt (and Qt on first iter) safe to overwrite
    for (int idx = tid; idx < 64 * 20; idx += 256) {
      int rr = idx / 20, d4 = (idx % 20) << 2;
      const size_t g = (size_t)(k0g + c * 64 + rr) * QKVD + DIM + h * HD + d4;
      *reinterpret_cast<float4*>(&Kt[rr][d4]) =
          *reinterpret_cast<const float4*>(&qkv[g]);
      *reinterpret_cast<float4*>(&Vt[rr][d4]) =
          *reinterpret_cast<const float4*>(&qkv[g + DIM]);
    }
    __syncthreads();

    // ---- scores: lane computes 4 keys: klocal = w*16 + dg*4 + j ----
    const int kl0 = w * 16 + (dg << 2);
    float sc[4] = {0.f, 0.f, 0.f, 0.f};
#pragma unroll
    for (int db = 0; db < 20; ++db) {
      float4 qv = *reinterpret_cast<const float4*>(&Qt[r][db << 2]);
#pragma unroll
      for (int j = 0; j < 4; ++j) {
        float4 kv = *reinterpret_cast<const float4*>(&Kt[kl0 + j][db << 2]);
        sc[j] += qv.x * kv.x + qv.y * kv.y + qv.z * kv.z + qv.w * kv.w;
      }
    }
#pragma unroll
    for (int j = 0; j < 4; ++j) sc[j] *= scale;

    // ---- online softmax over this wave's 16 keys (per q-row r) ----
    float cmax = fmaxf(fmaxf(sc[0], sc[1]), fmaxf(sc[2], sc[3]));
    cmax = fmaxf(cmax, __shfl_xor(cmax, 16));
    cmax = fmaxf(cmax, __shfl_xor(cmax, 32));
    const float m_new = fmaxf(m_run, cmax);
    const float fac = __expf(m_run - m_new);
    float psum = 0.f;
#pragma unroll
    for (int j = 0; j < 4; ++j) {
      sc[j] = __expf(sc[j] - m_new);
      psum += sc[j];
    }
    psum += __shfl_xor(psum, 16);
    psum += __shfl_xor(psum, 32);
    l_run = l_run * fac + psum;
    m_run = m_new;

#pragma unroll
    for (int i = 0; i < 20; ++i) oacc[i] *= fac;

    // ---- PV: lane (r,dg) accumulates dims dg*20..dg*20+19 over wave's 16 ks
#pragma unroll
    for (int k = 0; k < 16; ++k) {
      // p[r][k] lives in lane (r + 16*(k/4)), register sc[k%4]
      float p = __shfl(sc[k & 3], (l & 15) + ((k >> 2) << 4));
      const float* vrow = &Vt[w * 16 + k][dg * 20];
#pragma unroll
      for (int i4 = 0; i4 < 5; ++i4) {
        float4 vv = *reinterpret_cast<const float4*>(&vrow[i4 << 2]);
        oacc[i4 * 4 + 0] += p * vv.x;
        oacc[i4 * 4 + 1] += p * vv.y;
        oacc[i4 * 4 + 2] += p * vv.z;
        oacc[i4 * 4 + 3] += p * vv.w;
      }
    }
  }

  // ---- merge the 4 per-wave partial softmaxes ----
  if (dg == 0) {
    Mw[w][r] = m_run;
    Lw[w][r] = l_run;
  }
#pragma unroll
  for (int i4 = 0; i4 < 5; ++i4) {
    float4 o;
    o.x = oacc[i4 * 4 + 0];
    o.y = oacc[i4 * 4 + 1];
    o.z = oacc[i4 * 4 + 2];
    o.w = oacc[i4 * 4 + 3];
    *reinterpret_cast<float4*>(&Ow[w][r][dg * 20 + (i4 << 2)]) = o;
  }
  __syncthreads();

  for (int idx = tid; idx < 16 * 80; idx += 256) {
    const int rr = idx / 80, d = idx % 80;
    const float m0 = Mw[0][rr], m1 = Mw[1][rr], m2 = Mw[2][rr], m3 = Mw[3][rr];
    const float M = fmaxf(fmaxf(m0, m1), fmaxf(m2, m3));
    const float f0 = __expf(m0 - M), f1 = __expf(m1 - M);
    const float f2 = __expf(m2 - M), f3 = __expf(m3 - M);
    const float L = Lw[0][rr] * f0 + Lw[1][rr] * f1 + Lw[2][rr] * f2 + Lw[3][rr] * f3;
    const float o = Ow[0][rr][d] * f0 + Ow[1][rr][d] * f1 + Ow[2][rr][d] * f2 +
                    Ow[3][rr][d] * f3;
    out[(size_t)(s0 + rr) * DIM + h * HD + d] = o / L;
  }
}

// ---------------------------------------------------------------------------
// Launch. ws layout: qkv fp32 [8192][3840] at offset 0 (125.8 MB).
// attn output goes to d_out (scratch), proj result to ws offset 0 (qkv dead by
// then), then one d2d copy back to d_out.
// ---------------------------------------------------------------------------
extern "C" void kernel_launch(void* const* d_in, const int* in_sizes, int n_in,
                              void* d_out, int out_size, void* d_ws,
                              size_t ws_size, hipStream_t stream) {
  const float* hs = (const float*)d_in[0];
  const float* cosb = (const float*)d_in[1];
  const float* sinb = (const float*)d_in[2];
  const float* qkv_w = (const float*)d_in[3];
  const float* qkv_b = (const float*)d_in[4];
  const float* proj_w = (const float*)d_in[5];
  const float* proj_b = (const float*)d_in[6];
  float* out = (float*)d_out;
  float* qkv = (float*)d_ws;

  // 1) qkv = hs @ qkv_w + qkv_b
  gemm_bias_kernel<<<dim3(QKVD / 64, SEQ / 64), 256, 0, stream>>>(
      hs, qkv_w, qkv_b, qkv, SEQ, QKVD, DIM);
  // 2) RoPE in place on q,k
  rope_kernel<<<(SEQ * HEADS * 2 * 40) / 256, 256, 0, stream>>>(qkv, cosb, sinb);
  // 3) attention -> d_out (scratch)
  attn_kernel<<<dim3(SEQ / 16, HEADS), 256, 0, stream>>>(qkv, out);
  // 4) proj: ws[0..] = d_out @ proj_w + proj_b   (qkv region is dead now)
  gemm_bias_kernel<<<dim3(DIM / 64, SEQ / 64), 256, 0, stream>>>(
      out, proj_w, proj_b, qkv, SEQ, DIM, DIM);
  // 5) copy result back to d_out
  hipMemcpyAsync(d_out, qkv, (size_t)SEQ * DIM * sizeof(float),
                 hipMemcpyDeviceToDevice, stream);
}

// Round 2
// 533.812 us; speedup vs baseline: 5.6184x; 5.6184x over previous
//
#include <hip/hip_runtime.h>

#define SEQ   8192
#define DIM   1280
#define HEADS 16
#define HD    80
#define LSEG  1024
#define QKVD  3840

typedef unsigned short USHORT;
typedef __attribute__((ext_vector_type(8))) short bf16x8;
typedef __attribute__((ext_vector_type(4))) float f32x4;

__device__ __forceinline__ USHORT f2bf(float x) {
  unsigned u = __float_as_uint(x);
  u += 0x7fffu + ((u >> 16) & 1u);
  return (USHORT)(u >> 16);
}
__device__ __forceinline__ float bf2f(USHORT b) {
  return __uint_as_float(((unsigned)b) << 16);
}
__device__ __forceinline__ void gload16(const void* g, void* l) {
  __builtin_amdgcn_global_load_lds(
      (const __attribute__((address_space(1))) void*)g,
      (__attribute__((address_space(3))) void*)l, 16, 0, 0);
}

// ---------------------------------------------------------------------------
// f32 -> bf16 elementwise (4 per thread)
// ---------------------------------------------------------------------------
__global__ __launch_bounds__(256) void conv_f2b(const float* __restrict__ in,
                                                USHORT* __restrict__ out, int n4) {
  int i = blockIdx.x * 256 + threadIdx.x;
  if (i >= n4) return;
  float4 v = reinterpret_cast<const float4*>(in)[i];
  USHORT* o = out + (size_t)i * 4;
  o[0] = f2bf(v.x); o[1] = f2bf(v.y); o[2] = f2bf(v.z); o[3] = f2bf(v.w);
}

// ---------------------------------------------------------------------------
// f32 -> (hi,lo) bf16 split, elementwise
// ---------------------------------------------------------------------------
__global__ __launch_bounds__(256) void split_f2b(const float* __restrict__ in,
                                                 USHORT* __restrict__ hi,
                                                 USHORT* __restrict__ lo, int n4) {
  int i = blockIdx.x * 256 + threadIdx.x;
  if (i >= n4) return;
  float4 v = reinterpret_cast<const float4*>(in)[i];
  float x[4] = {v.x, v.y, v.z, v.w};
  USHORT* oh = hi + (size_t)i * 4;
  USHORT* ol = lo + (size_t)i * 4;
#pragma unroll
  for (int j = 0; j < 4; ++j) {
    USHORT hb = f2bf(x[j]);
    oh[j] = hb;
    ol[j] = f2bf(x[j] - bf2f(hb));
  }
}

// ---------------------------------------------------------------------------
// W[K][N] f32 -> Wt[N][K] bf16 (optionally hi/lo split). 32x32 LDS transpose.
// ---------------------------------------------------------------------------
template <int SPLIT>
__global__ __launch_bounds__(256) void conv_transpose(const float* __restrict__ W,
                                                      USHORT* __restrict__ Th,
                                                      USHORT* __restrict__ Tl,
                                                      int K, int N) {
  __shared__ float t[32][33];
  const int n0 = blockIdx.x * 32, k0 = blockIdx.y * 32;
  const int c = threadIdx.x & 31, r0 = threadIdx.x >> 5;
  for (int r = r0; r < 32; r += 8) t[r][c] = W[(size_t)(k0 + r) * N + n0 + c];
  __syncthreads();
  for (int r = r0; r < 32; r += 8) {
    const float v = t[c][r];  // = W[k0+c][n0+r]
    const USHORT hb = f2bf(v);
    Th[(size_t)(n0 + r) * K + k0 + c] = hb;
    if (SPLIT) Tl[(size_t)(n0 + r) * K + k0 + c] = f2bf(v - bf2f(hb));
  }
}

// ---------------------------------------------------------------------------
// MFMA GEMM: C[M,N] = A[M,K] @ Bt[N,K]^T + bias. A,Bt bf16 row-major.
// 128x128 tile, BK=32, 256 threads (4 waves, 64x64 quadrant each).
// SPLIT: A = Ah+Al, B = Bh+Bl, 3 MFMA per frag pair (drop Al*Bl).
// ---------------------------------------------------------------------------
template <int SPLIT, int OUTBF>
__global__ __launch_bounds__(256) void mfma_gemm(
    const USHORT* __restrict__ Ah, const USHORT* __restrict__ Al,
    const USHORT* __restrict__ Bh, const USHORT* __restrict__ Bl,
    const float* __restrict__ bias, void* __restrict__ Cout,
    int M, int N, int K) {
  extern __shared__ USHORT sm[];
  USHORT* AhL = sm;           // 4096 shorts (128 rows x 32 k)
  USHORT* BhL = sm + 4096;
  USHORT* AlL = sm + 8192;    // SPLIT only
  USHORT* BlL = sm + 12288;

  const int tid = threadIdx.x;
  const int l = tid & 63;
  const int w = tid >> 6;
  const int nrow = M >> 7;
  const int nwg = nrow * (N >> 7);
  const int orig = blockIdx.x;
  const int wg = (orig & 7) * (nwg >> 3) + (orig >> 3);  // XCD swizzle (nwg%8==0)
  const int row0 = (wg % nrow) << 7;
  const int col0 = (wg / nrow) << 7;
  const int wr = (w >> 1) << 6;
  const int wc = (w & 1) << 6;

  const f32x4 fz = {0.f, 0.f, 0.f, 0.f};
  f32x4 acc[4][4];
#pragma unroll
  for (int m = 0; m < 4; ++m)
#pragma unroll
    for (int n = 0; n < 4; ++n) acc[m][n] = fz;

  const int sr = l >> 2;         // staging: row within 16-row group
  const int sk = (l & 3) << 3;   // staging: k offset (shorts)
  const int fr = l & 15;         // frag row(A)/col(B)
  const int fk = (l >> 4) << 3;  // frag k offset (shorts)

  for (int k0 = 0; k0 < K; k0 += 32) {
    __syncthreads();
#pragma unroll
    for (int i2 = 0; i2 < 2; ++i2) {
      const int i = w * 2 + i2;
      const size_t ga = (size_t)(row0 + i * 16 + sr) * K + k0 + sk;
      const size_t gb = (size_t)(col0 + i * 16 + sr) * K + k0 + sk;
      gload16(Ah + ga, AhL + i * 512);
      gload16(Bh + gb, BhL + i * 512);
      if (SPLIT) {
        gload16(Al + ga, AlL + i * 512);
        gload16(Bl + gb, BlL + i * 512);
      }
    }
    __syncthreads();
    bf16x8 ah[4], bh[4], al[4], bl[4];
#pragma unroll
    for (int m = 0; m < 4; ++m) {
      ah[m] = *(const bf16x8*)&AhL[(wr + m * 16 + fr) * 32 + fk];
      bh[m] = *(const bf16x8*)&BhL[(wc + m * 16 + fr) * 32 + fk];
      if (SPLIT) {
        al[m] = *(const bf16x8*)&AlL[(wr + m * 16 + fr) * 32 + fk];
        bl[m] = *(const bf16x8*)&BlL[(wc + m * 16 + fr) * 32 + fk];
      }
    }
#pragma unroll
    for (int m = 0; m < 4; ++m)
#pragma unroll
      for (int n = 0; n < 4; ++n) {
        acc[m][n] = __builtin_amdgcn_mfma_f32_16x16x32_bf16(ah[m], bh[n], acc[m][n], 0, 0, 0);
        if (SPLIT) {
          acc[m][n] = __builtin_amdgcn_mfma_f32_16x16x32_bf16(ah[m], bl[n], acc[m][n], 0, 0, 0);
          acc[m][n] = __builtin_amdgcn_mfma_f32_16x16x32_bf16(al[m], bh[n], acc[m][n], 0, 0, 0);
        }
      }
  }

  float bv[4];
#pragma unroll
  for (int n = 0; n < 4; ++n) bv[n] = bias[col0 + wc + n * 16 + fr];
#pragma unroll
  for (int m = 0; m < 4; ++m)
#pragma unroll
    for (int n = 0; n < 4; ++n)
#pragma unroll
      for (int r = 0; r < 4; ++r) {
        const float v = acc[m][n][r] + bv[n];
        const int row = row0 + wr + m * 16 + (l >> 4) * 4 + r;
        const int col = col0 + wc + n * 16 + fr;
        if (OUTBF)
          ((USHORT*)Cout)[(size_t)row * N + col] = f2bf(v);
        else
          ((float*)Cout)[(size_t)row * N + col] = v;
      }
}

// ---------------------------------------------------------------------------
// RoPE in-place on bf16 qkv (q,k halves). Thread per rotation pair.
// ---------------------------------------------------------------------------
__global__ __launch_bounds__(256) void rope_b(USHORT* __restrict__ qkv,
                                              const float* __restrict__ cosb,
                                              const float* __restrict__ sinb) {
  int idx = blockIdx.x * 256 + threadIdx.x;  // SEQ*HEADS*2*40 total
  const int d = idx % 40;
  int t = idx / 40;
  const int h = t % HEADS;
  t /= HEADS;
  const int qk = t & 1;
  const int s = t >> 1;
  USHORT* base = qkv + (size_t)s * QKVD + qk * DIM + h * HD;
  const float x1 = bf2f(base[d]);
  const float x2 = bf2f(base[d + 40]);
  const float c1 = cosb[s * HD + d], s1 = sinb[s * HD + d];
  const float c2 = cosb[s * HD + d + 40], s2 = sinb[s * HD + d + 40];
  base[d] = f2bf(x1 * c1 - x2 * s1);
  base[d + 40] = f2bf(x2 * c2 + x1 * s2);
}

// ---------------------------------------------------------------------------
// Flash attention, bf16 MFMA. Block = (64 q-rows, head); 4 waves, each owns
// 16 q-rows over all 1024 keys of the segment (no cross-wave merge).
// K staged [64][104] (dims 80..95 zeroed; K-dim padded 80->96).
// V staged transposed [80][72]. P round-trips via per-wave LDS [16][72].
// ---------------------------------------------------------------------------
__global__ __launch_bounds__(256) void attn_mfma(const USHORT* __restrict__ qkv,
                                                 float* __restrict__ out) {
  const int qb = blockIdx.x;  // 0..127
  const int h = blockIdx.y;   // 0..15
  const int s0 = qb * 64;
  const int k0g = (s0 / LSEG) * LSEG;

  const int tid = threadIdx.x;
  const int w = tid >> 6;
  const int l = tid & 63;
  const int fr = l & 15;
  const int fk = (l >> 4) << 3;

  __shared__ USHORT Klds[64 * 104];
  __shared__ USHORT Vt[80 * 72];
  __shared__ USHORT Plds[4][16 * 72];

  const bf16x8 bz = {0, 0, 0, 0, 0, 0, 0, 0};
  const f32x4 fz = {0.f, 0.f, 0.f, 0.f};

  // Q fragments, hoisted (rows: wave's 16 q-rows; K-dim padded to 96)
  bf16x8 qa[3];
  const size_t qrow = (size_t)(s0 + w * 16 + fr) * QKVD + h * HD;
#pragma unroll
  for (int ks = 0; ks < 3; ++ks) {
    const int db = ks * 32 + fk;
    qa[ks] = (db < 80) ? *(const bf16x8*)&qkv[qrow + db] : bz;
  }

  f32x4 oacc[5];
#pragma unroll
  for (int nt = 0; nt < 5; ++nt) oacc[nt] = fz;
  float m_run[4], l_run[4];
#pragma unroll
  for (int j = 0; j < 4; ++j) { m_run[j] = -1e30f; l_run[j] = 0.f; }

  const float scale = 0.11180339887498949f;  // 1/sqrt(80)

  for (int kb = 0; kb < 16; ++kb) {
    const size_t kbase = (size_t)(k0g + kb * 64);
    __syncthreads();  // previous iteration's readers done
    // stage K rows (+zero pad dims 80..95)
    for (int idx = tid; idx < 64 * 12; idx += 256) {
      const int key = idx / 12, ch = idx % 12;
      bf16x8 v = bz;
      if (ch < 10)
        v = *(const bf16x8*)&qkv[(kbase + key) * QKVD + DIM + h * HD + ch * 8];
      *(bf16x8*)&Klds[key * 104 + ch * 8] = v;
    }
    // stage V transposed
    for (int idx = tid; idx < 64 * 10; idx += 256) {
      const int key = idx / 10, ch = idx % 10;
      const bf16x8 v =
          *(const bf16x8*)&qkv[(kbase + key) * QKVD + 2 * DIM + h * HD + ch * 8];
#pragma unroll
      for (int jj = 0; jj < 8; ++jj) Vt[(ch * 8 + jj) * 72 + key] = v[jj];
    }
    __syncthreads();

    // ---- QK^T: S[16 q][64 keys] ----
    f32x4 sc[4];
#pragma unroll
    for (int n = 0; n < 4; ++n) sc[n] = fz;
#pragma unroll
    for (int ks = 0; ks < 3; ++ks) {
#pragma unroll
      for (int n = 0; n < 4; ++n) {
        const bf16x8 kbf = *(const bf16x8*)&Klds[(n * 16 + fr) * 104 + ks * 32 + fk];
        sc[n] = __builtin_amdgcn_mfma_f32_16x16x32_bf16(qa[ks], kbf, sc[n], 0, 0, 0);
      }
    }

    // ---- online softmax per q-row (row j lives in 16-lane group) ----
#pragma unroll
    for (int j = 0; j < 4; ++j) {
      float v0 = sc[0][j] * scale, v1 = sc[1][j] * scale;
      float v2 = sc[2][j] * scale, v3 = sc[3][j] * scale;
      float mx = fmaxf(fmaxf(v0, v1), fmaxf(v2, v3));
      mx = fmaxf(mx, __shfl_xor(mx, 1));
      mx = fmaxf(mx, __shfl_xor(mx, 2));
      mx = fmaxf(mx, __shfl_xor(mx, 4));
      mx = fmaxf(mx, __shfl_xor(mx, 8));
      const float mn = fmaxf(m_run[j], mx);
      const float fac = __expf(m_run[j] - mn);
      const float p0 = __expf(v0 - mn), p1 = __expf(v1 - mn);
      const float p2 = __expf(v2 - mn), p3 = __expf(v3 - mn);
      float ps = p0 + p1 + p2 + p3;
      ps += __shfl_xor(ps, 1);
      ps += __shfl_xor(ps, 2);
      ps += __shfl_xor(ps, 4);
      ps += __shfl_xor(ps, 8);
      l_run[j] = l_run[j] * fac + ps;
      m_run[j] = mn;
      sc[0][j] = p0; sc[1][j] = p1; sc[2][j] = p2; sc[3][j] = p3;
#pragma unroll
      for (int nt = 0; nt < 5; ++nt) oacc[nt][j] *= fac;
    }

    // ---- P -> per-wave LDS (C/D layout -> A layout transpose) ----
#pragma unroll
    for (int n = 0; n < 4; ++n)
#pragma unroll
      for (int j = 0; j < 4; ++j)
        Plds[w][((l >> 4) * 4 + j) * 72 + n * 16 + fr] = f2bf(sc[n][j]);

    // ---- PV: O += P[16][64] @ V[64][80] ----
#pragma unroll
    for (int ks = 0; ks < 2; ++ks) {
      const bf16x8 pa = *(const bf16x8*)&Plds[w][fr * 72 + ks * 32 + fk];
#pragma unroll
      for (int nt = 0; nt < 5; ++nt) {
        const bf16x8 vb = *(const bf16x8*)&Vt[(nt * 16 + fr) * 72 + ks * 32 + fk];
        oacc[nt] = __builtin_amdgcn_mfma_f32_16x16x32_bf16(pa, vb, oacc[nt], 0, 0, 0);
      }
    }
  }

  // ---- epilogue: normalize and store fp32 ----
#pragma unroll
  for (int nt = 0; nt < 5; ++nt)
#pragma unroll
    for (int j = 0; j < 4; ++j) {
      const int row = s0 + w * 16 + (l >> 4) * 4 + j;
      const int col = h * HD + nt * 16 + fr;
      out[(size_t)row * DIM + col] = oacc[nt][j] / l_run[j];
    }
}

// ---------------------------------------------------------------------------
// ws layout (bytes):
//   [0, 62914560)            qkv bf16 [8192][3840]   (later reused: attn hi/lo)
//   [62914560, 83886080)     hs bf16  [8192][1280]
//   [83886080, 93716480)     qkv_w^T bf16 [3840][1280]
//   [93716480, 96993280)     proj_w^T hi  [1280][1280]
//   [96993280, 100270080)    proj_w^T lo  [1280][1280]
// attn output (f32) uses d_out as scratch; final GEMM writes d_out.
// ---------------------------------------------------------------------------
extern "C" void kernel_launch(void* const* d_in, const int* in_sizes, int n_in,
                              void* d_out, int out_size, void* d_ws,
                              size_t ws_size, hipStream_t stream) {
  const float* hs = (const float*)d_in[0];
  const float* cosb = (const float*)d_in[1];
  const float* sinb = (const float*)d_in[2];
  const float* qkv_w = (const float*)d_in[3];
  const float* qkv_b = (const float*)d_in[4];
  const float* proj_w = (const float*)d_in[5];
  const float* proj_b = (const float*)d_in[6];
  char* ws = (char*)d_ws;

  USHORT* qkvB  = (USHORT*)(ws);
  USHORT* hsB   = (USHORT*)(ws + 62914560u);
  USHORT* qkvwT = (USHORT*)(ws + 83886080u);
  USHORT* pwTh  = (USHORT*)(ws + 93716480u);
  USHORT* pwTl  = (USHORT*)(ws + 96993280u);
  USHORT* aoH   = (USHORT*)(ws);              // after attn, qkvB is dead
  USHORT* aoL   = (USHORT*)(ws + 20971520u);

  // input conversions
  conv_f2b<<<SEQ * DIM / 4 / 256, 256, 0, stream>>>(hs, hsB, SEQ * DIM / 4);
  conv_transpose<0><<<dim3(QKVD / 32, DIM / 32), 256, 0, stream>>>(
      qkv_w, qkvwT, nullptr, DIM, QKVD);
  conv_transpose<1><<<dim3(DIM / 32, DIM / 32), 256, 0, stream>>>(
      proj_w, pwTh, pwTl, DIM, DIM);

  // 1) qkv = hs @ qkv_w + b  (plain bf16, bf16 out)
  mfma_gemm<0, 1><<<(SEQ / 128) * (QKVD / 128), 256, 16384, stream>>>(
      hsB, nullptr, qkvwT, nullptr, qkv_b, qkvB, SEQ, QKVD, DIM);
  // 2) RoPE in place
  rope_b<<<SEQ * HEADS * 2 * 40 / 256, 256, 0, stream>>>(qkvB, cosb, sinb);
  // 3) attention -> d_out (f32 scratch)
  attn_mfma<<<dim3(SEQ / 64, HEADS), 256, 0, stream>>>(qkvB, (float*)d_out);
  // 4) split attn output into hi/lo bf16
  split_f2b<<<SEQ * DIM / 4 / 256, 256, 0, stream>>>((const float*)d_out, aoH,
                                                     aoL, SEQ * DIM / 4);
  // 5) out = attn @ proj_w + b  (split bf16, f32 out) -> d_out
  mfma_gemm<1, 0><<<(SEQ / 128) * (DIM / 128), 256, 32768, stream>>>(
      aoH, aoL, pwTh, pwTl, proj_b, d_out, SEQ, DIM, DIM);
}

// Round 5
// 427.872 us; speedup vs baseline: 7.0095x; 1.2476x over previous
//
#include <hip/hip_runtime.h>

#define SEQ   8192
#define DIM   1280
#define HEADS 16
#define HD    80
#define LSEG  1024
#define QKVD  3840

typedef unsigned short USHORT;
typedef __attribute__((ext_vector_type(8))) short bf16x8;
typedef __attribute__((ext_vector_type(4))) float f32x4;
typedef __attribute__((ext_vector_type(4))) USHORT u16x4;

#define CSF  0.16129832f    // (1/sqrt(80)) * log2(e)
#define DTHR 71.554175f     // 8 / (1/sqrt(80)) : defer-max threshold in raw units

__device__ __forceinline__ USHORT f2bf(float x) {
  unsigned u = __float_as_uint(x);
  u += 0x7fffu + ((u >> 16) & 1u);
  return (USHORT)(u >> 16);
}
__device__ __forceinline__ float bf2f(USHORT b) {
  return __uint_as_float(((unsigned)b) << 16);
}
__device__ __forceinline__ void gload16(const void* g, void* l) {
  __builtin_amdgcn_global_load_lds(
      (const __attribute__((address_space(1))) void*)g,
      (__attribute__((address_space(3))) void*)l, 16, 0, 0);
}

// ---------------------------------------------------------------------------
// f32 -> bf16 elementwise (4 per thread)
// ---------------------------------------------------------------------------
__global__ __launch_bounds__(256) void conv_f2b(const float* __restrict__ in,
                                                USHORT* __restrict__ out, int n4) {
  int i = blockIdx.x * 256 + threadIdx.x;
  if (i >= n4) return;
  float4 v = reinterpret_cast<const float4*>(in)[i];
  USHORT* o = out + (size_t)i * 4;
  o[0] = f2bf(v.x); o[1] = f2bf(v.y); o[2] = f2bf(v.z); o[3] = f2bf(v.w);
}

// ---------------------------------------------------------------------------
// f32 -> (hi,lo) bf16 split, elementwise
// ---------------------------------------------------------------------------
__global__ __launch_bounds__(256) void split_f2b(const float* __restrict__ in,
                                                 USHORT* __restrict__ hi,
                                                 USHORT* __restrict__ lo, int n4) {
  int i = blockIdx.x * 256 + threadIdx.x;
  if (i >= n4) return;
  float4 v = reinterpret_cast<const float4*>(in)[i];
  float x[4] = {v.x, v.y, v.z, v.w};
  USHORT* oh = hi + (size_t)i * 4;
  USHORT* ol = lo + (size_t)i * 4;
#pragma unroll
  for (int j = 0; j < 4; ++j) {
    USHORT hb = f2bf(x[j]);
    oh[j] = hb;
    ol[j] = f2bf(x[j] - bf2f(hb));
  }
}

// ---------------------------------------------------------------------------
// W[K][N] f32 -> Wt[N][K] bf16 (optionally hi/lo split). 32x32 LDS transpose.
// ---------------------------------------------------------------------------
template <int SPLIT>
__global__ __launch_bounds__(256) void conv_transpose(const float* __restrict__ W,
                                                      USHORT* __restrict__ Th,
                                                      USHORT* __restrict__ Tl,
                                                      int K, int N) {
  __shared__ float t[32][33];
  const int n0 = blockIdx.x * 32, k0 = blockIdx.y * 32;
  const int c = threadIdx.x & 31, r0 = threadIdx.x >> 5;
  for (int r = r0; r < 32; r += 8) t[r][c] = W[(size_t)(k0 + r) * N + n0 + c];
  __syncthreads();
  for (int r = r0; r < 32; r += 8) {
    const float v = t[c][r];  // = W[k0+c][n0+r]
    const USHORT hb = f2bf(v);
    Th[(size_t)(n0 + r) * K + k0 + c] = hb;
    if (SPLIT) Tl[(size_t)(n0 + r) * K + k0 + c] = f2bf(v - bf2f(hb));
  }
}

// ---------------------------------------------------------------------------
// bf16 V-transpose: VtG[c][s] = qkv[s][2*DIM + c]  (c = h*80+d, 0..1279).
// 32x32 LDS tiles, coalesced both sides.
// ---------------------------------------------------------------------------
__global__ __launch_bounds__(256) void vtrans(const USHORT* __restrict__ qkv,
                                              USHORT* __restrict__ VtG) {
  __shared__ USHORT t[32][33];
  const int c0 = blockIdx.x * 32, s0 = blockIdx.y * 32;
  const int c = threadIdx.x & 31, r0 = threadIdx.x >> 5;
  for (int r = r0; r < 32; r += 8)
    t[r][c] = qkv[(size_t)(s0 + r) * QKVD + 2 * DIM + c0 + c];
  __syncthreads();
  for (int r = r0; r < 32; r += 8)
    VtG[(size_t)(c0 + r) * SEQ + s0 + c] = t[c][r];
}

// ---------------------------------------------------------------------------
// MFMA GEMM: C[M,N] = A[M,K] @ Bt[N,K]^T + bias. 128x128 tile, BK=32.
// ---------------------------------------------------------------------------
template <int SPLIT, int OUTBF>
__global__ __launch_bounds__(256) void mfma_gemm(
    const USHORT* __restrict__ Ah, const USHORT* __restrict__ Al,
    const USHORT* __restrict__ Bh, const USHORT* __restrict__ Bl,
    const float* __restrict__ bias, void* __restrict__ Cout,
    int M, int N, int K) {
  extern __shared__ USHORT sm[];
  USHORT* AhL = sm;           // 4096 shorts (128 rows x 32 k)
  USHORT* BhL = sm + 4096;
  USHORT* AlL = sm + 8192;    // SPLIT only
  USHORT* BlL = sm + 12288;

  const int tid = threadIdx.x;
  const int l = tid & 63;
  const int w = tid >> 6;
  const int nrow = M >> 7;
  const int nwg = nrow * (N >> 7);
  const int orig = blockIdx.x;
  const int wg = (orig & 7) * (nwg >> 3) + (orig >> 3);  // XCD swizzle (nwg%8==0)
  const int row0 = (wg % nrow) << 7;
  const int col0 = (wg / nrow) << 7;
  const int wr = (w >> 1) << 6;
  const int wc = (w & 1) << 6;

  const f32x4 fz = {0.f, 0.f, 0.f, 0.f};
  f32x4 acc[4][4];
#pragma unroll
  for (int m = 0; m < 4; ++m)
#pragma unroll
    for (int n = 0; n < 4; ++n) acc[m][n] = fz;

  const int sr = l >> 2;         // staging: row within 16-row group
  const int sk = (l & 3) << 3;   // staging: k offset (shorts)
  const int fr = l & 15;         // frag row(A)/col(B)
  const int fk = (l >> 4) << 3;  // frag k offset (shorts)

  for (int k0 = 0; k0 < K; k0 += 32) {
    __syncthreads();
#pragma unroll
    for (int i2 = 0; i2 < 2; ++i2) {
      const int i = w * 2 + i2;
      const size_t ga = (size_t)(row0 + i * 16 + sr) * K + k0 + sk;
      const size_t gb = (size_t)(col0 + i * 16 + sr) * K + k0 + sk;
      gload16(Ah + ga, AhL + i * 512);
      gload16(Bh + gb, BhL + i * 512);
      if (SPLIT) {
        gload16(Al + ga, AlL + i * 512);
        gload16(Bl + gb, BlL + i * 512);
      }
    }
    __syncthreads();
    bf16x8 ah[4], bh[4], al[4], bl[4];
#pragma unroll
    for (int m = 0; m < 4; ++m) {
      ah[m] = *(const bf16x8*)&AhL[(wr + m * 16 + fr) * 32 + fk];
      bh[m] = *(const bf16x8*)&BhL[(wc + m * 16 + fr) * 32 + fk];
      if (SPLIT) {
        al[m] = *(const bf16x8*)&AlL[(wr + m * 16 + fr) * 32 + fk];
        bl[m] = *(const bf16x8*)&BlL[(wc + m * 16 + fr) * 32 + fk];
      }
    }
#pragma unroll
    for (int m = 0; m < 4; ++m)
#pragma unroll
      for (int n = 0; n < 4; ++n) {
        acc[m][n] = __builtin_amdgcn_mfma_f32_16x16x32_bf16(ah[m], bh[n], acc[m][n], 0, 0, 0);
        if (SPLIT) {
          acc[m][n] = __builtin_amdgcn_mfma_f32_16x16x32_bf16(ah[m], bl[n], acc[m][n], 0, 0, 0);
          acc[m][n] = __builtin_amdgcn_mfma_f32_16x16x32_bf16(al[m], bh[n], acc[m][n], 0, 0, 0);
        }
      }
  }

  float bv[4];
#pragma unroll
  for (int n = 0; n < 4; ++n) bv[n] = bias[col0 + wc + n * 16 + fr];
#pragma unroll
  for (int m = 0; m < 4; ++m)
#pragma unroll
    for (int n = 0; n < 4; ++n)
#pragma unroll
      for (int r = 0; r < 4; ++r) {
        const float v = acc[m][n][r] + bv[n];
        const int row = row0 + wr + m * 16 + (l >> 4) * 4 + r;
        const int col = col0 + wc + n * 16 + fr;
        if (OUTBF)
          ((USHORT*)Cout)[(size_t)row * N + col] = f2bf(v);
        else
          ((float*)Cout)[(size_t)row * N + col] = v;
      }
}

// ---------------------------------------------------------------------------
// RoPE in-place on bf16 qkv (q,k halves). Thread per rotation pair.
// ---------------------------------------------------------------------------
__global__ __launch_bounds__(256) void rope_b(USHORT* __restrict__ qkv,
                                              const float* __restrict__ cosb,
                                              const float* __restrict__ sinb) {
  int idx = blockIdx.x * 256 + threadIdx.x;  // SEQ*HEADS*2*40 total
  const int d = idx % 40;
  int t = idx / 40;
  const int h = t % HEADS;
  t /= HEADS;
  const int qk = t & 1;
  const int s = t >> 1;
  USHORT* base = qkv + (size_t)s * QKVD + qk * DIM + h * HD;
  const float x1 = bf2f(base[d]);
  const float x2 = bf2f(base[d + 40]);
  const float c1 = cosb[s * HD + d], s1 = sinb[s * HD + d];
  const float c2 = cosb[s * HD + d + 40], s2 = sinb[s * HD + d + 40];
  base[d] = f2bf(x1 * c1 - x2 * s1);
  base[d + 40] = f2bf(x2 * c2 + x1 * s2);
}

// ---------------------------------------------------------------------------
// 1KB zero region for global_load_lds pad sources.
// ---------------------------------------------------------------------------
__global__ void zero_ws(uint4* z) {
  z[threadIdx.x] = uint4{0u, 0u, 0u, 0u};
}

// ---------------------------------------------------------------------------
// Flash attention v5: swapped QK^T (S^T = K@Q^T), lane-local softmax with
// defer-max, P via wave-private LDS (ordered keys), V^T staged from the
// pre-transposed global VtG via global_load_lds (NO tr16), K via swizzled
// global_load_lds. Block = (128 q-rows, head); 4 waves x 32 q-rows.
//
// K LDS:  [64 rows][16 slots of 16B], slot c2 holds K dims (c2^(row&7))*8;
//         dims 80..95 zero (zbuf) -> K-dim padded to 96.
// Vt LDS: [80 d-rows][72 keys-padded]; row d holds V^T[d][keys 0..63];
//         stride 72 shorts -> conflict-free b128 B-frag reads.
// P LDS:  per-wave [32 q][72 keys-padded]; write b64 (4 keys), read b128.
// ---------------------------------------------------------------------------
__global__ __launch_bounds__(256) void attn_mfma4(const USHORT* __restrict__ qkv,
                                                  const USHORT* __restrict__ VtG,
                                                  const USHORT* __restrict__ zbuf,
                                                  float* __restrict__ out) {
  const int h = blockIdx.y;
  const int s0 = blockIdx.x * 128;
  const int k0g = (s0 / LSEG) * LSEG;
  const int tid = threadIdx.x;
  const int w = tid >> 6, l = tid & 63;
  const int g = l >> 4, fr = l & 15;
  const int q0 = s0 + w * 32;

  __shared__ __align__(16) USHORT Kl[64 * 128];
  __shared__ __align__(16) USHORT Vl[6144];      // 80 rows x 72 + staging tail
  __shared__ __align__(16) USHORT Pl[4][32 * 72];

  // Q B-frags, hoisted. Tail dims 80..95 read in-row garbage (finite) --
  // multiplied by K's zeroed pad, contribute 0.
  bf16x8 qb[2][3];
#pragma unroll
  for (int nt2 = 0; nt2 < 2; ++nt2)
#pragma unroll
    for (int ks = 0; ks < 3; ++ks)
      qb[nt2][ks] = *(const bf16x8*)&qkv[(size_t)(q0 + nt2 * 16 + fr) * QKVD +
                                         h * HD + ks * 32 + g * 8];

  const f32x4 fz = {0.f, 0.f, 0.f, 0.f};
  f32x4 oacc[2][5];
#pragma unroll
  for (int m = 0; m < 2; ++m)
#pragma unroll
    for (int n = 0; n < 5; ++n) oacc[m][n] = fz;
  float m_run[2] = {-3e38f, -3e38f};
  float l_run[2] = {0.f, 0.f};

  for (int kb = 0; kb < 16; ++kb) {
    const size_t krow0 = (size_t)(k0g + kb * 64);
    __syncthreads();  // previous iteration's readers done

    // ---- stage K: 16 gload16 calls (4/wave), swizzled source ----
#pragma unroll
    for (int i = 0; i < 4; ++i) {
      const int t = (w * 4 + i) * 64 + l;
      const int row = t >> 4, c2 = t & 15, c = c2 ^ (row & 7);
      const USHORT* src =
          (c < 10) ? &qkv[(krow0 + row) * QKVD + DIM + h * HD + c * 8] : zbuf;
      gload16(src, &Kl[(w * 4 + i) * 512]);
    }
    // ---- stage V^T: 12 gload16 calls (3/wave) from VtG ----
#pragma unroll
    for (int i = 0; i < 3; ++i) {
      const int u = (w * 3 + i) * 64 + l;
      const int s = u / 9, r8 = u - s * 9;   // d-row s, 16B chunk r8 (8=pad)
      const USHORT* src = (r8 < 8 && s < 80)
          ? &VtG[(size_t)(h * HD + s) * SEQ + krow0 + r8 * 8] : zbuf;
      gload16(src, &Vl[(w * 3 + i) * 512]);
    }
    __syncthreads();

    // ---- QK^T: S^T[64 keys][32 q]; lane holds keys {16m+4g+j}, q=16nt2+fr --
    f32x4 sc[4][2];
#pragma unroll
    for (int m = 0; m < 4; ++m)
#pragma unroll
      for (int nt2 = 0; nt2 < 2; ++nt2) sc[m][nt2] = fz;
#pragma unroll
    for (int ks = 0; ks < 3; ++ks)
#pragma unroll
      for (int m = 0; m < 4; ++m) {
        const bf16x8 kbf = *(const bf16x8*)
            &Kl[(m * 16 + fr) * 128 + ((4 * ks + g) ^ (fr & 7)) * 8];
#pragma unroll
        for (int nt2 = 0; nt2 < 2; ++nt2)
          sc[m][nt2] = __builtin_amdgcn_mfma_f32_16x16x32_bf16(
              kbf, qb[nt2][ks], sc[m][nt2], 0, 0, 0);
      }

    // ---- lane-local online softmax with defer-max ----
    float rmax[2];
#pragma unroll
    for (int nt2 = 0; nt2 < 2; ++nt2) {
      float mx = -3e38f;
#pragma unroll
      for (int m = 0; m < 4; ++m)
#pragma unroll
        for (int j = 0; j < 4; ++j) mx = fmaxf(mx, sc[m][nt2][j]);
      mx = fmaxf(mx, __shfl_xor(mx, 16));
      mx = fmaxf(mx, __shfl_xor(mx, 32));
      rmax[nt2] = mx;
    }
    const bool need =
        (rmax[0] > m_run[0] + DTHR) || (rmax[1] > m_run[1] + DTHR);
    if (__any(need)) {
      float fac[2];
#pragma unroll
      for (int nt2 = 0; nt2 < 2; ++nt2) {
        const float mn = fmaxf(m_run[nt2], rmax[nt2]);
        fac[nt2] = exp2f((m_run[nt2] - mn) * CSF);
        m_run[nt2] = mn;
        l_run[nt2] *= fac[nt2];
      }
#pragma unroll
      for (int mt2 = 0; mt2 < 2; ++mt2)
#pragma unroll
        for (int j = 0; j < 4; ++j) {
          const float fb = __shfl(fac[mt2], 20 * g + j);
#pragma unroll
          for (int nt = 0; nt < 5; ++nt) oacc[mt2][nt][j] *= fb;
        }
    }
#pragma unroll
    for (int nt2 = 0; nt2 < 2; ++nt2) {
      const float mcs = m_run[nt2] * CSF;
      float ps = 0.f;
#pragma unroll
      for (int m = 0; m < 4; ++m) {
        u16x4 w4;
#pragma unroll
        for (int j = 0; j < 4; ++j) {
          const float p = exp2f(sc[m][nt2][j] * CSF - mcs);
          ps += p;
          w4[j] = f2bf(p);
        }
        // P[q = nt2*16+fr][keys 16m+4g .. +3]
        *(u16x4*)&Pl[w][(nt2 * 16 + fr) * 72 + m * 16 + g * 4] = w4;
      }
      ps += __shfl_xor(ps, 16);
      ps += __shfl_xor(ps, 32);
      l_run[nt2] += ps;
    }

    // ---- PV: O[32q][80d] += P @ V (ordered keys; V^T rows are d) ----
#pragma unroll
    for (int ks = 0; ks < 2; ++ks) {
      bf16x8 pa[2];
#pragma unroll
      for (int mt2 = 0; mt2 < 2; ++mt2)
        pa[mt2] = *(const bf16x8*)&Pl[w][(mt2 * 16 + fr) * 72 + ks * 32 + g * 8];
#pragma unroll
      for (int nt = 0; nt < 5; ++nt) {
        const bf16x8 vb =
            *(const bf16x8*)&Vl[(nt * 16 + fr) * 72 + ks * 32 + g * 8];
#pragma unroll
        for (int mt2 = 0; mt2 < 2; ++mt2)
          oacc[mt2][nt] = __builtin_amdgcn_mfma_f32_16x16x32_bf16(
              pa[mt2], vb, oacc[mt2][nt], 0, 0, 0);
      }
    }
  }

  // ---- epilogue: broadcast l_run to C-row layout, normalize, store f32 ----
  float linv[2][4];
#pragma unroll
  for (int mt2 = 0; mt2 < 2; ++mt2)
#pragma unroll
    for (int j = 0; j < 4; ++j)
      linv[mt2][j] = 1.f / __shfl(l_run[mt2], 20 * g + j);
#pragma unroll
  for (int mt2 = 0; mt2 < 2; ++mt2)
#pragma unroll
    for (int nt = 0; nt < 5; ++nt)
#pragma unroll
      for (int j = 0; j < 4; ++j) {
        const int row = s0 + w * 32 + mt2 * 16 + g * 4 + j;
        const int col = h * HD + nt * 16 + fr;
        out[(size_t)row * DIM + col] = oacc[mt2][nt][j] * linv[mt2][j];
      }
}

// ---------------------------------------------------------------------------
// ws layout (bytes):
//   [0, 62914560)            qkv bf16 [8192][3840]   (later reused: attn hi/lo)
//   [62914560, 83886080)     hs bf16 [8192][1280]; after GEMM1 reused as
//                            VtG bf16 [1280][8192] (V pre-transposed)
//   [83886080, 93716480)     qkv_w^T bf16 [3840][1280]; first 1KB re-zeroed
//                            after GEMM1 -> zbuf for attn pad sources
//   [93716480, 96993280)     proj_w^T hi  [1280][1280]
//   [96993280, 100270080)    proj_w^T lo  [1280][1280]
// ---------------------------------------------------------------------------
extern "C" void kernel_launch(void* const* d_in, const int* in_sizes, int n_in,
                              void* d_out, int out_size, void* d_ws,
                              size_t ws_size, hipStream_t stream) {
  const float* hs = (const float*)d_in[0];
  const float* cosb = (const float*)d_in[1];
  const float* sinb = (const float*)d_in[2];
  const float* qkv_w = (const float*)d_in[3];
  const float* qkv_b = (const float*)d_in[4];
  const float* proj_w = (const float*)d_in[5];
  const float* proj_b = (const float*)d_in[6];
  char* ws = (char*)d_ws;

  USHORT* qkvB  = (USHORT*)(ws);
  USHORT* hsB   = (USHORT*)(ws + 62914560u);
  USHORT* qkvwT = (USHORT*)(ws + 83886080u);
  USHORT* pwTh  = (USHORT*)(ws + 93716480u);
  USHORT* pwTl  = (USHORT*)(ws + 96993280u);
  USHORT* aoH   = (USHORT*)(ws);              // after attn, qkvB is dead
  USHORT* aoL   = (USHORT*)(ws + 20971520u);
  USHORT* VtG   = hsB;                        // hsB dead after GEMM1
  USHORT* zbuf  = qkvwT;                      // qkvwT dead after GEMM1

  // input conversions
  conv_f2b<<<SEQ * DIM / 4 / 256, 256, 0, stream>>>(hs, hsB, SEQ * DIM / 4);
  conv_transpose<0><<<dim3(QKVD / 32, DIM / 32), 256, 0, stream>>>(
      qkv_w, qkvwT, nullptr, DIM, QKVD);
  conv_transpose<1><<<dim3(DIM / 32, DIM / 32), 256, 0, stream>>>(
      proj_w, pwTh, pwTl, DIM, DIM);

  // 1) qkv = hs @ qkv_w + b  (plain bf16, bf16 out)
  mfma_gemm<0, 1><<<(SEQ / 128) * (QKVD / 128), 256, 16384, stream>>>(
      hsB, nullptr, qkvwT, nullptr, qkv_b, qkvB, SEQ, QKVD, DIM);
  // 2) RoPE in place (q,k only)
  rope_b<<<SEQ * HEADS * 2 * 40 / 256, 256, 0, stream>>>(qkvB, cosb, sinb);
  // 2.3) pre-transpose V: VtG[c][s]  (hsB region is dead now)
  vtrans<<<dim3(DIM / 32, SEQ / 32), 256, 0, stream>>>(qkvB, VtG);
  // 2.6) zero pad-source region (qkvwT dead after GEMM1)
  zero_ws<<<1, 64, 0, stream>>>((uint4*)zbuf);
  // 3) attention -> d_out (f32 scratch)
  attn_mfma4<<<dim3(SEQ / 128, HEADS), 256, 0, stream>>>(qkvB, VtG, zbuf,
                                                         (float*)d_out);
  // 4) split attn output into hi/lo bf16
  split_f2b<<<SEQ * DIM / 4 / 256, 256, 0, stream>>>((const float*)d_out, aoH,
                                                     aoL, SEQ * DIM / 4);
  // 5) out = attn @ proj_w + b  (split bf16, f32 out) -> d_out
  mfma_gemm<1, 0><<<(SEQ / 128) * (DIM / 128), 256, 32768, stream>>>(
      aoH, aoL, pwTh, pwTl, proj_b, d_out, SEQ, DIM, DIM);
}

// Round 6
// 344.850 us; speedup vs baseline: 8.6970x; 1.2407x over previous
//
#include <hip/hip_runtime.h>

#define SEQ   8192
#define DIM   1280
#define HEADS 16
#define HD    80
#define LSEG  1024
#define QKVD  3840

typedef unsigned short USHORT;
typedef __attribute__((ext_vector_type(8))) short bf16x8;
typedef __attribute__((ext_vector_type(4))) float f32x4;
typedef __attribute__((ext_vector_type(4))) USHORT u16x4;

#define CSF  0.16129832f    // (1/sqrt(80)) * log2(e)
#define DTHR 71.554175f     // 8 / (1/sqrt(80)) : defer-max threshold in raw units

__device__ __forceinline__ USHORT f2bf(float x) {
  unsigned u = __float_as_uint(x);
  u += 0x7fffu + ((u >> 16) & 1u);
  return (USHORT)(u >> 16);
}
__device__ __forceinline__ float bf2f(USHORT b) {
  return __uint_as_float(((unsigned)b) << 16);
}
__device__ __forceinline__ void gload16(const void* g, void* l) {
  __builtin_amdgcn_global_load_lds(
      (const __attribute__((address_space(1))) void*)g,
      (__attribute__((address_space(3))) void*)l, 16, 0, 0);
}

// ---------------------------------------------------------------------------
// f32 -> bf16 elementwise (4 per thread)
// ---------------------------------------------------------------------------
__global__ __launch_bounds__(256) void conv_f2b(const float* __restrict__ in,
                                                USHORT* __restrict__ out, int n4) {
  int i = blockIdx.x * 256 + threadIdx.x;
  if (i >= n4) return;
  float4 v = reinterpret_cast<const float4*>(in)[i];
  USHORT* o = out + (size_t)i * 4;
  o[0] = f2bf(v.x); o[1] = f2bf(v.y); o[2] = f2bf(v.z); o[3] = f2bf(v.w);
}

// ---------------------------------------------------------------------------
// W[K][N] f32 -> Wt[N][K] bf16. 32x32 LDS transpose.
// ---------------------------------------------------------------------------
__global__ __launch_bounds__(256) void conv_transpose(const float* __restrict__ W,
                                                      USHORT* __restrict__ Th,
                                                      int K, int N) {
  __shared__ float t[32][33];
  const int n0 = blockIdx.x * 32, k0 = blockIdx.y * 32;
  const int c = threadIdx.x & 31, r0 = threadIdx.x >> 5;
  for (int r = r0; r < 32; r += 8) t[r][c] = W[(size_t)(k0 + r) * N + n0 + c];
  __syncthreads();
  for (int r = r0; r < 32; r += 8)
    Th[(size_t)(n0 + r) * K + k0 + c] = f2bf(t[c][r]);  // = W[k0+c][n0+r]
}

// ---------------------------------------------------------------------------
// bf16 V-transpose: VtG[c][s] = qkv[s][2*DIM + c]  (c = h*80+d, 0..1279).
// 32x32 LDS tiles, coalesced both sides.
// ---------------------------------------------------------------------------
__global__ __launch_bounds__(256) void vtrans(const USHORT* __restrict__ qkv,
                                              USHORT* __restrict__ VtG) {
  __shared__ USHORT t[32][33];
  const int c0 = blockIdx.x * 32, s0 = blockIdx.y * 32;
  const int c = threadIdx.x & 31, r0 = threadIdx.x >> 5;
  for (int r = r0; r < 32; r += 8)
    t[r][c] = qkv[(size_t)(s0 + r) * QKVD + 2 * DIM + c0 + c];
  __syncthreads();
  for (int r = r0; r < 32; r += 8)
    VtG[(size_t)(c0 + r) * SEQ + s0 + c] = t[c][r];
}

// ---------------------------------------------------------------------------
// MFMA GEMM: C[M,N] = A[M,K] @ Bt[N,K]^T + bias. A row stride lda (shorts),
// Bt row stride K. 128x128 tile, BK=32, 256 threads (4 waves).
// ---------------------------------------------------------------------------
template <int OUTBF>
__global__ __launch_bounds__(256) void mfma_gemm(
    const USHORT* __restrict__ Ah, const USHORT* __restrict__ Bh,
    const float* __restrict__ bias, void* __restrict__ Cout,
    int M, int N, int K, int lda) {
  extern __shared__ USHORT sm[];
  USHORT* AhL = sm;           // 4096 shorts (128 rows x 32 k)
  USHORT* BhL = sm + 4096;

  const int tid = threadIdx.x;
  const int l = tid & 63;
  const int w = tid >> 6;
  const int nrow = M >> 7;
  const int nwg = nrow * (N >> 7);
  const int orig = blockIdx.x;
  const int wg = (orig & 7) * (nwg >> 3) + (orig >> 3);  // XCD swizzle (nwg%8==0)
  const int row0 = (wg % nrow) << 7;
  const int col0 = (wg / nrow) << 7;
  const int wr = (w >> 1) << 6;
  const int wc = (w & 1) << 6;

  const f32x4 fz = {0.f, 0.f, 0.f, 0.f};
  f32x4 acc[4][4];
#pragma unroll
  for (int m = 0; m < 4; ++m)
#pragma unroll
    for (int n = 0; n < 4; ++n) acc[m][n] = fz;

  const int sr = l >> 2;         // staging: row within 16-row group
  const int sk = (l & 3) << 3;   // staging: k offset (shorts)
  const int fr = l & 15;         // frag row(A)/col(B)
  const int fk = (l >> 4) << 3;  // frag k offset (shorts)

  for (int k0 = 0; k0 < K; k0 += 32) {
    __syncthreads();
#pragma unroll
    for (int i2 = 0; i2 < 2; ++i2) {
      const int i = w * 2 + i2;
      const size_t ga = (size_t)(row0 + i * 16 + sr) * lda + k0 + sk;
      const size_t gb = (size_t)(col0 + i * 16 + sr) * K + k0 + sk;
      gload16(Ah + ga, AhL + i * 512);
      gload16(Bh + gb, BhL + i * 512);
    }
    __syncthreads();
    bf16x8 ah[4], bh[4];
#pragma unroll
    for (int m = 0; m < 4; ++m) {
      ah[m] = *(const bf16x8*)&AhL[(wr + m * 16 + fr) * 32 + fk];
      bh[m] = *(const bf16x8*)&BhL[(wc + m * 16 + fr) * 32 + fk];
    }
#pragma unroll
    for (int m = 0; m < 4; ++m)
#pragma unroll
      for (int n = 0; n < 4; ++n)
        acc[m][n] = __builtin_amdgcn_mfma_f32_16x16x32_bf16(ah[m], bh[n], acc[m][n], 0, 0, 0);
  }

  float bv[4];
#pragma unroll
  for (int n = 0; n < 4; ++n) bv[n] = bias[col0 + wc + n * 16 + fr];
#pragma unroll
  for (int m = 0; m < 4; ++m)
#pragma unroll
    for (int n = 0; n < 4; ++n)
#pragma unroll
      for (int r = 0; r < 4; ++r) {
        const float v = acc[m][n][r] + bv[n];
        const int row = row0 + wr + m * 16 + (l >> 4) * 4 + r;
        const int col = col0 + wc + n * 16 + fr;
        if (OUTBF)
          ((USHORT*)Cout)[(size_t)row * N + col] = f2bf(v);
        else
          ((float*)Cout)[(size_t)row * N + col] = v;
      }
}

// ---------------------------------------------------------------------------
// RoPE in-place on bf16 qkv (q,k halves). Thread per rotation pair.
// ---------------------------------------------------------------------------
__global__ __launch_bounds__(256) void rope_b(USHORT* __restrict__ qkv,
                                              const float* __restrict__ cosb,
                                              const float* __restrict__ sinb) {
  int idx = blockIdx.x * 256 + threadIdx.x;  // SEQ*HEADS*2*40 total
  const int d = idx % 40;
  int t = idx / 40;
  const int h = t % HEADS;
  t /= HEADS;
  const int qk = t & 1;
  const int s = t >> 1;
  USHORT* base = qkv + (size_t)s * QKVD + qk * DIM + h * HD;
  const float x1 = bf2f(base[d]);
  const float x2 = bf2f(base[d + 40]);
  const float c1 = cosb[s * HD + d], s1 = sinb[s * HD + d];
  const float c2 = cosb[s * HD + d + 40], s2 = sinb[s * HD + d + 40];
  base[d] = f2bf(x1 * c1 - x2 * s1);
  base[d + 40] = f2bf(x2 * c2 + x1 * s2);
}

// ---------------------------------------------------------------------------
// 1KB zero region for global_load_lds pad sources.
// ---------------------------------------------------------------------------
__global__ void zero_ws(uint4* z) {
  z[threadIdx.x] = uint4{0u, 0u, 0u, 0u};
}

// ---------------------------------------------------------------------------
// Flash attention v6 (= verified v5 core): swapped QK^T (S^T = K@Q^T),
// lane-local softmax with defer-max, P via wave-private LDS, V^T staged from
// pre-transposed global VtG, K via swizzled global_load_lds.
// Epilogue now writes bf16 DIRECTLY into the dead V-slots of qkv
// (cols 2560..3839), which become the A operand of the proj GEMM (lda=3840).
// Block = (128 q-rows, head); 4 waves x 32 q-rows.
// ---------------------------------------------------------------------------
__global__ __launch_bounds__(256) void attn_mfma5(const USHORT* __restrict__ qkv,
                                                  const USHORT* __restrict__ VtG,
                                                  const USHORT* __restrict__ zbuf,
                                                  USHORT* __restrict__ aoB) {
  const int h = blockIdx.y;
  const int s0 = blockIdx.x * 128;
  const int k0g = (s0 / LSEG) * LSEG;
  const int tid = threadIdx.x;
  const int w = tid >> 6, l = tid & 63;
  const int g = l >> 4, fr = l & 15;
  const int q0 = s0 + w * 32;

  __shared__ __align__(16) USHORT Kl[64 * 128];
  __shared__ __align__(16) USHORT Vl[6144];      // 80 rows x 72 + staging tail
  __shared__ __align__(16) USHORT Pl[4][32 * 72];

  // Q B-frags, hoisted. Tail dims 80..95 read in-row garbage (finite) --
  // multiplied by K's zeroed pad, contribute 0.
  bf16x8 qb[2][3];
#pragma unroll
  for (int nt2 = 0; nt2 < 2; ++nt2)
#pragma unroll
    for (int ks = 0; ks < 3; ++ks)
      qb[nt2][ks] = *(const bf16x8*)&qkv[(size_t)(q0 + nt2 * 16 + fr) * QKVD +
                                         h * HD + ks * 32 + g * 8];

  const f32x4 fz = {0.f, 0.f, 0.f, 0.f};
  f32x4 oacc[2][5];
#pragma unroll
  for (int m = 0; m < 2; ++m)
#pragma unroll
    for (int n = 0; n < 5; ++n) oacc[m][n] = fz;
  float m_run[2] = {-3e38f, -3e38f};
  float l_run[2] = {0.f, 0.f};

  for (int kb = 0; kb < 16; ++kb) {
    const size_t krow0 = (size_t)(k0g + kb * 64);
    __syncthreads();  // previous iteration's readers done

    // ---- stage K: 16 gload16 calls (4/wave), swizzled source ----
#pragma unroll
    for (int i = 0; i < 4; ++i) {
      const int t = (w * 4 + i) * 64 + l;
      const int row = t >> 4, c2 = t & 15, c = c2 ^ (row & 7);
      const USHORT* src =
          (c < 10) ? &qkv[(krow0 + row) * QKVD + DIM + h * HD + c * 8] : zbuf;
      gload16(src, &Kl[(w * 4 + i) * 512]);
    }
    // ---- stage V^T: 12 gload16 calls (3/wave) from VtG ----
#pragma unroll
    for (int i = 0; i < 3; ++i) {
      const int u = (w * 3 + i) * 64 + l;
      const int s = u / 9, r8 = u - s * 9;   // d-row s, 16B chunk r8 (8=pad)
      const USHORT* src = (r8 < 8 && s < 80)
          ? &VtG[(size_t)(h * HD + s) * SEQ + krow0 + r8 * 8] : zbuf;
      gload16(src, &Vl[(w * 3 + i) * 512]);
    }
    __syncthreads();

    // ---- QK^T: S^T[64 keys][32 q]; lane holds keys {16m+4g+j}, q=16nt2+fr --
    f32x4 sc[4][2];
#pragma unroll
    for (int m = 0; m < 4; ++m)
#pragma unroll
      for (int nt2 = 0; nt2 < 2; ++nt2) sc[m][nt2] = fz;
#pragma unroll
    for (int ks = 0; ks < 3; ++ks)
#pragma unroll
      for (int m = 0; m < 4; ++m) {
        const bf16x8 kbf = *(const bf16x8*)
            &Kl[(m * 16 + fr) * 128 + ((4 * ks + g) ^ (fr & 7)) * 8];
#pragma unroll
        for (int nt2 = 0; nt2 < 2; ++nt2)
          sc[m][nt2] = __builtin_amdgcn_mfma_f32_16x16x32_bf16(
              kbf, qb[nt2][ks], sc[m][nt2], 0, 0, 0);
      }

    // ---- lane-local online softmax with defer-max ----
    float rmax[2];
#pragma unroll
    for (int nt2 = 0; nt2 < 2; ++nt2) {
      float mx = -3e38f;
#pragma unroll
      for (int m = 0; m < 4; ++m)
#pragma unroll
        for (int j = 0; j < 4; ++j) mx = fmaxf(mx, sc[m][nt2][j]);
      mx = fmaxf(mx, __shfl_xor(mx, 16));
      mx = fmaxf(mx, __shfl_xor(mx, 32));
      rmax[nt2] = mx;
    }
    const bool need =
        (rmax[0] > m_run[0] + DTHR) || (rmax[1] > m_run[1] + DTHR);
    if (__any(need)) {
      float fac[2];
#pragma unroll
      for (int nt2 = 0; nt2 < 2; ++nt2) {
        const float mn = fmaxf(m_run[nt2], rmax[nt2]);
        fac[nt2] = exp2f((m_run[nt2] - mn) * CSF);
        m_run[nt2] = mn;
        l_run[nt2] *= fac[nt2];
      }
#pragma unroll
      for (int mt2 = 0; mt2 < 2; ++mt2)
#pragma unroll
        for (int j = 0; j < 4; ++j) {
          const float fb = __shfl(fac[mt2], 20 * g + j);
#pragma unroll
          for (int nt = 0; nt < 5; ++nt) oacc[mt2][nt][j] *= fb;
        }
    }
#pragma unroll
    for (int nt2 = 0; nt2 < 2; ++nt2) {
      const float mcs = m_run[nt2] * CSF;
      float ps = 0.f;
#pragma unroll
      for (int m = 0; m < 4; ++m) {
        u16x4 w4;
#pragma unroll
        for (int j = 0; j < 4; ++j) {
          const float p = exp2f(sc[m][nt2][j] * CSF - mcs);
          ps += p;
          w4[j] = f2bf(p);
        }
        // P[q = nt2*16+fr][keys 16m+4g .. +3]
        *(u16x4*)&Pl[w][(nt2 * 16 + fr) * 72 + m * 16 + g * 4] = w4;
      }
      ps += __shfl_xor(ps, 16);
      ps += __shfl_xor(ps, 32);
      l_run[nt2] += ps;
    }

    // ---- PV: O[32q][80d] += P @ V (ordered keys; V^T rows are d) ----
#pragma unroll
    for (int ks = 0; ks < 2; ++ks) {
      bf16x8 pa[2];
#pragma unroll
      for (int mt2 = 0; mt2 < 2; ++mt2)
        pa[mt2] = *(const bf16x8*)&Pl[w][(mt2 * 16 + fr) * 72 + ks * 32 + g * 8];
#pragma unroll
      for (int nt = 0; nt < 5; ++nt) {
        const bf16x8 vb =
            *(const bf16x8*)&Vl[(nt * 16 + fr) * 72 + ks * 32 + g * 8];
#pragma unroll
        for (int mt2 = 0; mt2 < 2; ++mt2)
          oacc[mt2][nt] = __builtin_amdgcn_mfma_f32_16x16x32_bf16(
              pa[mt2], vb, oacc[mt2][nt], 0, 0, 0);
      }
    }
  }

  // ---- epilogue: normalize, store bf16 into qkv's dead V-slots ----
  float linv[2][4];
#pragma unroll
  for (int mt2 = 0; mt2 < 2; ++mt2)
#pragma unroll
    for (int j = 0; j < 4; ++j)
      linv[mt2][j] = 1.f / __shfl(l_run[mt2], 20 * g + j);
#pragma unroll
  for (int mt2 = 0; mt2 < 2; ++mt2)
#pragma unroll
    for (int nt = 0; nt < 5; ++nt)
#pragma unroll
      for (int j = 0; j < 4; ++j) {
        const int row = s0 + w * 32 + mt2 * 16 + g * 4 + j;
        const int col = h * HD + nt * 16 + fr;
        aoB[(size_t)row * QKVD + col] = f2bf(oacc[mt2][nt][j] * linv[mt2][j]);
      }
}

// ---------------------------------------------------------------------------
// ws layout (bytes):
//   [0, 62914560)            qkv bf16 [8192][3840]; during attn, the V-slots
//                            (cols 2560..3839) are dead (V read via VtG) and
//                            receive the attn output bf16 -> proj A (lda=3840)
//   [62914560, 83886080)     hs bf16 [8192][1280]; after GEMM1 reused as
//                            VtG bf16 [1280][8192] (V pre-transposed)
//   [83886080, 93716480)     qkv_w^T bf16 [3840][1280]; first 1KB re-zeroed
//                            after GEMM1 -> zbuf for attn pad sources
//   [93716480, 96993280)     proj_w^T bf16 [1280][1280]
// ---------------------------------------------------------------------------
extern "C" void kernel_launch(void* const* d_in, const int* in_sizes, int n_in,
                              void* d_out, int out_size, void* d_ws,
                              size_t ws_size, hipStream_t stream) {
  const float* hs = (const float*)d_in[0];
  const float* cosb = (const float*)d_in[1];
  const float* sinb = (const float*)d_in[2];
  const float* qkv_w = (const float*)d_in[3];
  const float* qkv_b = (const float*)d_in[4];
  const float* proj_w = (const float*)d_in[5];
  const float* proj_b = (const float*)d_in[6];
  char* ws = (char*)d_ws;

  USHORT* qkvB  = (USHORT*)(ws);
  USHORT* hsB   = (USHORT*)(ws + 62914560u);
  USHORT* qkvwT = (USHORT*)(ws + 83886080u);
  USHORT* pwT   = (USHORT*)(ws + 93716480u);
  USHORT* VtG   = hsB;                        // hsB dead after GEMM1
  USHORT* zbuf  = qkvwT;                      // qkvwT dead after GEMM1
  USHORT* aoB   = qkvB + 2 * DIM;             // attn out -> dead V-slots

  // input conversions
  conv_f2b<<<SEQ * DIM / 4 / 256, 256, 0, stream>>>(hs, hsB, SEQ * DIM / 4);
  conv_transpose<<<dim3(QKVD / 32, DIM / 32), 256, 0, stream>>>(
      qkv_w, qkvwT, DIM, QKVD);
  conv_transpose<<<dim3(DIM / 32, DIM / 32), 256, 0, stream>>>(
      proj_w, pwT, DIM, DIM);

  // 1) qkv = hs @ qkv_w + b  (bf16 out)
  mfma_gemm<1><<<(SEQ / 128) * (QKVD / 128), 256, 16384, stream>>>(
      hsB, qkvwT, qkv_b, qkvB, SEQ, QKVD, DIM, DIM);
  // 2) RoPE in place (q,k only)
  rope_b<<<SEQ * HEADS * 2 * 40 / 256, 256, 0, stream>>>(qkvB, cosb, sinb);
  // 2.3) pre-transpose V: VtG[c][s]  (hsB region is dead now)
  vtrans<<<dim3(DIM / 32, SEQ / 32), 256, 0, stream>>>(qkvB, VtG);
  // 2.6) zero pad-source region (qkvwT dead after GEMM1)
  zero_ws<<<1, 64, 0, stream>>>((uint4*)zbuf);
  // 3) attention -> bf16 into qkv's dead V-slots
  attn_mfma5<<<dim3(SEQ / 128, HEADS), 256, 0, stream>>>(qkvB, VtG, zbuf, aoB);
  // 4) out = attn @ proj_w + b  (f32 out) -> d_out   (A stride = QKVD)
  mfma_gemm<0><<<(SEQ / 128) * (DIM / 128), 256, 16384, stream>>>(
      aoB, pwT, proj_b, d_out, SEQ, DIM, DIM, QKVD);
}

// Round 7
// 333.613 us; speedup vs baseline: 8.9900x; 1.0337x over previous
//
#include <hip/hip_runtime.h>

#define SEQ   8192
#define DIM   1280
#define HEADS 16
#define HD    80
#define LSEG  1024
#define QKVD  3840

typedef unsigned short USHORT;
typedef __attribute__((ext_vector_type(8))) short bf16x8;
typedef __attribute__((ext_vector_type(4))) float f32x4;
typedef __attribute__((ext_vector_type(4))) USHORT u16x4;

#define CSF  0.16129832f    // (1/sqrt(80)) * log2(e)
#define DTHR 71.554175f     // 8 / (1/sqrt(80)) : defer-max threshold in raw units

__device__ __forceinline__ USHORT f2bf(float x) {
  unsigned u = __float_as_uint(x);
  u += 0x7fffu + ((u >> 16) & 1u);
  return (USHORT)(u >> 16);
}
__device__ __forceinline__ float bf2f(USHORT b) {
  return __uint_as_float(((unsigned)b) << 16);
}
__device__ __forceinline__ void gload16(const void* g, void* l) {
  __builtin_amdgcn_global_load_lds(
      (const __attribute__((address_space(1))) void*)g,
      (__attribute__((address_space(3))) void*)l, 16, 0, 0);
}

// ---------------------------------------------------------------------------
// f32 -> bf16 elementwise (4 per thread)
// ---------------------------------------------------------------------------
__global__ __launch_bounds__(256) void conv_f2b(const float* __restrict__ in,
                                                USHORT* __restrict__ out, int n4) {
  int i = blockIdx.x * 256 + threadIdx.x;
  if (i >= n4) return;
  float4 v = reinterpret_cast<const float4*>(in)[i];
  USHORT* o = out + (size_t)i * 4;
  o[0] = f2bf(v.x); o[1] = f2bf(v.y); o[2] = f2bf(v.z); o[3] = f2bf(v.w);
}

// ---------------------------------------------------------------------------
// W[K][N] f32 -> Wt[N][K] bf16. 32x32 LDS transpose.
// ---------------------------------------------------------------------------
__global__ __launch_bounds__(256) void conv_transpose(const float* __restrict__ W,
                                                      USHORT* __restrict__ Th,
                                                      int K, int N) {
  __shared__ float t[32][33];
  const int n0 = blockIdx.x * 32, k0 = blockIdx.y * 32;
  const int c = threadIdx.x & 31, r0 = threadIdx.x >> 5;
  for (int r = r0; r < 32; r += 8) t[r][c] = W[(size_t)(k0 + r) * N + n0 + c];
  __syncthreads();
  for (int r = r0; r < 32; r += 8)
    Th[(size_t)(n0 + r) * K + k0 + c] = f2bf(t[c][r]);  // = W[k0+c][n0+r]
}

// ---------------------------------------------------------------------------
// bf16 V-transpose: VtG[c][s] = qkv[s][2*DIM + c]  (c = h*80+d, 0..1279).
// 32x32 LDS tiles, coalesced both sides.
// ---------------------------------------------------------------------------
__global__ __launch_bounds__(256) void vtrans(const USHORT* __restrict__ qkv,
                                              USHORT* __restrict__ VtG) {
  __shared__ USHORT t[32][33];
  const int c0 = blockIdx.x * 32, s0 = blockIdx.y * 32;
  const int c = threadIdx.x & 31, r0 = threadIdx.x >> 5;
  for (int r = r0; r < 32; r += 8)
    t[r][c] = qkv[(size_t)(s0 + r) * QKVD + 2 * DIM + c0 + c];
  __syncthreads();
  for (int r = r0; r < 32; r += 8)
    VtG[(size_t)(c0 + r) * SEQ + s0 + c] = t[c][r];
}

// ---------------------------------------------------------------------------
// MFMA GEMM, depth-2 counted-vmcnt pipeline (T3/T4-lite):
// C[M,N] = A[M,K] @ Bt[N,K]^T + bias. A row stride lda (shorts), Bt stride K.
// 128x128 tile, BK=32, 256 threads (4 waves). Double-buffered LDS; per iter:
//   vmcnt(4) [retire tile t only] -> barrier -> ds_read frags -> lgkmcnt(0)
//   -> barrier -> stage tile t+2 into just-read buffer -> 16 MFMA.
// Tile t+1's loads stay in flight across the whole iteration.
// ---------------------------------------------------------------------------
template <int OUTBF>
__global__ __launch_bounds__(256) void mfma_gemm(
    const USHORT* __restrict__ Ah, const USHORT* __restrict__ Bh,
    const float* __restrict__ bias, void* __restrict__ Cout,
    int M, int N, int K, int lda) {
  __shared__ __align__(16) USHORT AhL[2][4096];
  __shared__ __align__(16) USHORT BhL[2][4096];

  const int tid = threadIdx.x;
  const int l = tid & 63;
  const int w = tid >> 6;
  const int nrow = M >> 7;
  const int nwg = nrow * (N >> 7);
  const int orig = blockIdx.x;
  const int wg = (orig & 7) * (nwg >> 3) + (orig >> 3);  // XCD swizzle (nwg%8==0)
  const int row0 = (wg % nrow) << 7;
  const int col0 = (wg / nrow) << 7;
  const int wr = (w >> 1) << 6;
  const int wc = (w & 1) << 6;

  const f32x4 fz = {0.f, 0.f, 0.f, 0.f};
  f32x4 acc[4][4];
#pragma unroll
  for (int m = 0; m < 4; ++m)
#pragma unroll
    for (int n = 0; n < 4; ++n) acc[m][n] = fz;

  const int sr = l >> 2;         // staging: row within 16-row group
  const int sk = (l & 3) << 3;   // staging: k offset (shorts)
  const int fr = l & 15;         // frag row(A)/col(B)
  const int fk = (l >> 4) << 3;  // frag k offset (shorts)

  const int NT = K >> 5;

  // stage tile t (K cols t*32..t*32+31) into buffer b: 4 gload16 per thread
  auto stage = [&](int t, int b) {
    const int k0 = t << 5;
#pragma unroll
    for (int i2 = 0; i2 < 2; ++i2) {
      const int i = w * 2 + i2;
      gload16(Ah + (size_t)(row0 + i * 16 + sr) * lda + k0 + sk,
              &AhL[b][i * 512]);
      gload16(Bh + (size_t)(col0 + i * 16 + sr) * K + k0 + sk,
              &BhL[b][i * 512]);
    }
  };

  stage(0, 0);
  stage(1, 1);

  for (int t = 0; t < NT; ++t) {
    const int cur = t & 1;
    // retire tile t's 4 loads/wave; tile t+1's 4 stay in flight
    asm volatile("s_waitcnt vmcnt(4)" ::: "memory");
    __builtin_amdgcn_sched_barrier(0);
    __builtin_amdgcn_s_barrier();
    __builtin_amdgcn_sched_barrier(0);
    bf16x8 ah[4], bh[4];
#pragma unroll
    for (int m = 0; m < 4; ++m) {
      ah[m] = *(const bf16x8*)&AhL[cur][(wr + m * 16 + fr) * 32 + fk];
      bh[m] = *(const bf16x8*)&BhL[cur][(wc + m * 16 + fr) * 32 + fk];
    }
    asm volatile("s_waitcnt lgkmcnt(0)" ::: "memory");
    __builtin_amdgcn_sched_barrier(0);
    __builtin_amdgcn_s_barrier();   // all waves done reading buf[cur]
    __builtin_amdgcn_sched_barrier(0);
    // stage tile t+2 into the just-read buffer (dummy restage near the tail
    // keeps vmcnt counting uniform; rewrites already-consumed data)
    const int tn = (t + 2 < NT) ? t + 2 : t;
    stage(tn, cur);
    __builtin_amdgcn_sched_barrier(0);
    __builtin_amdgcn_s_setprio(1);
#pragma unroll
    for (int m = 0; m < 4; ++m)
#pragma unroll
      for (int n = 0; n < 4; ++n)
        acc[m][n] = __builtin_amdgcn_mfma_f32_16x16x32_bf16(ah[m], bh[n],
                                                            acc[m][n], 0, 0, 0);
    __builtin_amdgcn_s_setprio(0);
  }

  // drain pending global_load_lds before LDS deallocation at endpgm
  asm volatile("s_waitcnt vmcnt(0)" ::: "memory");

  float bv[4];
#pragma unroll
  for (int n = 0; n < 4; ++n) bv[n] = bias[col0 + wc + n * 16 + fr];
#pragma unroll
  for (int m = 0; m < 4; ++m)
#pragma unroll
    for (int n = 0; n < 4; ++n)
#pragma unroll
      for (int r = 0; r < 4; ++r) {
        const float v = acc[m][n][r] + bv[n];
        const int row = row0 + wr + m * 16 + (l >> 4) * 4 + r;
        const int col = col0 + wc + n * 16 + fr;
        if (OUTBF)
          ((USHORT*)Cout)[(size_t)row * N + col] = f2bf(v);
        else
          ((float*)Cout)[(size_t)row * N + col] = v;
      }
}

// ---------------------------------------------------------------------------
// RoPE in-place on bf16 qkv (q,k halves). Thread per rotation pair.
// ---------------------------------------------------------------------------
__global__ __launch_bounds__(256) void rope_b(USHORT* __restrict__ qkv,
                                              const float* __restrict__ cosb,
                                              const float* __restrict__ sinb) {
  int idx = blockIdx.x * 256 + threadIdx.x;  // SEQ*HEADS*2*40 total
  const int d = idx % 40;
  int t = idx / 40;
  const int h = t % HEADS;
  t /= HEADS;
  const int qk = t & 1;
  const int s = t >> 1;
  USHORT* base = qkv + (size_t)s * QKVD + qk * DIM + h * HD;
  const float x1 = bf2f(base[d]);
  const float x2 = bf2f(base[d + 40]);
  const float c1 = cosb[s * HD + d], s1 = sinb[s * HD + d];
  const float c2 = cosb[s * HD + d + 40], s2 = sinb[s * HD + d + 40];
  base[d] = f2bf(x1 * c1 - x2 * s1);
  base[d + 40] = f2bf(x2 * c2 + x1 * s2);
}

// ---------------------------------------------------------------------------
// 1KB zero region for global_load_lds pad sources.
// ---------------------------------------------------------------------------
__global__ void zero_ws(uint4* z) {
  z[threadIdx.x] = uint4{0u, 0u, 0u, 0u};
}

// ---------------------------------------------------------------------------
// Flash attention (verified v5 core): swapped QK^T (S^T = K@Q^T),
// lane-local softmax with defer-max, P via wave-private LDS, V^T staged from
// pre-transposed global VtG, K via swizzled global_load_lds.
// Epilogue writes bf16 directly into the dead V-slots of qkv (cols
// 2560..3839) -> proj GEMM A operand (lda=3840).
// Block = (128 q-rows, head); 4 waves x 32 q-rows.
// ---------------------------------------------------------------------------
__global__ __launch_bounds__(256) void attn_mfma5(const USHORT* __restrict__ qkv,
                                                  const USHORT* __restrict__ VtG,
                                                  const USHORT* __restrict__ zbuf,
                                                  USHORT* __restrict__ aoB) {
  const int h = blockIdx.y;
  const int s0 = blockIdx.x * 128;
  const int k0g = (s0 / LSEG) * LSEG;
  const int tid = threadIdx.x;
  const int w = tid >> 6, l = tid & 63;
  const int g = l >> 4, fr = l & 15;
  const int q0 = s0 + w * 32;

  __shared__ __align__(16) USHORT Kl[64 * 128];
  __shared__ __align__(16) USHORT Vl[6144];      // 80 rows x 72 + staging tail
  __shared__ __align__(16) USHORT Pl[4][32 * 72];

  // Q B-frags, hoisted. Tail dims 80..95 read in-row garbage (finite) --
  // multiplied by K's zeroed pad, contribute 0.
  bf16x8 qb[2][3];
#pragma unroll
  for (int nt2 = 0; nt2 < 2; ++nt2)
#pragma unroll
    for (int ks = 0; ks < 3; ++ks)
      qb[nt2][ks] = *(const bf16x8*)&qkv[(size_t)(q0 + nt2 * 16 + fr) * QKVD +
                                         h * HD + ks * 32 + g * 8];

  const f32x4 fz = {0.f, 0.f, 0.f, 0.f};
  f32x4 oacc[2][5];
#pragma unroll
  for (int m = 0; m < 2; ++m)
#pragma unroll
    for (int n = 0; n < 5; ++n) oacc[m][n] = fz;
  float m_run[2] = {-3e38f, -3e38f};
  float l_run[2] = {0.f, 0.f};

  for (int kb = 0; kb < 16; ++kb) {
    const size_t krow0 = (size_t)(k0g + kb * 64);
    __syncthreads();  // previous iteration's readers done

    // ---- stage K: 16 gload16 calls (4/wave), swizzled source ----
#pragma unroll
    for (int i = 0; i < 4; ++i) {
      const int t = (w * 4 + i) * 64 + l;
      const int row = t >> 4, c2 = t & 15, c = c2 ^ (row & 7);
      const USHORT* src =
          (c < 10) ? &qkv[(krow0 + row) * QKVD + DIM + h * HD + c * 8] : zbuf;
      gload16(src, &Kl[(w * 4 + i) * 512]);
    }
    // ---- stage V^T: 12 gload16 calls (3/wave) from VtG ----
#pragma unroll
    for (int i = 0; i < 3; ++i) {
      const int u = (w * 3 + i) * 64 + l;
      const int s = u / 9, r8 = u - s * 9;   // d-row s, 16B chunk r8 (8=pad)
      const USHORT* src = (r8 < 8 && s < 80)
          ? &VtG[(size_t)(h * HD + s) * SEQ + krow0 + r8 * 8] : zbuf;
      gload16(src, &Vl[(w * 3 + i) * 512]);
    }
    __syncthreads();

    // ---- QK^T: S^T[64 keys][32 q]; lane holds keys {16m+4g+j}, q=16nt2+fr --
    f32x4 sc[4][2];
#pragma unroll
    for (int m = 0; m < 4; ++m)
#pragma unroll
      for (int nt2 = 0; nt2 < 2; ++nt2) sc[m][nt2] = fz;
#pragma unroll
    for (int ks = 0; ks < 3; ++ks)
#pragma unroll
      for (int m = 0; m < 4; ++m) {
        const bf16x8 kbf = *(const bf16x8*)
            &Kl[(m * 16 + fr) * 128 + ((4 * ks + g) ^ (fr & 7)) * 8];
#pragma unroll
        for (int nt2 = 0; nt2 < 2; ++nt2)
          sc[m][nt2] = __builtin_amdgcn_mfma_f32_16x16x32_bf16(
              kbf, qb[nt2][ks], sc[m][nt2], 0, 0, 0);
      }

    // ---- lane-local online softmax with defer-max ----
    float rmax[2];
#pragma unroll
    for (int nt2 = 0; nt2 < 2; ++nt2) {
      float mx = -3e38f;
#pragma unroll
      for (int m = 0; m < 4; ++m)
#pragma unroll
        for (int j = 0; j < 4; ++j) mx = fmaxf(mx, sc[m][nt2][j]);
      mx = fmaxf(mx, __shfl_xor(mx, 16));
      mx = fmaxf(mx, __shfl_xor(mx, 32));
      rmax[nt2] = mx;
    }
    const bool need =
        (rmax[0] > m_run[0] + DTHR) || (rmax[1] > m_run[1] + DTHR);
    if (__any(need)) {
      float fac[2];
#pragma unroll
      for (int nt2 = 0; nt2 < 2; ++nt2) {
        const float mn = fmaxf(m_run[nt2], rmax[nt2]);
        fac[nt2] = exp2f((m_run[nt2] - mn) * CSF);
        m_run[nt2] = mn;
        l_run[nt2] *= fac[nt2];
      }
#pragma unroll
      for (int mt2 = 0; mt2 < 2; ++mt2)
#pragma unroll
        for (int j = 0; j < 4; ++j) {
          const float fb = __shfl(fac[mt2], 20 * g + j);
#pragma unroll
          for (int nt = 0; nt < 5; ++nt) oacc[mt2][nt][j] *= fb;
        }
    }
#pragma unroll
    for (int nt2 = 0; nt2 < 2; ++nt2) {
      const float mcs = m_run[nt2] * CSF;
      float ps = 0.f;
#pragma unroll
      for (int m = 0; m < 4; ++m) {
        u16x4 w4;
#pragma unroll
        for (int j = 0; j < 4; ++j) {
          const float p = exp2f(sc[m][nt2][j] * CSF - mcs);
          ps += p;
          w4[j] = f2bf(p);
        }
        // P[q = nt2*16+fr][keys 16m+4g .. +3]
        *(u16x4*)&Pl[w][(nt2 * 16 + fr) * 72 + m * 16 + g * 4] = w4;
      }
      ps += __shfl_xor(ps, 16);
      ps += __shfl_xor(ps, 32);
      l_run[nt2] += ps;
    }

    // ---- PV: O[32q][80d] += P @ V (ordered keys; V^T rows are d) ----
#pragma unroll
    for (int ks = 0; ks < 2; ++ks) {
      bf16x8 pa[2];
#pragma unroll
      for (int mt2 = 0; mt2 < 2; ++mt2)
        pa[mt2] = *(const bf16x8*)&Pl[w][(mt2 * 16 + fr) * 72 + ks * 32 + g * 8];
#pragma unroll
      for (int nt = 0; nt < 5; ++nt) {
        const bf16x8 vb =
            *(const bf16x8*)&Vl[(nt * 16 + fr) * 72 + ks * 32 + g * 8];
#pragma unroll
        for (int mt2 = 0; mt2 < 2; ++mt2)
          oacc[mt2][nt] = __builtin_amdgcn_mfma_f32_16x16x32_bf16(
              pa[mt2], vb, oacc[mt2][nt], 0, 0, 0);
      }
    }
  }

  // ---- epilogue: normalize, store bf16 into qkv's dead V-slots ----
  float linv[2][4];
#pragma unroll
  for (int mt2 = 0; mt2 < 2; ++mt2)
#pragma unroll
    for (int j = 0; j < 4; ++j)
      linv[mt2][j] = 1.f / __shfl(l_run[mt2], 20 * g + j);
#pragma unroll
  for (int mt2 = 0; mt2 < 2; ++mt2)
#pragma unroll
    for (int nt = 0; nt < 5; ++nt)
#pragma unroll
      for (int j = 0; j < 4; ++j) {
        const int row = s0 + w * 32 + mt2 * 16 + g * 4 + j;
        const int col = h * HD + nt * 16 + fr;
        aoB[(size_t)row * QKVD + col] = f2bf(oacc[mt2][nt][j] * linv[mt2][j]);
      }
}

// ---------------------------------------------------------------------------
// ws layout (bytes):
//   [0, 62914560)            qkv bf16 [8192][3840]; during attn, the V-slots
//                            (cols 2560..3839) are dead (V read via VtG) and
//                            receive the attn output bf16 -> proj A (lda=3840)
//   [62914560, 83886080)     hs bf16 [8192][1280]; after GEMM1 reused as
//                            VtG bf16 [1280][8192] (V pre-transposed)
//   [83886080, 93716480)     qkv_w^T bf16 [3840][1280]; first 1KB re-zeroed
//                            after GEMM1 -> zbuf for attn pad sources
//   [93716480, 96993280)     proj_w^T bf16 [1280][1280]
// ---------------------------------------------------------------------------
extern "C" void kernel_launch(void* const* d_in, const int* in_sizes, int n_in,
                              void* d_out, int out_size, void* d_ws,
                              size_t ws_size, hipStream_t stream) {
  const float* hs = (const float*)d_in[0];
  const float* cosb = (const float*)d_in[1];
  const float* sinb = (const float*)d_in[2];
  const float* qkv_w = (const float*)d_in[3];
  const float* qkv_b = (const float*)d_in[4];
  const float* proj_w = (const float*)d_in[5];
  const float* proj_b = (const float*)d_in[6];
  char* ws = (char*)d_ws;

  USHORT* qkvB  = (USHORT*)(ws);
  USHORT* hsB   = (USHORT*)(ws + 62914560u);
  USHORT* qkvwT = (USHORT*)(ws + 83886080u);
  USHORT* pwT   = (USHORT*)(ws + 93716480u);
  USHORT* VtG   = hsB;                        // hsB dead after GEMM1
  USHORT* zbuf  = qkvwT;                      // qkvwT dead after GEMM1
  USHORT* aoB   = qkvB + 2 * DIM;             // attn out -> dead V-slots

  // input conversions
  conv_f2b<<<SEQ * DIM / 4 / 256, 256, 0, stream>>>(hs, hsB, SEQ * DIM / 4);
  conv_transpose<<<dim3(QKVD / 32, DIM / 32), 256, 0, stream>>>(
      qkv_w, qkvwT, DIM, QKVD);
  conv_transpose<<<dim3(DIM / 32, DIM / 32), 256, 0, stream>>>(
      proj_w, pwT, DIM, DIM);

  // 1) qkv = hs @ qkv_w + b  (bf16 out)
  mfma_gemm<1><<<(SEQ / 128) * (QKVD / 128), 256, 0, stream>>>(
      hsB, qkvwT, qkv_b, qkvB, SEQ, QKVD, DIM, DIM);
  // 2) RoPE in place (q,k only)
  rope_b<<<SEQ * HEADS * 2 * 40 / 256, 256, 0, stream>>>(qkvB, cosb, sinb);
  // 2.3) pre-transpose V: VtG[c][s]  (hsB region is dead now)
  vtrans<<<dim3(DIM / 32, SEQ / 32), 256, 0, stream>>>(qkvB, VtG);
  // 2.6) zero pad-source region (qkvwT dead after GEMM1)
  zero_ws<<<1, 64, 0, stream>>>((uint4*)zbuf);
  // 3) attention -> bf16 into qkv's dead V-slots
  attn_mfma5<<<dim3(SEQ / 128, HEADS), 256, 0, stream>>>(qkvB, VtG, zbuf, aoB);
  // 4) out = attn @ proj_w + b  (f32 out) -> d_out   (A stride = QKVD)
  mfma_gemm<0><<<(SEQ / 128) * (DIM / 128), 256, 0, stream>>>(
      aoB, pwT, proj_b, d_out, SEQ, DIM, DIM, QKVD);
}

// Round 8
// 323.860 us; speedup vs baseline: 9.2607x; 1.0301x over previous
//
#include <hip/hip_runtime.h>

#define SEQ   8192
#define DIM   1280
#define HEADS 16
#define HD    80
#define LSEG  1024
#define QKVD  3840

typedef unsigned short USHORT;
typedef __attribute__((ext_vector_type(8))) short bf16x8;
typedef __attribute__((ext_vector_type(4))) float f32x4;
typedef __attribute__((ext_vector_type(4))) USHORT u16x4;

#define CSF  0.16129832f    // (1/sqrt(80)) * log2(e)
#define DTHR 71.554175f     // 8 / (1/sqrt(80)) : defer-max threshold in raw units

__device__ __forceinline__ USHORT f2bf(float x) {
  unsigned u = __float_as_uint(x);
  u += 0x7fffu + ((u >> 16) & 1u);
  return (USHORT)(u >> 16);
}
__device__ __forceinline__ float bf2f(USHORT b) {
  return __uint_as_float(((unsigned)b) << 16);
}
__device__ __forceinline__ void gload16(const void* g, void* l) {
  __builtin_amdgcn_global_load_lds(
      (const __attribute__((address_space(1))) void*)g,
      (__attribute__((address_space(3))) void*)l, 16, 0, 0);
}

// ---------------------------------------------------------------------------
// f32 -> bf16 elementwise (4 per thread)
// ---------------------------------------------------------------------------
__global__ __launch_bounds__(256) void conv_f2b(const float* __restrict__ in,
                                                USHORT* __restrict__ out, int n4) {
  int i = blockIdx.x * 256 + threadIdx.x;
  if (i >= n4) return;
  float4 v = reinterpret_cast<const float4*>(in)[i];
  USHORT* o = out + (size_t)i * 4;
  o[0] = f2bf(v.x); o[1] = f2bf(v.y); o[2] = f2bf(v.z); o[3] = f2bf(v.w);
}

// ---------------------------------------------------------------------------
// W[K][N] f32 -> Wt[N][K] bf16. 32x32 LDS transpose.
// ---------------------------------------------------------------------------
__global__ __launch_bounds__(256) void conv_transpose(const float* __restrict__ W,
                                                      USHORT* __restrict__ Th,
                                                      int K, int N) {
  __shared__ float t[32][33];
  const int n0 = blockIdx.x * 32, k0 = blockIdx.y * 32;
  const int c = threadIdx.x & 31, r0 = threadIdx.x >> 5;
  for (int r = r0; r < 32; r += 8) t[r][c] = W[(size_t)(k0 + r) * N + n0 + c];
  __syncthreads();
  for (int r = r0; r < 32; r += 8)
    Th[(size_t)(n0 + r) * K + k0 + c] = f2bf(t[c][r]);  // = W[k0+c][n0+r]
}

// ---------------------------------------------------------------------------
// bf16 V-transpose: VtG[c][s] = qkv[s][2*DIM + c]  (c = h*80+d, 0..1279).
// 32x32 LDS tiles, coalesced both sides.
// ---------------------------------------------------------------------------
__global__ __launch_bounds__(256) void vtrans(const USHORT* __restrict__ qkv,
                                              USHORT* __restrict__ VtG) {
  __shared__ USHORT t[32][33];
  const int c0 = blockIdx.x * 32, s0 = blockIdx.y * 32;
  const int c = threadIdx.x & 31, r0 = threadIdx.x >> 5;
  for (int r = r0; r < 32; r += 8)
    t[r][c] = qkv[(size_t)(s0 + r) * QKVD + 2 * DIM + c0 + c];
  __syncthreads();
  for (int r = r0; r < 32; r += 8)
    VtG[(size_t)(c0 + r) * SEQ + s0 + c] = t[c][r];
}

// ---------------------------------------------------------------------------
// MFMA GEMM, depth-2 counted-vmcnt pipeline + T2 XOR-swizzled LDS:
// C[M,N] = A[M,K] @ Bt[N,K]^T + bias. A row stride lda (shorts), Bt stride K.
// 128x128 tile, BK=64, 256 threads (4 waves).
// LDS tile [128 rows][64 k] shorts (128B rows); slot c2 of row r holds
// global k-chunk (c2 ^ (r&7)) -- staged by pre-swizzling the GLOBAL source
// (LDS dest linear, per gload_lds semantics). Frag reads XOR the slot with
// fr&7 -> every 8 consecutive lanes touch all 8 slots -> conflict-free.
// Per iter: vmcnt(8) [retire tile t] -> barrier -> ds_read 16 frags ->
// lgkmcnt(0) -> barrier -> stage tile t+2 -> 32 MFMA (ks-outer: k-order
// identical to the BK=32 version, bit-identical results).
// ---------------------------------------------------------------------------
template <int OUTBF>
__global__ __launch_bounds__(256) void mfma_gemm(
    const USHORT* __restrict__ Ah, const USHORT* __restrict__ Bh,
    const float* __restrict__ bias, void* __restrict__ Cout,
    int M, int N, int K, int lda) {
  __shared__ __align__(16) USHORT AhL[2][8192];
  __shared__ __align__(16) USHORT BhL[2][8192];

  const int tid = threadIdx.x;
  const int l = tid & 63;
  const int w = tid >> 6;
  const int nrow = M >> 7;
  const int nwg = nrow * (N >> 7);
  const int orig = blockIdx.x;
  const int wg = (orig & 7) * (nwg >> 3) + (orig >> 3);  // XCD swizzle (nwg%8==0)
  const int row0 = (wg % nrow) << 7;
  const int col0 = (wg / nrow) << 7;
  const int wr = (w >> 1) << 6;
  const int wc = (w & 1) << 6;

  const f32x4 fz = {0.f, 0.f, 0.f, 0.f};
  f32x4 acc[4][4];
#pragma unroll
  for (int m = 0; m < 4; ++m)
#pragma unroll
    for (int n = 0; n < 4; ++n) acc[m][n] = fz;

  const int fr = l & 15;         // frag row(A)/col(B)
  const int g = l >> 4;          // 16-lane group -> k sub-chunk

  const int NT = K >> 6;

  // stage tile t (K cols t*64..t*64+63) into buffer b: 8 gload16 per thread.
  // LDS linear chunk u = (w*4+i)*64 + l -> row u>>3, slot u&7; source chunk
  // c = (u&7) ^ (row&7).
  auto stage = [&](int t, int b) {
    const int k0 = t << 6;
#pragma unroll
    for (int i = 0; i < 4; ++i) {
      const int u = (w * 4 + i) * 64 + l;
      const int row = u >> 3;
      const int c = (u & 7) ^ (row & 7);
      gload16(Ah + (size_t)(row0 + row) * lda + k0 + c * 8,
              &AhL[b][(w * 4 + i) * 512]);
      gload16(Bh + (size_t)(col0 + row) * K + k0 + c * 8,
              &BhL[b][(w * 4 + i) * 512]);
    }
  };

  stage(0, 0);
  stage(1, 1);

  for (int t = 0; t < NT; ++t) {
    const int cur = t & 1;
    // retire tile t's 8 loads/thread; tile t+1's 8 stay in flight
    asm volatile("s_waitcnt vmcnt(8)" ::: "memory");
    __builtin_amdgcn_sched_barrier(0);
    __builtin_amdgcn_s_barrier();
    __builtin_amdgcn_sched_barrier(0);
    bf16x8 ah[2][4], bh[2][4];
#pragma unroll
    for (int ks = 0; ks < 2; ++ks)
#pragma unroll
      for (int m = 0; m < 4; ++m) {
        const int sl = (((ks << 2) + g) ^ (fr & 7)) << 3;
        ah[ks][m] = *(const bf16x8*)&AhL[cur][(wr + m * 16 + fr) * 64 + sl];
        bh[ks][m] = *(const bf16x8*)&BhL[cur][(wc + m * 16 + fr) * 64 + sl];
      }
    asm volatile("s_waitcnt lgkmcnt(0)" ::: "memory");
    __builtin_amdgcn_sched_barrier(0);
    __builtin_amdgcn_s_barrier();   // all waves done reading buf[cur]
    __builtin_amdgcn_sched_barrier(0);
    // stage tile t+2 into the just-read buffer (dummy restage near the tail
    // keeps vmcnt counting uniform; rewrites already-consumed data)
    const int tn = (t + 2 < NT) ? t + 2 : t;
    stage(tn, cur);
    __builtin_amdgcn_sched_barrier(0);
    __builtin_amdgcn_s_setprio(1);
#pragma unroll
    for (int ks = 0; ks < 2; ++ks)
#pragma unroll
      for (int m = 0; m < 4; ++m)
#pragma unroll
        for (int n = 0; n < 4; ++n)
          acc[m][n] = __builtin_amdgcn_mfma_f32_16x16x32_bf16(
              ah[ks][m], bh[ks][n], acc[m][n], 0, 0, 0);
    __builtin_amdgcn_s_setprio(0);
  }

  // drain pending global_load_lds before LDS deallocation at endpgm
  asm volatile("s_waitcnt vmcnt(0)" ::: "memory");

  float bv[4];
#pragma unroll
  for (int n = 0; n < 4; ++n) bv[n] = bias[col0 + wc + n * 16 + fr];
#pragma unroll
  for (int m = 0; m < 4; ++m)
#pragma unroll
    for (int n = 0; n < 4; ++n)
#pragma unroll
      for (int r = 0; r < 4; ++r) {
        const float v = acc[m][n][r] + bv[n];
        const int row = row0 + wr + m * 16 + (l >> 4) * 4 + r;
        const int col = col0 + wc + n * 16 + fr;
        if (OUTBF)
          ((USHORT*)Cout)[(size_t)row * N + col] = f2bf(v);
        else
          ((float*)Cout)[(size_t)row * N + col] = v;
      }
}

// ---------------------------------------------------------------------------
// RoPE in-place on bf16 qkv (q,k halves). Thread per rotation pair.
// ---------------------------------------------------------------------------
__global__ __launch_bounds__(256) void rope_b(USHORT* __restrict__ qkv,
                                              const float* __restrict__ cosb,
                                              const float* __restrict__ sinb) {
  int idx = blockIdx.x * 256 + threadIdx.x;  // SEQ*HEADS*2*40 total
  const int d = idx % 40;
  int t = idx / 40;
  const int h = t % HEADS;
  t /= HEADS;
  const int qk = t & 1;
  const int s = t >> 1;
  USHORT* base = qkv + (size_t)s * QKVD + qk * DIM + h * HD;
  const float x1 = bf2f(base[d]);
  const float x2 = bf2f(base[d + 40]);
  const float c1 = cosb[s * HD + d], s1 = sinb[s * HD + d];
  const float c2 = cosb[s * HD + d + 40], s2 = sinb[s * HD + d + 40];
  base[d] = f2bf(x1 * c1 - x2 * s1);
  base[d + 40] = f2bf(x2 * c2 + x1 * s2);
}

// ---------------------------------------------------------------------------
// 1KB zero region for global_load_lds pad sources.
// ---------------------------------------------------------------------------
__global__ void zero_ws(uint4* z) {
  z[threadIdx.x] = uint4{0u, 0u, 0u, 0u};
}

// ---------------------------------------------------------------------------
// Flash attention (verified v5 core): swapped QK^T (S^T = K@Q^T),
// lane-local softmax with defer-max, P via wave-private LDS, V^T staged from
// pre-transposed global VtG, K via swizzled global_load_lds.
// Epilogue writes bf16 directly into the dead V-slots of qkv (cols
// 2560..3839) -> proj GEMM A operand (lda=3840).
// Block = (128 q-rows, head); 4 waves x 32 q-rows.
// ---------------------------------------------------------------------------
__global__ __launch_bounds__(256) void attn_mfma5(const USHORT* __restrict__ qkv,
                                                  const USHORT* __restrict__ VtG,
                                                  const USHORT* __restrict__ zbuf,
                                                  USHORT* __restrict__ aoB) {
  const int h = blockIdx.y;
  const int s0 = blockIdx.x * 128;
  const int k0g = (s0 / LSEG) * LSEG;
  const int tid = threadIdx.x;
  const int w = tid >> 6, l = tid & 63;
  const int g = l >> 4, fr = l & 15;
  const int q0 = s0 + w * 32;

  __shared__ __align__(16) USHORT Kl[64 * 128];
  __shared__ __align__(16) USHORT Vl[6144];      // 80 rows x 72 + staging tail
  __shared__ __align__(16) USHORT Pl[4][32 * 72];

  // Q B-frags, hoisted. Tail dims 80..95 read in-row garbage (finite) --
  // multiplied by K's zeroed pad, contribute 0.
  bf16x8 qb[2][3];
#pragma unroll
  for (int nt2 = 0; nt2 < 2; ++nt2)
#pragma unroll
    for (int ks = 0; ks < 3; ++ks)
      qb[nt2][ks] = *(const bf16x8*)&qkv[(size_t)(q0 + nt2 * 16 + fr) * QKVD +
                                         h * HD + ks * 32 + g * 8];

  const f32x4 fz = {0.f, 0.f, 0.f, 0.f};
  f32x4 oacc[2][5];
#pragma unroll
  for (int m = 0; m < 2; ++m)
#pragma unroll
    for (int n = 0; n < 5; ++n) oacc[m][n] = fz;
  float m_run[2] = {-3e38f, -3e38f};
  float l_run[2] = {0.f, 0.f};

  for (int kb = 0; kb < 16; ++kb) {
    const size_t krow0 = (size_t)(k0g + kb * 64);
    __syncthreads();  // previous iteration's readers done

    // ---- stage K: 16 gload16 calls (4/wave), swizzled source ----
#pragma unroll
    for (int i = 0; i < 4; ++i) {
      const int t = (w * 4 + i) * 64 + l;
      const int row = t >> 4, c2 = t & 15, c = c2 ^ (row & 7);
      const USHORT* src =
          (c < 10) ? &qkv[(krow0 + row) * QKVD + DIM + h * HD + c * 8] : zbuf;
      gload16(src, &Kl[(w * 4 + i) * 512]);
    }
    // ---- stage V^T: 12 gload16 calls (3/wave) from VtG ----
#pragma unroll
    for (int i = 0; i < 3; ++i) {
      const int u = (w * 3 + i) * 64 + l;
      const int s = u / 9, r8 = u - s * 9;   // d-row s, 16B chunk r8 (8=pad)
      const USHORT* src = (r8 < 8 && s < 80)
          ? &VtG[(size_t)(h * HD + s) * SEQ + krow0 + r8 * 8] : zbuf;
      gload16(src, &Vl[(w * 3 + i) * 512]);
    }
    __syncthreads();

    // ---- QK^T: S^T[64 keys][32 q]; lane holds keys {16m+4g+j}, q=16nt2+fr --
    f32x4 sc[4][2];
#pragma unroll
    for (int m = 0; m < 4; ++m)
#pragma unroll
      for (int nt2 = 0; nt2 < 2; ++nt2) sc[m][nt2] = fz;
#pragma unroll
    for (int ks = 0; ks < 3; ++ks)
#pragma unroll
      for (int m = 0; m < 4; ++m) {
        const bf16x8 kbf = *(const bf16x8*)
            &Kl[(m * 16 + fr) * 128 + ((4 * ks + g) ^ (fr & 7)) * 8];
#pragma unroll
        for (int nt2 = 0; nt2 < 2; ++nt2)
          sc[m][nt2] = __builtin_amdgcn_mfma_f32_16x16x32_bf16(
              kbf, qb[nt2][ks], sc[m][nt2], 0, 0, 0);
      }

    // ---- lane-local online softmax with defer-max ----
    float rmax[2];
#pragma unroll
    for (int nt2 = 0; nt2 < 2; ++nt2) {
      float mx = -3e38f;
#pragma unroll
      for (int m = 0; m < 4; ++m)
#pragma unroll
        for (int j = 0; j < 4; ++j) mx = fmaxf(mx, sc[m][nt2][j]);
      mx = fmaxf(mx, __shfl_xor(mx, 16));
      mx = fmaxf(mx, __shfl_xor(mx, 32));
      rmax[nt2] = mx;
    }
    const bool need =
        (rmax[0] > m_run[0] + DTHR) || (rmax[1] > m_run[1] + DTHR);
    if (__any(need)) {
      float fac[2];
#pragma unroll
      for (int nt2 = 0; nt2 < 2; ++nt2) {
        const float mn = fmaxf(m_run[nt2], rmax[nt2]);
        fac[nt2] = exp2f((m_run[nt2] - mn) * CSF);
        m_run[nt2] = mn;
        l_run[nt2] *= fac[nt2];
      }
#pragma unroll
      for (int mt2 = 0; mt2 < 2; ++mt2)
#pragma unroll
        for (int j = 0; j < 4; ++j) {
          const float fb = __shfl(fac[mt2], 20 * g + j);
#pragma unroll
          for (int nt = 0; nt < 5; ++nt) oacc[mt2][nt][j] *= fb;
        }
    }
#pragma unroll
    for (int nt2 = 0; nt2 < 2; ++nt2) {
      const float mcs = m_run[nt2] * CSF;
      float ps = 0.f;
#pragma unroll
      for (int m = 0; m < 4; ++m) {
        u16x4 w4;
#pragma unroll
        for (int j = 0; j < 4; ++j) {
          const float p = exp2f(sc[m][nt2][j] * CSF - mcs);
          ps += p;
          w4[j] = f2bf(p);
        }
        // P[q = nt2*16+fr][keys 16m+4g .. +3]
        *(u16x4*)&Pl[w][(nt2 * 16 + fr) * 72 + m * 16 + g * 4] = w4;
      }
      ps += __shfl_xor(ps, 16);
      ps += __shfl_xor(ps, 32);
      l_run[nt2] += ps;
    }

    // ---- PV: O[32q][80d] += P @ V (ordered keys; V^T rows are d) ----
#pragma unroll
    for (int ks = 0; ks < 2; ++ks) {
      bf16x8 pa[2];
#pragma unroll
      for (int mt2 = 0; mt2 < 2; ++mt2)
        pa[mt2] = *(const bf16x8*)&Pl[w][(mt2 * 16 + fr) * 72 + ks * 32 + g * 8];
#pragma unroll
      for (int nt = 0; nt < 5; ++nt) {
        const bf16x8 vb =
            *(const bf16x8*)&Vl[(nt * 16 + fr) * 72 + ks * 32 + g * 8];
#pragma unroll
        for (int mt2 = 0; mt2 < 2; ++mt2)
          oacc[mt2][nt] = __builtin_amdgcn_mfma_f32_16x16x32_bf16(
              pa[mt2], vb, oacc[mt2][nt], 0, 0, 0);
      }
    }
  }

  // ---- epilogue: normalize, store bf16 into qkv's dead V-slots ----
  float linv[2][4];
#pragma unroll
  for (int mt2 = 0; mt2 < 2; ++mt2)
#pragma unroll
    for (int j = 0; j < 4; ++j)
      linv[mt2][j] = 1.f / __shfl(l_run[mt2], 20 * g + j);
#pragma unroll
  for (int mt2 = 0; mt2 < 2; ++mt2)
#pragma unroll
    for (int nt = 0; nt < 5; ++nt)
#pragma unroll
      for (int j = 0; j < 4; ++j) {
        const int row = s0 + w * 32 + mt2 * 16 + g * 4 + j;
        const int col = h * HD + nt * 16 + fr;
        aoB[(size_t)row * QKVD + col] = f2bf(oacc[mt2][nt][j] * linv[mt2][j]);
      }
}

// ---------------------------------------------------------------------------
// ws layout (bytes):
//   [0, 62914560)            qkv bf16 [8192][3840]; during attn, the V-slots
//                            (cols 2560..3839) are dead (V read via VtG) and
//                            receive the attn output bf16 -> proj A (lda=3840)
//   [62914560, 83886080)     hs bf16 [8192][1280]; after GEMM1 reused as
//                            VtG bf16 [1280][8192] (V pre-transposed)
//   [83886080, 93716480)     qkv_w^T bf16 [3840][1280]; first 1KB re-zeroed
//                            after GEMM1 -> zbuf for attn pad sources
//   [93716480, 96993280)     proj_w^T bf16 [1280][1280]
// ---------------------------------------------------------------------------
extern "C" void kernel_launch(void* const* d_in, const int* in_sizes, int n_in,
                              void* d_out, int out_size, void* d_ws,
                              size_t ws_size, hipStream_t stream) {
  const float* hs = (const float*)d_in[0];
  const float* cosb = (const float*)d_in[1];
  const float* sinb = (const float*)d_in[2];
  const float* qkv_w = (const float*)d_in[3];
  const float* qkv_b = (const float*)d_in[4];
  const float* proj_w = (const float*)d_in[5];
  const float* proj_b = (const float*)d_in[6];
  char* ws = (char*)d_ws;

  USHORT* qkvB  = (USHORT*)(ws);
  USHORT* hsB   = (USHORT*)(ws + 62914560u);
  USHORT* qkvwT = (USHORT*)(ws + 83886080u);
  USHORT* pwT   = (USHORT*)(ws + 93716480u);
  USHORT* VtG   = hsB;                        // hsB dead after GEMM1
  USHORT* zbuf  = qkvwT;                      // qkvwT dead after GEMM1
  USHORT* aoB   = qkvB + 2 * DIM;             // attn out -> dead V-slots

  // input conversions
  conv_f2b<<<SEQ * DIM / 4 / 256, 256, 0, stream>>>(hs, hsB, SEQ * DIM / 4);
  conv_transpose<<<dim3(QKVD / 32, DIM / 32), 256, 0, stream>>>(
      qkv_w, qkvwT, DIM, QKVD);
  conv_transpose<<<dim3(DIM / 32, DIM / 32), 256, 0, stream>>>(
      proj_w, pwT, DIM, DIM);

  // 1) qkv = hs @ qkv_w + b  (bf16 out)
  mfma_gemm<1><<<(SEQ / 128) * (QKVD / 128), 256, 0, stream>>>(
      hsB, qkvwT, qkv_b, qkvB, SEQ, QKVD, DIM, DIM);
  // 2) RoPE in place (q,k only)
  rope_b<<<SEQ * HEADS * 2 * 40 / 256, 256, 0, stream>>>(qkvB, cosb, sinb);
  // 2.3) pre-transpose V: VtG[c][s]  (hsB region is dead now)
  vtrans<<<dim3(DIM / 32, SEQ / 32), 256, 0, stream>>>(qkvB, VtG);
  // 2.6) zero pad-source region (qkvwT dead after GEMM1)
  zero_ws<<<1, 64, 0, stream>>>((uint4*)zbuf);
  // 3) attention -> bf16 into qkv's dead V-slots
  attn_mfma5<<<dim3(SEQ / 128, HEADS), 256, 0, stream>>>(qkvB, VtG, zbuf, aoB);
  // 4) out = attn @ proj_w + b  (f32 out) -> d_out   (A stride = QKVD)
  mfma_gemm<0><<<(SEQ / 128) * (DIM / 128), 256, 0, stream>>>(
      aoB, pwT, proj_b, d_out, SEQ, DIM, DIM, QKVD);
}

// Round 9
// 311.555 us; speedup vs baseline: 9.6264x; 1.0395x over previous
//
#include <hip/hip_runtime.h>

#define SEQ   8192
#define DIM   1280
#define HEADS 16
#define HD    80
#define LSEG  1024
#define QKVD  3840

typedef unsigned short USHORT;
typedef __attribute__((ext_vector_type(8))) short bf16x8;
typedef __attribute__((ext_vector_type(4))) float f32x4;
typedef __attribute__((ext_vector_type(4))) USHORT u16x4;
typedef __attribute__((ext_vector_type(2))) unsigned uint2v;

#define CSF  0.16129832f    // (1/sqrt(80)) * log2(e)
#define DTHR 71.554175f     // 8 / (1/sqrt(80)) : defer-max threshold in raw units

__device__ __forceinline__ USHORT f2bf(float x) {
  unsigned u = __float_as_uint(x);
  u += 0x7fffu + ((u >> 16) & 1u);
  return (USHORT)(u >> 16);
}
__device__ __forceinline__ float bf2f(USHORT b) {
  return __uint_as_float(((unsigned)b) << 16);
}
__device__ __forceinline__ void gload16(const void* g, void* l) {
  __builtin_amdgcn_global_load_lds(
      (const __attribute__((address_space(1))) void*)g,
      (__attribute__((address_space(3))) void*)l, 16, 0, 0);
}
// packs {bf16(a) -> [15:0], bf16(b) -> [31:16]}, RNE (same as f2bf)
__device__ __forceinline__ unsigned cvtpk(float a, float b) {
  unsigned d;
  asm("v_cvt_pk_bf16_f32 %0, %1, %2" : "=v"(d) : "v"(a), "v"(b));
  return d;
}

// ---------------------------------------------------------------------------
// f32 -> bf16 elementwise (4 per thread)
// ---------------------------------------------------------------------------
__global__ __launch_bounds__(256) void conv_f2b(const float* __restrict__ in,
                                                USHORT* __restrict__ out, int n4) {
  int i = blockIdx.x * 256 + threadIdx.x;
  if (i >= n4) return;
  float4 v = reinterpret_cast<const float4*>(in)[i];
  USHORT* o = out + (size_t)i * 4;
  o[0] = f2bf(v.x); o[1] = f2bf(v.y); o[2] = f2bf(v.z); o[3] = f2bf(v.w);
}

// ---------------------------------------------------------------------------
// W[K][N] f32 -> Wt[N][K] bf16. 32x32 LDS transpose.
// ---------------------------------------------------------------------------
__global__ __launch_bounds__(256) void conv_transpose(const float* __restrict__ W,
                                                      USHORT* __restrict__ Th,
                                                      int K, int N) {
  __shared__ float t[32][33];
  const int n0 = blockIdx.x * 32, k0 = blockIdx.y * 32;
  const int c = threadIdx.x & 31, r0 = threadIdx.x >> 5;
  for (int r = r0; r < 32; r += 8) t[r][c] = W[(size_t)(k0 + r) * N + n0 + c];
  __syncthreads();
  for (int r = r0; r < 32; r += 8)
    Th[(size_t)(n0 + r) * K + k0 + c] = f2bf(t[c][r]);  // = W[k0+c][n0+r]
}

// ---------------------------------------------------------------------------
// bf16 V-transpose: VtG[c][s] = qkv[s][2*DIM + c]  (c = h*80+d, 0..1279).
// ---------------------------------------------------------------------------
__global__ __launch_bounds__(256) void vtrans(const USHORT* __restrict__ qkv,
                                              USHORT* __restrict__ VtG) {
  __shared__ USHORT t[32][33];
  const int c0 = blockIdx.x * 32, s0 = blockIdx.y * 32;
  const int c = threadIdx.x & 31, r0 = threadIdx.x >> 5;
  for (int r = r0; r < 32; r += 8)
    t[r][c] = qkv[(size_t)(s0 + r) * QKVD + 2 * DIM + c0 + c];
  __syncthreads();
  for (int r = r0; r < 32; r += 8)
    VtG[(size_t)(c0 + r) * SEQ + s0 + c] = t[c][r];
}

// ---------------------------------------------------------------------------
// MFMA GEMM, depth-2 counted-vmcnt pipeline + T2 XOR-swizzled LDS (r8-proven).
// ---------------------------------------------------------------------------
template <int OUTBF>
__global__ __launch_bounds__(256) void mfma_gemm(
    const USHORT* __restrict__ Ah, const USHORT* __restrict__ Bh,
    const float* __restrict__ bias, void* __restrict__ Cout,
    int M, int N, int K, int lda) {
  __shared__ __align__(16) USHORT AhL[2][8192];
  __shared__ __align__(16) USHORT BhL[2][8192];

  const int tid = threadIdx.x;
  const int l = tid & 63;
  const int w = tid >> 6;
  const int nrow = M >> 7;
  const int nwg = nrow * (N >> 7);
  const int orig = blockIdx.x;
  const int wg = (orig & 7) * (nwg >> 3) + (orig >> 3);  // XCD swizzle (nwg%8==0)
  const int row0 = (wg % nrow) << 7;
  const int col0 = (wg / nrow) << 7;
  const int wr = (w >> 1) << 6;
  const int wc = (w & 1) << 6;

  const f32x4 fz = {0.f, 0.f, 0.f, 0.f};
  f32x4 acc[4][4];
#pragma unroll
  for (int m = 0; m < 4; ++m)
#pragma unroll
    for (int n = 0; n < 4; ++n) acc[m][n] = fz;

  const int fr = l & 15;
  const int g = l >> 4;

  const int NT = K >> 6;

  auto stage = [&](int t, int b) {
    const int k0 = t << 6;
#pragma unroll
    for (int i = 0; i < 4; ++i) {
      const int u = (w * 4 + i) * 64 + l;
      const int row = u >> 3;
      const int c = (u & 7) ^ (row & 7);
      gload16(Ah + (size_t)(row0 + row) * lda + k0 + c * 8,
              &AhL[b][(w * 4 + i) * 512]);
      gload16(Bh + (size_t)(col0 + row) * K + k0 + c * 8,
              &BhL[b][(w * 4 + i) * 512]);
    }
  };

  stage(0, 0);
  stage(1, 1);

  for (int t = 0; t < NT; ++t) {
    const int cur = t & 1;
    asm volatile("s_waitcnt vmcnt(8)" ::: "memory");
    __builtin_amdgcn_sched_barrier(0);
    __builtin_amdgcn_s_barrier();
    __builtin_amdgcn_sched_barrier(0);
    bf16x8 ah[2][4], bh[2][4];
#pragma unroll
    for (int ks = 0; ks < 2; ++ks)
#pragma unroll
      for (int m = 0; m < 4; ++m) {
        const int sl = (((ks << 2) + g) ^ (fr & 7)) << 3;
        ah[ks][m] = *(const bf16x8*)&AhL[cur][(wr + m * 16 + fr) * 64 + sl];
        bh[ks][m] = *(const bf16x8*)&BhL[cur][(wc + m * 16 + fr) * 64 + sl];
      }
    asm volatile("s_waitcnt lgkmcnt(0)" ::: "memory");
    __builtin_amdgcn_sched_barrier(0);
    __builtin_amdgcn_s_barrier();
    __builtin_amdgcn_sched_barrier(0);
    const int tn = (t + 2 < NT) ? t + 2 : t;
    stage(tn, cur);
    __builtin_amdgcn_sched_barrier(0);
    __builtin_amdgcn_s_setprio(1);
#pragma unroll
    for (int ks = 0; ks < 2; ++ks)
#pragma unroll
      for (int m = 0; m < 4; ++m)
#pragma unroll
        for (int n = 0; n < 4; ++n)
          acc[m][n] = __builtin_amdgcn_mfma_f32_16x16x32_bf16(
              ah[ks][m], bh[ks][n], acc[m][n], 0, 0, 0);
    __builtin_amdgcn_s_setprio(0);
  }

  asm volatile("s_waitcnt vmcnt(0)" ::: "memory");

  float bv[4];
#pragma unroll
  for (int n = 0; n < 4; ++n) bv[n] = bias[col0 + wc + n * 16 + fr];
#pragma unroll
  for (int m = 0; m < 4; ++m)
#pragma unroll
    for (int n = 0; n < 4; ++n)
#pragma unroll
      for (int r = 0; r < 4; ++r) {
        const float v = acc[m][n][r] + bv[n];
        const int row = row0 + wr + m * 16 + (l >> 4) * 4 + r;
        const int col = col0 + wc + n * 16 + fr;
        if (OUTBF)
          ((USHORT*)Cout)[(size_t)row * N + col] = f2bf(v);
        else
          ((float*)Cout)[(size_t)row * N + col] = v;
      }
}

// ---------------------------------------------------------------------------
// RoPE in-place on bf16 qkv (q,k halves). Vectorized: 4 rotation pairs/thread.
// ---------------------------------------------------------------------------
__global__ __launch_bounds__(256) void rope_b(USHORT* __restrict__ qkv,
                                              const float* __restrict__ cosb,
                                              const float* __restrict__ sinb) {
  int idx = blockIdx.x * 256 + threadIdx.x;  // SEQ*HEADS*2*10 total
  const int d4 = (idx % 10) * 4;
  int t = idx / 10;
  const int h = t % HEADS;
  t /= HEADS;
  const int qk = t & 1;
  const int s = t >> 1;
  USHORT* base = qkv + (size_t)s * QKVD + qk * DIM + h * HD;
  const u16x4 x1 = *(const u16x4*)&base[d4];
  const u16x4 x2 = *(const u16x4*)&base[d4 + 40];
  const f32x4 c1 = *(const f32x4*)&cosb[s * HD + d4];
  const f32x4 s1 = *(const f32x4*)&sinb[s * HD + d4];
  const f32x4 c2 = *(const f32x4*)&cosb[s * HD + d4 + 40];
  const f32x4 s2 = *(const f32x4*)&sinb[s * HD + d4 + 40];
  u16x4 o1, o2;
#pragma unroll
  for (int j = 0; j < 4; ++j) {
    const float a = bf2f(x1[j]), b = bf2f(x2[j]);
    o1[j] = f2bf(a * c1[j] - b * s1[j]);
    o2[j] = f2bf(b * c2[j] + a * s2[j]);
  }
  *(u16x4*)&base[d4] = o1;
  *(u16x4*)&base[d4 + 40] = o2;
}

// ---------------------------------------------------------------------------
// 1KB zero region for global_load_lds pad sources.
// ---------------------------------------------------------------------------
__global__ void zero_ws(uint4* z) {
  z[threadIdx.x] = uint4{0u, 0u, 0u, 0u};
}

// ---------------------------------------------------------------------------
// Flash attention v7: r5-verified core + (a) segment-affine XCD swizzle
// (qb = (bx&7)*8 + bx>>3 -> XCD c holds segment c's K/V in its L2),
// (b) depth-2 counted-vmcnt K/V pipeline (7 gloads/wave/tile, vmcnt(7),
// raw barriers, dummy tail restage -- mirrors the proven GEMM structure),
// (c) v_cvt_pk_bf16_f32 P-packing (RNE, bit-identical to f2bf).
// Block = (128 q-rows, head); 4 waves x 32 q-rows; 16 KV tiles of 64 keys.
// ---------------------------------------------------------------------------
__global__ __launch_bounds__(256) void attn_mfma6(const USHORT* __restrict__ qkv,
                                                  const USHORT* __restrict__ VtG,
                                                  const USHORT* __restrict__ zbuf,
                                                  USHORT* __restrict__ aoB) {
  const int h = blockIdx.y;
  const int bx = blockIdx.x;
  const int qb = (bx & 7) * 8 + (bx >> 3);   // seg = bx&7 == XCD (id%8)
  const int s0 = qb * 128;
  const int k0g = (s0 / LSEG) * LSEG;
  const int tid = threadIdx.x;
  const int w = tid >> 6, l = tid & 63;
  const int g = l >> 4, fr = l & 15;
  const int q0 = s0 + w * 32;

  __shared__ __align__(16) USHORT Kl[2][64 * 128];
  __shared__ __align__(16) USHORT Vl[2][6144];   // 80 rows x 72 + staging tail
  __shared__ __align__(16) USHORT Pl[4][32 * 72];

  // Q B-frags, hoisted. Tail dims 80..95 read in-row garbage (finite) --
  // multiplied by K's zeroed pad, contribute 0.
  bf16x8 qb_frag[2][3];
#pragma unroll
  for (int nt2 = 0; nt2 < 2; ++nt2)
#pragma unroll
    for (int ks = 0; ks < 3; ++ks)
      qb_frag[nt2][ks] = *(const bf16x8*)
          &qkv[(size_t)(q0 + nt2 * 16 + fr) * QKVD + h * HD + ks * 32 + g * 8];

  const f32x4 fz = {0.f, 0.f, 0.f, 0.f};
  f32x4 oacc[2][5];
#pragma unroll
  for (int m = 0; m < 2; ++m)
#pragma unroll
    for (int n = 0; n < 5; ++n) oacc[m][n] = fz;
  float m_run[2] = {-3e38f, -3e38f};
  float l_run[2] = {0.f, 0.f};

  // stage KV tile kb into buffer b: 7 gload16 per wave (4 K + 3 V)
  auto stageKV = [&](int kb, int b) {
    const size_t krow0 = (size_t)(k0g + kb * 64);
#pragma unroll
    for (int i = 0; i < 4; ++i) {
      const int t = (w * 4 + i) * 64 + l;
      const int row = t >> 4, c2 = t & 15, c = c2 ^ (row & 7);
      const USHORT* src =
          (c < 10) ? &qkv[(krow0 + row) * QKVD + DIM + h * HD + c * 8] : zbuf;
      gload16(src, &Kl[b][(w * 4 + i) * 512]);
    }
#pragma unroll
    for (int i = 0; i < 3; ++i) {
      const int u = (w * 3 + i) * 64 + l;
      const int s = u / 9, r8 = u - s * 9;
      const USHORT* src = (r8 < 8 && s < 80)
          ? &VtG[(size_t)(h * HD + s) * SEQ + krow0 + r8 * 8] : zbuf;
      gload16(src, &Vl[b][(w * 3 + i) * 512]);
    }
  };

  stageKV(0, 0);
  stageKV(1, 1);

  for (int kb = 0; kb < 16; ++kb) {
    const int cur = kb & 1;
    // retire tile kb's 7 loads/wave; tile kb+1's 7 stay in flight
    asm volatile("s_waitcnt vmcnt(7)" ::: "memory");
    __builtin_amdgcn_sched_barrier(0);
    __builtin_amdgcn_s_barrier();   // all waves' tile-kb loads landed
    __builtin_amdgcn_sched_barrier(0);

    // ---- QK^T: S^T[64 keys][32 q]; lane holds keys {16m+4g+j}, q=16nt2+fr --
    f32x4 sc[4][2];
#pragma unroll
    for (int m = 0; m < 4; ++m)
#pragma unroll
      for (int nt2 = 0; nt2 < 2; ++nt2) sc[m][nt2] = fz;
#pragma unroll
    for (int ks = 0; ks < 3; ++ks)
#pragma unroll
      for (int m = 0; m < 4; ++m) {
        const bf16x8 kbf = *(const bf16x8*)
            &Kl[cur][(m * 16 + fr) * 128 + ((4 * ks + g) ^ (fr & 7)) * 8];
#pragma unroll
        for (int nt2 = 0; nt2 < 2; ++nt2)
          sc[m][nt2] = __builtin_amdgcn_mfma_f32_16x16x32_bf16(
              kbf, qb_frag[nt2][ks], sc[m][nt2], 0, 0, 0);
      }

    // ---- lane-local online softmax with defer-max ----
    float rmax[2];
#pragma unroll
    for (int nt2 = 0; nt2 < 2; ++nt2) {
      float mx = -3e38f;
#pragma unroll
      for (int m = 0; m < 4; ++m)
#pragma unroll
        for (int j = 0; j < 4; ++j) mx = fmaxf(mx, sc[m][nt2][j]);
      mx = fmaxf(mx, __shfl_xor(mx, 16));
      mx = fmaxf(mx, __shfl_xor(mx, 32));
      rmax[nt2] = mx;
    }
    const bool need =
        (rmax[0] > m_run[0] + DTHR) || (rmax[1] > m_run[1] + DTHR);
    if (__any(need)) {
      float fac[2];
#pragma unroll
      for (int nt2 = 0; nt2 < 2; ++nt2) {
        const float mn = fmaxf(m_run[nt2], rmax[nt2]);
        fac[nt2] = exp2f((m_run[nt2] - mn) * CSF);
        m_run[nt2] = mn;
        l_run[nt2] *= fac[nt2];
      }
#pragma unroll
      for (int mt2 = 0; mt2 < 2; ++mt2)
#pragma unroll
        for (int j = 0; j < 4; ++j) {
          const float fb = __shfl(fac[mt2], 20 * g + j);
#pragma unroll
          for (int nt = 0; nt < 5; ++nt) oacc[mt2][nt][j] *= fb;
        }
    }
#pragma unroll
    for (int nt2 = 0; nt2 < 2; ++nt2) {
      const float mcs = m_run[nt2] * CSF;
      float ps = 0.f;
#pragma unroll
      for (int m = 0; m < 4; ++m) {
        float p[4];
#pragma unroll
        for (int j = 0; j < 4; ++j) {
          p[j] = exp2f(sc[m][nt2][j] * CSF - mcs);
          ps += p[j];
        }
        const uint2v pw = {cvtpk(p[0], p[1]), cvtpk(p[2], p[3])};
        // P[q = nt2*16+fr][keys 16m+4g .. +3]
        *(uint2v*)&Pl[w][(nt2 * 16 + fr) * 72 + m * 16 + g * 4] = pw;
      }
      ps += __shfl_xor(ps, 16);
      ps += __shfl_xor(ps, 32);
      l_run[nt2] += ps;
    }

    // ---- PV: O[32q][80d] += P @ V (ordered keys; V^T rows are d) ----
#pragma unroll
    for (int ks = 0; ks < 2; ++ks) {
      bf16x8 pa[2];
#pragma unroll
      for (int mt2 = 0; mt2 < 2; ++mt2)
        pa[mt2] = *(const bf16x8*)&Pl[w][(mt2 * 16 + fr) * 72 + ks * 32 + g * 8];
#pragma unroll
      for (int nt = 0; nt < 5; ++nt) {
        const bf16x8 vb =
            *(const bf16x8*)&Vl[cur][(nt * 16 + fr) * 72 + ks * 32 + g * 8];
#pragma unroll
        for (int mt2 = 0; mt2 < 2; ++mt2)
          oacc[mt2][nt] = __builtin_amdgcn_mfma_f32_16x16x32_bf16(
              pa[mt2], vb, oacc[mt2][nt], 0, 0, 0);
      }
    }

    // all waves done reading buf[cur] (frag reads consumed by issued MFMAs)
    __builtin_amdgcn_s_barrier();
    __builtin_amdgcn_sched_barrier(0);
    // stage tile kb+2 into the just-read buffer (dummy restage at tail)
    const int kn = (kb + 2 < 16) ? kb + 2 : kb;
    stageKV(kn, cur);
    __builtin_amdgcn_sched_barrier(0);
  }

  // drain pending global_load_lds before LDS deallocation at endpgm
  asm volatile("s_waitcnt vmcnt(0)" ::: "memory");

  // ---- epilogue: normalize, store bf16 into qkv's dead V-slots ----
  float linv[2][4];
#pragma unroll
  for (int mt2 = 0; mt2 < 2; ++mt2)
#pragma unroll
    for (int j = 0; j < 4; ++j)
      linv[mt2][j] = 1.f / __shfl(l_run[mt2], 20 * g + j);
#pragma unroll
  for (int mt2 = 0; mt2 < 2; ++mt2)
#pragma unroll
    for (int nt = 0; nt < 5; ++nt)
#pragma unroll
      for (int j = 0; j < 4; ++j) {
        const int row = s0 + w * 32 + mt2 * 16 + g * 4 + j;
        const int col = h * HD + nt * 16 + fr;
        aoB[(size_t)row * QKVD + col] = f2bf(oacc[mt2][nt][j] * linv[mt2][j]);
      }
}

// ---------------------------------------------------------------------------
// ws layout (bytes):
//   [0, 62914560)            qkv bf16 [8192][3840]; during attn, the V-slots
//                            (cols 2560..3839) are dead (V read via VtG) and
//                            receive the attn output bf16 -> proj A (lda=3840)
//   [62914560, 83886080)     hs bf16 [8192][1280]; after GEMM1 reused as
//                            VtG bf16 [1280][8192] (V pre-transposed)
//   [83886080, 93716480)     qkv_w^T bf16 [3840][1280]; first 1KB re-zeroed
//                            after GEMM1 -> zbuf for attn pad sources
//   [93716480, 96993280)     proj_w^T bf16 [1280][1280]
// ---------------------------------------------------------------------------
extern "C" void kernel_launch(void* const* d_in, const int* in_sizes, int n_in,
                              void* d_out, int out_size, void* d_ws,
                              size_t ws_size, hipStream_t stream) {
  const float* hs = (const float*)d_in[0];
  const float* cosb = (const float*)d_in[1];
  const float* sinb = (const float*)d_in[2];
  const float* qkv_w = (const float*)d_in[3];
  const float* qkv_b = (const float*)d_in[4];
  const float* proj_w = (const float*)d_in[5];
  const float* proj_b = (const float*)d_in[6];
  char* ws = (char*)d_ws;

  USHORT* qkvB  = (USHORT*)(ws);
  USHORT* hsB   = (USHORT*)(ws + 62914560u);
  USHORT* qkvwT = (USHORT*)(ws + 83886080u);
  USHORT* pwT   = (USHORT*)(ws + 93716480u);
  USHORT* VtG   = hsB;                        // hsB dead after GEMM1
  USHORT* zbuf  = qkvwT;                      // qkvwT dead after GEMM1
  USHORT* aoB   = qkvB + 2 * DIM;             // attn out -> dead V-slots

  // input conversions
  conv_f2b<<<SEQ * DIM / 4 / 256, 256, 0, stream>>>(hs, hsB, SEQ * DIM / 4);
  conv_transpose<<<dim3(QKVD / 32, DIM / 32), 256, 0, stream>>>(
      qkv_w, qkvwT, DIM, QKVD);
  conv_transpose<<<dim3(DIM / 32, DIM / 32), 256, 0, stream>>>(
      proj_w, pwT, DIM, DIM);

  // 1) qkv = hs @ qkv_w + b  (bf16 out)
  mfma_gemm<1><<<(SEQ / 128) * (QKVD / 128), 256, 0, stream>>>(
      hsB, qkvwT, qkv_b, qkvB, SEQ, QKVD, DIM, DIM);
  // 2) RoPE in place (q,k only), vectorized
  rope_b<<<SEQ * HEADS * 2 * 10 / 256, 256, 0, stream>>>(qkvB, cosb, sinb);
  // 2.3) pre-transpose V: VtG[c][s]  (hsB region is dead now)
  vtrans<<<dim3(DIM / 32, SEQ / 32), 256, 0, stream>>>(qkvB, VtG);
  // 2.6) zero pad-source region (qkvwT dead after GEMM1)
  zero_ws<<<1, 64, 0, stream>>>((uint4*)zbuf);
  // 3) attention -> bf16 into qkv's dead V-slots
  attn_mfma6<<<dim3(SEQ / 128, HEADS), 256, 0, stream>>>(qkvB, VtG, zbuf, aoB);
  // 4) out = attn @ proj_w + b  (f32 out) -> d_out   (A stride = QKVD)
  mfma_gemm<0><<<(SEQ / 128) * (DIM / 128), 256, 0, stream>>>(
      aoB, pwT, proj_b, d_out, SEQ, DIM, DIM, QKVD);
}

// Round 10
// 290.010 us; speedup vs baseline: 10.3416x; 1.0743x over previous
//
#include <hip/hip_runtime.h>

#define SEQ   8192
#define DIM   1280
#define HEADS 16
#define HD    80
#define LSEG  1024
#define QKVD  3840

typedef unsigned short USHORT;
typedef __attribute__((ext_vector_type(8))) short bf16x8;
typedef __attribute__((ext_vector_type(4))) float f32x4;
typedef __attribute__((ext_vector_type(4))) USHORT u16x4;
typedef __attribute__((ext_vector_type(2))) unsigned uint2v;

#define CSF  0.16129832f    // (1/sqrt(80)) * log2(e)
#define DTHR 71.554175f     // 8 / (1/sqrt(80)) : defer-max threshold in raw units

__device__ __forceinline__ USHORT f2bf(float x) {
  unsigned u = __float_as_uint(x);
  u += 0x7fffu + ((u >> 16) & 1u);
  return (USHORT)(u >> 16);
}
__device__ __forceinline__ float bf2f(USHORT b) {
  return __uint_as_float(((unsigned)b) << 16);
}
__device__ __forceinline__ void gload16(const void* g, void* l) {
  __builtin_amdgcn_global_load_lds(
      (const __attribute__((address_space(1))) void*)g,
      (__attribute__((address_space(3))) void*)l, 16, 0, 0);
}
// packs {bf16(a) -> [15:0], bf16(b) -> [31:16]}, RNE (same as f2bf)
__device__ __forceinline__ unsigned cvtpk(float a, float b) {
  unsigned d;
  asm("v_cvt_pk_bf16_f32 %0, %1, %2" : "=v"(d) : "v"(a), "v"(b));
  return d;
}

// ---------------------------------------------------------------------------
// f32 -> bf16 elementwise (4 per thread)
// ---------------------------------------------------------------------------
__global__ __launch_bounds__(256) void conv_f2b(const float* __restrict__ in,
                                                USHORT* __restrict__ out, int n4) {
  int i = blockIdx.x * 256 + threadIdx.x;
  if (i >= n4) return;
  float4 v = reinterpret_cast<const float4*>(in)[i];
  USHORT* o = out + (size_t)i * 4;
  o[0] = f2bf(v.x); o[1] = f2bf(v.y); o[2] = f2bf(v.z); o[3] = f2bf(v.w);
}

// ---------------------------------------------------------------------------
// W[K][N] f32 -> Wt[N][K] bf16. 32x32 LDS transpose.
// ---------------------------------------------------------------------------
__global__ __launch_bounds__(256) void conv_transpose(const float* __restrict__ W,
                                                      USHORT* __restrict__ Th,
                                                      int K, int N) {
  __shared__ float t[32][33];
  const int n0 = blockIdx.x * 32, k0 = blockIdx.y * 32;
  const int c = threadIdx.x & 31, r0 = threadIdx.x >> 5;
  for (int r = r0; r < 32; r += 8) t[r][c] = W[(size_t)(k0 + r) * N + n0 + c];
  __syncthreads();
  for (int r = r0; r < 32; r += 8)
    Th[(size_t)(n0 + r) * K + k0 + c] = f2bf(t[c][r]);  // = W[k0+c][n0+r]
}

// ---------------------------------------------------------------------------
// bf16 V-transpose: VtG[c][s] = qkv[s][2*DIM + c]  (c = h*80+d, 0..1279).
// ---------------------------------------------------------------------------
__global__ __launch_bounds__(256) void vtrans(const USHORT* __restrict__ qkv,
                                              USHORT* __restrict__ VtG) {
  __shared__ USHORT t[32][33];
  const int c0 = blockIdx.x * 32, s0 = blockIdx.y * 32;
  const int c = threadIdx.x & 31, r0 = threadIdx.x >> 5;
  for (int r = r0; r < 32; r += 8)
    t[r][c] = qkv[(size_t)(s0 + r) * QKVD + 2 * DIM + c0 + c];
  __syncthreads();
  for (int r = r0; r < 32; r += 8)
    VtG[(size_t)(c0 + r) * SEQ + s0 + c] = t[c][r];
}

// ---------------------------------------------------------------------------
// 256x256 MFMA GEMM (bf16 out), depth-2 counted-vmcnt + XOR-8 swizzle.
// 512 threads = 8 waves (2M x 4N); per-wave C = 128x64 (acc[8][4]).
// LDS (dynamic, 128 KB): A dbuf 2x[256][64], B dbuf 2x[256][64] shorts.
// Same per-C-element k-order as the 128^2 kernel -> bit-identical results.
// ---------------------------------------------------------------------------
__global__ __launch_bounds__(512, 2) void mfma_gemm256(
    const USHORT* __restrict__ Ah, const USHORT* __restrict__ Bh,
    const float* __restrict__ bias, USHORT* __restrict__ Cout,
    int M, int N, int K, int lda) {
  extern __shared__ USHORT sm[];  // [0)A0 [16384)A1 [32768)B0 [49152)B1

  const int tid = threadIdx.x;
  const int l = tid & 63;
  const int w = tid >> 6;
  const int fr = l & 15;
  const int g = l >> 4;
  const int nrow = M >> 8;
  const int nwg = nrow * (N >> 8);
  const int orig = blockIdx.x;
  const int wg = (orig & 7) * (nwg >> 3) + (orig >> 3);  // XCD swizzle (nwg%8==0)
  const int row0 = (wg % nrow) << 8;
  const int col0 = (wg / nrow) << 8;
  const int wr = (w >> 2) << 7;   // 0 / 128
  const int wc = (w & 3) << 6;    // 0 / 64 / 128 / 192

  const f32x4 fz = {0.f, 0.f, 0.f, 0.f};
  f32x4 acc[8][4];
#pragma unroll
  for (int m = 0; m < 8; ++m)
#pragma unroll
    for (int n = 0; n < 4; ++n) acc[m][n] = fz;

  const int NT = K >> 6;

  // stage tile t into buffer b: 8 gload16/thread (4 A + 4 B).
  // LDS chunk u = i*512+tid -> row u>>3, slot u&7; source chunk (u&7)^(row&7).
  auto stage = [&](int t, int b) {
    const int k0 = t << 6;
#pragma unroll
    for (int i = 0; i < 4; ++i) {
      const int u = i * 512 + tid;
      const int row = u >> 3;
      const int c = (u & 7) ^ (row & 7);
      USHORT* dst = sm + (i * 512 + (w << 6)) * 8;  // + lane*16B implicit
      gload16(Ah + (size_t)(row0 + row) * lda + k0 + c * 8,
              dst + b * 16384);
      gload16(Bh + (size_t)(col0 + row) * K + k0 + c * 8,
              dst + 32768 + b * 16384);
    }
  };

  stage(0, 0);
  stage(1, 1);

  for (int t = 0; t < NT; ++t) {
    const int cur = t & 1;
    // retire tile t's 8 loads/thread; tile t+1's 8 stay in flight
    asm volatile("s_waitcnt vmcnt(8)" ::: "memory");
    __builtin_amdgcn_sched_barrier(0);
    __builtin_amdgcn_s_barrier();
    __builtin_amdgcn_sched_barrier(0);
    bf16x8 ah[2][8], bh[2][4];
#pragma unroll
    for (int ks = 0; ks < 2; ++ks) {
      const int sl = (((ks << 2) + g) ^ (fr & 7)) << 3;
#pragma unroll
      for (int m = 0; m < 8; ++m)
        ah[ks][m] = *(const bf16x8*)
            &sm[cur * 16384 + (wr + m * 16 + fr) * 64 + sl];
#pragma unroll
      for (int n = 0; n < 4; ++n)
        bh[ks][n] = *(const bf16x8*)
            &sm[32768 + cur * 16384 + (wc + n * 16 + fr) * 64 + sl];
    }
    asm volatile("s_waitcnt lgkmcnt(0)" ::: "memory");
    __builtin_amdgcn_sched_barrier(0);
    __builtin_amdgcn_s_barrier();   // all waves done reading buf[cur]
    __builtin_amdgcn_sched_barrier(0);
    const int tn = (t + 2 < NT) ? t + 2 : t;
    stage(tn, cur);
    __builtin_amdgcn_sched_barrier(0);
    __builtin_amdgcn_s_setprio(1);
#pragma unroll
    for (int ks = 0; ks < 2; ++ks)
#pragma unroll
      for (int m = 0; m < 8; ++m)
#pragma unroll
        for (int n = 0; n < 4; ++n)
          acc[m][n] = __builtin_amdgcn_mfma_f32_16x16x32_bf16(
              ah[ks][m], bh[ks][n], acc[m][n], 0, 0, 0);
    __builtin_amdgcn_s_setprio(0);
  }

  asm volatile("s_waitcnt vmcnt(0)" ::: "memory");

  float bv[4];
#pragma unroll
  for (int n = 0; n < 4; ++n) bv[n] = bias[col0 + wc + n * 16 + fr];
#pragma unroll
  for (int m = 0; m < 8; ++m)
#pragma unroll
    for (int n = 0; n < 4; ++n)
#pragma unroll
      for (int r = 0; r < 4; ++r) {
        const float v = acc[m][n][r] + bv[n];
        const int row = row0 + wr + m * 16 + g * 4 + r;
        const int col = col0 + wc + n * 16 + fr;
        Cout[(size_t)row * N + col] = f2bf(v);
      }
}

// ---------------------------------------------------------------------------
// 128x128 MFMA GEMM, depth-2 counted-vmcnt + XOR-8 swizzle (r8-proven).
// Used for the proj GEMM (N=1280: 640 blocks beats 160 at 256^2).
// ---------------------------------------------------------------------------
template <int OUTBF>
__global__ __launch_bounds__(256) void mfma_gemm(
    const USHORT* __restrict__ Ah, const USHORT* __restrict__ Bh,
    const float* __restrict__ bias, void* __restrict__ Cout,
    int M, int N, int K, int lda) {
  __shared__ __align__(16) USHORT AhL[2][8192];
  __shared__ __align__(16) USHORT BhL[2][8192];

  const int tid = threadIdx.x;
  const int l = tid & 63;
  const int w = tid >> 6;
  const int nrow = M >> 7;
  const int nwg = nrow * (N >> 7);
  const int orig = blockIdx.x;
  const int wg = (orig & 7) * (nwg >> 3) + (orig >> 3);  // XCD swizzle (nwg%8==0)
  const int row0 = (wg % nrow) << 7;
  const int col0 = (wg / nrow) << 7;
  const int wr = (w >> 1) << 6;
  const int wc = (w & 1) << 6;

  const f32x4 fz = {0.f, 0.f, 0.f, 0.f};
  f32x4 acc[4][4];
#pragma unroll
  for (int m = 0; m < 4; ++m)
#pragma unroll
    for (int n = 0; n < 4; ++n) acc[m][n] = fz;

  const int fr = l & 15;
  const int g = l >> 4;

  const int NT = K >> 6;

  auto stage = [&](int t, int b) {
    const int k0 = t << 6;
#pragma unroll
    for (int i = 0; i < 4; ++i) {
      const int u = (w * 4 + i) * 64 + l;
      const int row = u >> 3;
      const int c = (u & 7) ^ (row & 7);
      gload16(Ah + (size_t)(row0 + row) * lda + k0 + c * 8,
              &AhL[b][(w * 4 + i) * 512]);
      gload16(Bh + (size_t)(col0 + row) * K + k0 + c * 8,
              &BhL[b][(w * 4 + i) * 512]);
    }
  };

  stage(0, 0);
  stage(1, 1);

  for (int t = 0; t < NT; ++t) {
    const int cur = t & 1;
    asm volatile("s_waitcnt vmcnt(8)" ::: "memory");
    __builtin_amdgcn_sched_barrier(0);
    __builtin_amdgcn_s_barrier();
    __builtin_amdgcn_sched_barrier(0);
    bf16x8 ah[2][4], bh[2][4];
#pragma unroll
    for (int ks = 0; ks < 2; ++ks)
#pragma unroll
      for (int m = 0; m < 4; ++m) {
        const int sl = (((ks << 2) + g) ^ (fr & 7)) << 3;
        ah[ks][m] = *(const bf16x8*)&AhL[cur][(wr + m * 16 + fr) * 64 + sl];
        bh[ks][m] = *(const bf16x8*)&BhL[cur][(wc + m * 16 + fr) * 64 + sl];
      }
    asm volatile("s_waitcnt lgkmcnt(0)" ::: "memory");
    __builtin_amdgcn_sched_barrier(0);
    __builtin_amdgcn_s_barrier();
    __builtin_amdgcn_sched_barrier(0);
    const int tn = (t + 2 < NT) ? t + 2 : t;
    stage(tn, cur);
    __builtin_amdgcn_sched_barrier(0);
    __builtin_amdgcn_s_setprio(1);
#pragma unroll
    for (int ks = 0; ks < 2; ++ks)
#pragma unroll
      for (int m = 0; m < 4; ++m)
#pragma unroll
        for (int n = 0; n < 4; ++n)
          acc[m][n] = __builtin_amdgcn_mfma_f32_16x16x32_bf16(
              ah[ks][m], bh[ks][n], acc[m][n], 0, 0, 0);
    __builtin_amdgcn_s_setprio(0);
  }

  asm volatile("s_waitcnt vmcnt(0)" ::: "memory");

  float bv[4];
#pragma unroll
  for (int n = 0; n < 4; ++n) bv[n] = bias[col0 + wc + n * 16 + fr];
#pragma unroll
  for (int m = 0; m < 4; ++m)
#pragma unroll
    for (int n = 0; n < 4; ++n)
#pragma unroll
      for (int r = 0; r < 4; ++r) {
        const float v = acc[m][n][r] + bv[n];
        const int row = row0 + wr + m * 16 + (l >> 4) * 4 + r;
        const int col = col0 + wc + n * 16 + fr;
        if (OUTBF)
          ((USHORT*)Cout)[(size_t)row * N + col] = f2bf(v);
        else
          ((float*)Cout)[(size_t)row * N + col] = v;
      }
}

// ---------------------------------------------------------------------------
// RoPE in-place on bf16 qkv (q,k halves). Vectorized: 4 rotation pairs/thread.
// ---------------------------------------------------------------------------
__global__ __launch_bounds__(256) void rope_b(USHORT* __restrict__ qkv,
                                              const float* __restrict__ cosb,
                                              const float* __restrict__ sinb) {
  int idx = blockIdx.x * 256 + threadIdx.x;  // SEQ*HEADS*2*10 total
  const int d4 = (idx % 10) * 4;
  int t = idx / 10;
  const int h = t % HEADS;
  t /= HEADS;
  const int qk = t & 1;
  const int s = t >> 1;
  USHORT* base = qkv + (size_t)s * QKVD + qk * DIM + h * HD;
  const u16x4 x1 = *(const u16x4*)&base[d4];
  const u16x4 x2 = *(const u16x4*)&base[d4 + 40];
  const f32x4 c1 = *(const f32x4*)&cosb[s * HD + d4];
  const f32x4 s1 = *(const f32x4*)&sinb[s * HD + d4];
  const f32x4 c2 = *(const f32x4*)&cosb[s * HD + d4 + 40];
  const f32x4 s2 = *(const f32x4*)&sinb[s * HD + d4 + 40];
  u16x4 o1, o2;
#pragma unroll
  for (int j = 0; j < 4; ++j) {
    const float a = bf2f(x1[j]), b = bf2f(x2[j]);
    o1[j] = f2bf(a * c1[j] - b * s1[j]);
    o2[j] = f2bf(b * c2[j] + a * s2[j]);
  }
  *(u16x4*)&base[d4] = o1;
  *(u16x4*)&base[d4 + 40] = o2;
}

// ---------------------------------------------------------------------------
// 1KB zero region for global_load_lds pad sources.
// ---------------------------------------------------------------------------
__global__ void zero_ws(uint4* z) {
  z[threadIdx.x] = uint4{0u, 0u, 0u, 0u};
}

// ---------------------------------------------------------------------------
// Flash attention (r9-proven): swapped QK^T, lane-local softmax + defer-max,
// segment-affine XCD swizzle, depth-2 counted-vmcnt K/V pipeline, cvt_pk
// P-packing, P via wave-private LDS, V^T from pre-transposed VtG.
// ---------------------------------------------------------------------------
__global__ __launch_bounds__(256) void attn_mfma6(const USHORT* __restrict__ qkv,
                                                  const USHORT* __restrict__ VtG,
                                                  const USHORT* __restrict__ zbuf,
                                                  USHORT* __restrict__ aoB) {
  const int h = blockIdx.y;
  const int bx = blockIdx.x;
  const int qb = (bx & 7) * 8 + (bx >> 3);   // seg = bx&7 == XCD (id%8)
  const int s0 = qb * 128;
  const int k0g = (s0 / LSEG) * LSEG;
  const int tid = threadIdx.x;
  const int w = tid >> 6, l = tid & 63;
  const int g = l >> 4, fr = l & 15;
  const int q0 = s0 + w * 32;

  __shared__ __align__(16) USHORT Kl[2][64 * 128];
  __shared__ __align__(16) USHORT Vl[2][6144];   // 80 rows x 72 + staging tail
  __shared__ __align__(16) USHORT Pl[4][32 * 72];

  bf16x8 qb_frag[2][3];
#pragma unroll
  for (int nt2 = 0; nt2 < 2; ++nt2)
#pragma unroll
    for (int ks = 0; ks < 3; ++ks)
      qb_frag[nt2][ks] = *(const bf16x8*)
          &qkv[(size_t)(q0 + nt2 * 16 + fr) * QKVD + h * HD + ks * 32 + g * 8];

  const f32x4 fz = {0.f, 0.f, 0.f, 0.f};
  f32x4 oacc[2][5];
#pragma unroll
  for (int m = 0; m < 2; ++m)
#pragma unroll
    for (int n = 0; n < 5; ++n) oacc[m][n] = fz;
  float m_run[2] = {-3e38f, -3e38f};
  float l_run[2] = {0.f, 0.f};

  auto stageKV = [&](int kb, int b) {
    const size_t krow0 = (size_t)(k0g + kb * 64);
#pragma unroll
    for (int i = 0; i < 4; ++i) {
      const int t = (w * 4 + i) * 64 + l;
      const int row = t >> 4, c2 = t & 15, c = c2 ^ (row & 7);
      const USHORT* src =
          (c < 10) ? &qkv[(krow0 + row) * QKVD + DIM + h * HD + c * 8] : zbuf;
      gload16(src, &Kl[b][(w * 4 + i) * 512]);
    }
#pragma unroll
    for (int i = 0; i < 3; ++i) {
      const int u = (w * 3 + i) * 64 + l;
      const int s = u / 9, r8 = u - s * 9;
      const USHORT* src = (r8 < 8 && s < 80)
          ? &VtG[(size_t)(h * HD + s) * SEQ + krow0 + r8 * 8] : zbuf;
      gload16(src, &Vl[b][(w * 3 + i) * 512]);
    }
  };

  stageKV(0, 0);
  stageKV(1, 1);

  for (int kb = 0; kb < 16; ++kb) {
    const int cur = kb & 1;
    asm volatile("s_waitcnt vmcnt(7)" ::: "memory");
    __builtin_amdgcn_sched_barrier(0);
    __builtin_amdgcn_s_barrier();
    __builtin_amdgcn_sched_barrier(0);

    f32x4 sc[4][2];
#pragma unroll
    for (int m = 0; m < 4; ++m)
#pragma unroll
      for (int nt2 = 0; nt2 < 2; ++nt2) sc[m][nt2] = fz;
#pragma unroll
    for (int ks = 0; ks < 3; ++ks)
#pragma unroll
      for (int m = 0; m < 4; ++m) {
        const bf16x8 kbf = *(const bf16x8*)
            &Kl[cur][(m * 16 + fr) * 128 + ((4 * ks + g) ^ (fr & 7)) * 8];
#pragma unroll
        for (int nt2 = 0; nt2 < 2; ++nt2)
          sc[m][nt2] = __builtin_amdgcn_mfma_f32_16x16x32_bf16(
              kbf, qb_frag[nt2][ks], sc[m][nt2], 0, 0, 0);
      }

    float rmax[2];
#pragma unroll
    for (int nt2 = 0; nt2 < 2; ++nt2) {
      float mx = -3e38f;
#pragma unroll
      for (int m = 0; m < 4; ++m)
#pragma unroll
        for (int j = 0; j < 4; ++j) mx = fmaxf(mx, sc[m][nt2][j]);
      mx = fmaxf(mx, __shfl_xor(mx, 16));
      mx = fmaxf(mx, __shfl_xor(mx, 32));
      rmax[nt2] = mx;
    }
    const bool need =
        (rmax[0] > m_run[0] + DTHR) || (rmax[1] > m_run[1] + DTHR);
    if (__any(need)) {
      float fac[2];
#pragma unroll
      for (int nt2 = 0; nt2 < 2; ++nt2) {
        const float mn = fmaxf(m_run[nt2], rmax[nt2]);
        fac[nt2] = exp2f((m_run[nt2] - mn) * CSF);
        m_run[nt2] = mn;
        l_run[nt2] *= fac[nt2];
      }
#pragma unroll
      for (int mt2 = 0; mt2 < 2; ++mt2)
#pragma unroll
        for (int j = 0; j < 4; ++j) {
          const float fb = __shfl(fac[mt2], 20 * g + j);
#pragma unroll
          for (int nt = 0; nt < 5; ++nt) oacc[mt2][nt][j] *= fb;
        }
    }
#pragma unroll
    for (int nt2 = 0; nt2 < 2; ++nt2) {
      const float mcs = m_run[nt2] * CSF;
      float ps = 0.f;
#pragma unroll
      for (int m = 0; m < 4; ++m) {
        float p[4];
#pragma unroll
        for (int j = 0; j < 4; ++j) {
          p[j] = exp2f(sc[m][nt2][j] * CSF - mcs);
          ps += p[j];
        }
        const uint2v pw = {cvtpk(p[0], p[1]), cvtpk(p[2], p[3])};
        *(uint2v*)&Pl[w][(nt2 * 16 + fr) * 72 + m * 16 + g * 4] = pw;
      }
      ps += __shfl_xor(ps, 16);
      ps += __shfl_xor(ps, 32);
      l_run[nt2] += ps;
    }

#pragma unroll
    for (int ks = 0; ks < 2; ++ks) {
      bf16x8 pa[2];
#pragma unroll
      for (int mt2 = 0; mt2 < 2; ++mt2)
        pa[mt2] = *(const bf16x8*)&Pl[w][(mt2 * 16 + fr) * 72 + ks * 32 + g * 8];
#pragma unroll
      for (int nt = 0; nt < 5; ++nt) {
        const bf16x8 vb =
            *(const bf16x8*)&Vl[cur][(nt * 16 + fr) * 72 + ks * 32 + g * 8];
#pragma unroll
        for (int mt2 = 0; mt2 < 2; ++mt2)
          oacc[mt2][nt] = __builtin_amdgcn_mfma_f32_16x16x32_bf16(
              pa[mt2], vb, oacc[mt2][nt], 0, 0, 0);
      }
    }

    __builtin_amdgcn_s_barrier();
    __builtin_amdgcn_sched_barrier(0);
    const int kn = (kb + 2 < 16) ? kb + 2 : kb;
    stageKV(kn, cur);
    __builtin_amdgcn_sched_barrier(0);
  }

  asm volatile("s_waitcnt vmcnt(0)" ::: "memory");

  float linv[2][4];
#pragma unroll
  for (int mt2 = 0; mt2 < 2; ++mt2)
#pragma unroll
    for (int j = 0; j < 4; ++j)
      linv[mt2][j] = 1.f / __shfl(l_run[mt2], 20 * g + j);
#pragma unroll
  for (int mt2 = 0; mt2 < 2; ++mt2)
#pragma unroll
    for (int nt = 0; nt < 5; ++nt)
#pragma unroll
      for (int j = 0; j < 4; ++j) {
        const int row = s0 + w * 32 + mt2 * 16 + g * 4 + j;
        const int col = h * HD + nt * 16 + fr;
        aoB[(size_t)row * QKVD + col] = f2bf(oacc[mt2][nt][j] * linv[mt2][j]);
      }
}

// ---------------------------------------------------------------------------
// ws layout (bytes):
//   [0, 62914560)            qkv bf16 [8192][3840]; during attn, the V-slots
//                            (cols 2560..3839) are dead (V read via VtG) and
//                            receive the attn output bf16 -> proj A (lda=3840)
//   [62914560, 83886080)     hs bf16 [8192][1280]; after GEMM1 reused as
//                            VtG bf16 [1280][8192] (V pre-transposed)
//   [83886080, 93716480)     qkv_w^T bf16 [3840][1280]; first 1KB re-zeroed
//                            after GEMM1 -> zbuf for attn pad sources
//   [93716480, 96993280)     proj_w^T bf16 [1280][1280]
// ---------------------------------------------------------------------------
extern "C" void kernel_launch(void* const* d_in, const int* in_sizes, int n_in,
                              void* d_out, int out_size, void* d_ws,
                              size_t ws_size, hipStream_t stream) {
  const float* hs = (const float*)d_in[0];
  const float* cosb = (const float*)d_in[1];
  const float* sinb = (const float*)d_in[2];
  const float* qkv_w = (const float*)d_in[3];
  const float* qkv_b = (const float*)d_in[4];
  const float* proj_w = (const float*)d_in[5];
  const float* proj_b = (const float*)d_in[6];
  char* ws = (char*)d_ws;

  USHORT* qkvB  = (USHORT*)(ws);
  USHORT* hsB   = (USHORT*)(ws + 62914560u);
  USHORT* qkvwT = (USHORT*)(ws + 83886080u);
  USHORT* pwT   = (USHORT*)(ws + 93716480u);
  USHORT* VtG   = hsB;                        // hsB dead after GEMM1
  USHORT* zbuf  = qkvwT;                      // qkvwT dead after GEMM1
  USHORT* aoB   = qkvB + 2 * DIM;             // attn out -> dead V-slots

  // allow 128 KB dynamic LDS for the 256^2 GEMM (deterministic, no guards)
  hipFuncSetAttribute((const void*)mfma_gemm256,
                      hipFuncAttributeMaxDynamicSharedMemorySize, 131072);

  // input conversions
  conv_f2b<<<SEQ * DIM / 4 / 256, 256, 0, stream>>>(hs, hsB, SEQ * DIM / 4);
  conv_transpose<<<dim3(QKVD / 32, DIM / 32), 256, 0, stream>>>(
      qkv_w, qkvwT, DIM, QKVD);
  conv_transpose<<<dim3(DIM / 32, DIM / 32), 256, 0, stream>>>(
      proj_w, pwT, DIM, DIM);

  // 1) qkv = hs @ qkv_w + b  (bf16 out), 256^2 tile
  mfma_gemm256<<<(SEQ / 256) * (QKVD / 256), 512, 131072, stream>>>(
      hsB, qkvwT, qkv_b, qkvB, SEQ, QKVD, DIM, DIM);
  // 2) RoPE in place (q,k only), vectorized
  rope_b<<<SEQ * HEADS * 2 * 10 / 256, 256, 0, stream>>>(qkvB, cosb, sinb);
  // 2.3) pre-transpose V: VtG[c][s]  (hsB region is dead now)
  vtrans<<<dim3(DIM / 32, SEQ / 32), 256, 0, stream>>>(qkvB, VtG);
  // 2.6) zero pad-source region (qkvwT dead after GEMM1)
  zero_ws<<<1, 64, 0, stream>>>((uint4*)zbuf);
  // 3) attention -> bf16 into qkv's dead V-slots
  attn_mfma6<<<dim3(SEQ / 128, HEADS), 256, 0, stream>>>(qkvB, VtG, zbuf, aoB);
  // 4) out = attn @ proj_w + b  (f32 out) -> d_out   (A stride = QKVD)
  mfma_gemm<0><<<(SEQ / 128) * (DIM / 128), 256, 0, stream>>>(
      aoB, pwT, proj_b, d_out, SEQ, DIM, DIM, QKVD);
}

// Round 11
// 285.129 us; speedup vs baseline: 10.5186x; 1.0171x over previous
//
#include <hip/hip_runtime.h>

#define SEQ   8192
#define DIM   1280
#define HEADS 16
#define HD    80
#define LSEG  1024
#define QKVD  3840

typedef unsigned short USHORT;
typedef __attribute__((ext_vector_type(8))) short bf16x8;
typedef __attribute__((ext_vector_type(4))) float f32x4;
typedef __attribute__((ext_vector_type(4))) USHORT u16x4;
typedef __attribute__((ext_vector_type(2))) unsigned uint2v;

#define CSF  0.16129832f    // (1/sqrt(80)) * log2(e)
#define DTHR 71.554175f     // 8 / (1/sqrt(80)) : defer-max threshold in raw units

__device__ __forceinline__ USHORT f2bf(float x) {
  unsigned u = __float_as_uint(x);
  u += 0x7fffu + ((u >> 16) & 1u);
  return (USHORT)(u >> 16);
}
__device__ __forceinline__ float bf2f(USHORT b) {
  return __uint_as_float(((unsigned)b) << 16);
}
__device__ __forceinline__ void gload16(const void* g, void* l) {
  __builtin_amdgcn_global_load_lds(
      (const __attribute__((address_space(1))) void*)g,
      (__attribute__((address_space(3))) void*)l, 16, 0, 0);
}
// packs {bf16(a) -> [15:0], bf16(b) -> [31:16]}, RNE (same as f2bf)
__device__ __forceinline__ unsigned cvtpk(float a, float b) {
  unsigned d;
  asm("v_cvt_pk_bf16_f32 %0, %1, %2" : "=v"(d) : "v"(a), "v"(b));
  return d;
}

// ---------------------------------------------------------------------------
// f32 -> bf16 elementwise (4 per thread)
// ---------------------------------------------------------------------------
__global__ __launch_bounds__(256) void conv_f2b(const float* __restrict__ in,
                                                USHORT* __restrict__ out, int n4) {
  int i = blockIdx.x * 256 + threadIdx.x;
  if (i >= n4) return;
  float4 v = reinterpret_cast<const float4*>(in)[i];
  USHORT* o = out + (size_t)i * 4;
  o[0] = f2bf(v.x); o[1] = f2bf(v.y); o[2] = f2bf(v.z); o[3] = f2bf(v.w);
}

// ---------------------------------------------------------------------------
// W[K][N] f32 -> Wt[N][K] bf16. 32x32 LDS transpose.
// ---------------------------------------------------------------------------
__global__ __launch_bounds__(256) void conv_transpose(const float* __restrict__ W,
                                                      USHORT* __restrict__ Th,
                                                      int K, int N) {
  __shared__ float t[32][33];
  const int n0 = blockIdx.x * 32, k0 = blockIdx.y * 32;
  const int c = threadIdx.x & 31, r0 = threadIdx.x >> 5;
  for (int r = r0; r < 32; r += 8) t[r][c] = W[(size_t)(k0 + r) * N + n0 + c];
  __syncthreads();
  for (int r = r0; r < 32; r += 8)
    Th[(size_t)(n0 + r) * K + k0 + c] = f2bf(t[c][r]);  // = W[k0+c][n0+r]
}

// ---------------------------------------------------------------------------
// bf16 V-transpose: VtG[c][s] = qkv[s][2*DIM + c]  (c = h*80+d, 0..1279).
// ---------------------------------------------------------------------------
__global__ __launch_bounds__(256) void vtrans(const USHORT* __restrict__ qkv,
                                              USHORT* __restrict__ VtG) {
  __shared__ USHORT t[32][33];
  const int c0 = blockIdx.x * 32, s0 = blockIdx.y * 32;
  const int c = threadIdx.x & 31, r0 = threadIdx.x >> 5;
  for (int r = r0; r < 32; r += 8)
    t[r][c] = qkv[(size_t)(s0 + r) * QKVD + 2 * DIM + c0 + c];
  __syncthreads();
  for (int r = r0; r < 32; r += 8)
    VtG[(size_t)(c0 + r) * SEQ + s0 + c] = t[c][r];
}

// ---------------------------------------------------------------------------
// 256x256 MFMA GEMM (bf16 out), depth-2 counted-vmcnt + XOR-8 swizzle
// (r10-proven). 512 threads = 8 waves (2M x 4N); per-wave C = 128x64.
// ---------------------------------------------------------------------------
__global__ __launch_bounds__(512, 2) void mfma_gemm256(
    const USHORT* __restrict__ Ah, const USHORT* __restrict__ Bh,
    const float* __restrict__ bias, USHORT* __restrict__ Cout,
    int M, int N, int K, int lda) {
  extern __shared__ USHORT sm[];  // [0)A0 [16384)A1 [32768)B0 [49152)B1

  const int tid = threadIdx.x;
  const int l = tid & 63;
  const int w = tid >> 6;
  const int fr = l & 15;
  const int g = l >> 4;
  const int nrow = M >> 8;
  const int nwg = nrow * (N >> 8);
  const int orig = blockIdx.x;
  const int wg = (orig & 7) * (nwg >> 3) + (orig >> 3);  // XCD swizzle (nwg%8==0)
  const int row0 = (wg % nrow) << 8;
  const int col0 = (wg / nrow) << 8;
  const int wr = (w >> 2) << 7;   // 0 / 128
  const int wc = (w & 3) << 6;    // 0 / 64 / 128 / 192

  const f32x4 fz = {0.f, 0.f, 0.f, 0.f};
  f32x4 acc[8][4];
#pragma unroll
  for (int m = 0; m < 8; ++m)
#pragma unroll
    for (int n = 0; n < 4; ++n) acc[m][n] = fz;

  const int NT = K >> 6;

  auto stage = [&](int t, int b) {
    const int k0 = t << 6;
#pragma unroll
    for (int i = 0; i < 4; ++i) {
      const int u = i * 512 + tid;
      const int row = u >> 3;
      const int c = (u & 7) ^ (row & 7);
      USHORT* dst = sm + (i * 512 + (w << 6)) * 8;  // + lane*16B implicit
      gload16(Ah + (size_t)(row0 + row) * lda + k0 + c * 8,
              dst + b * 16384);
      gload16(Bh + (size_t)(col0 + row) * K + k0 + c * 8,
              dst + 32768 + b * 16384);
    }
  };

  stage(0, 0);
  stage(1, 1);

  for (int t = 0; t < NT; ++t) {
    const int cur = t & 1;
    asm volatile("s_waitcnt vmcnt(8)" ::: "memory");
    __builtin_amdgcn_sched_barrier(0);
    __builtin_amdgcn_s_barrier();
    __builtin_amdgcn_sched_barrier(0);
    bf16x8 ah[2][8], bh[2][4];
#pragma unroll
    for (int ks = 0; ks < 2; ++ks) {
      const int sl = (((ks << 2) + g) ^ (fr & 7)) << 3;
#pragma unroll
      for (int m = 0; m < 8; ++m)
        ah[ks][m] = *(const bf16x8*)
            &sm[cur * 16384 + (wr + m * 16 + fr) * 64 + sl];
#pragma unroll
      for (int n = 0; n < 4; ++n)
        bh[ks][n] = *(const bf16x8*)
            &sm[32768 + cur * 16384 + (wc + n * 16 + fr) * 64 + sl];
    }
    asm volatile("s_waitcnt lgkmcnt(0)" ::: "memory");
    __builtin_amdgcn_sched_barrier(0);
    __builtin_amdgcn_s_barrier();
    __builtin_amdgcn_sched_barrier(0);
    const int tn = (t + 2 < NT) ? t + 2 : t;
    stage(tn, cur);
    __builtin_amdgcn_sched_barrier(0);
    __builtin_amdgcn_s_setprio(1);
#pragma unroll
    for (int ks = 0; ks < 2; ++ks)
#pragma unroll
      for (int m = 0; m < 8; ++m)
#pragma unroll
        for (int n = 0; n < 4; ++n)
          acc[m][n] = __builtin_amdgcn_mfma_f32_16x16x32_bf16(
              ah[ks][m], bh[ks][n], acc[m][n], 0, 0, 0);
    __builtin_amdgcn_s_setprio(0);
  }

  asm volatile("s_waitcnt vmcnt(0)" ::: "memory");

  float bv[4];
#pragma unroll
  for (int n = 0; n < 4; ++n) bv[n] = bias[col0 + wc + n * 16 + fr];
#pragma unroll
  for (int m = 0; m < 8; ++m)
#pragma unroll
    for (int n = 0; n < 4; ++n)
#pragma unroll
      for (int r = 0; r < 4; ++r) {
        const float v = acc[m][n][r] + bv[n];
        const int row = row0 + wr + m * 16 + g * 4 + r;
        const int col = col0 + wc + n * 16 + fr;
        Cout[(size_t)row * N + col] = f2bf(v);
      }
}

// ---------------------------------------------------------------------------
// 128x128 MFMA GEMM, depth-2 counted-vmcnt + XOR-8 swizzle (r8-proven).
// Used for the proj GEMM (N=1280: 640 blocks beats 160 at 256^2).
// ---------------------------------------------------------------------------
template <int OUTBF>
__global__ __launch_bounds__(256) void mfma_gemm(
    const USHORT* __restrict__ Ah, const USHORT* __restrict__ Bh,
    const float* __restrict__ bias, void* __restrict__ Cout,
    int M, int N, int K, int lda) {
  __shared__ __align__(16) USHORT AhL[2][8192];
  __shared__ __align__(16) USHORT BhL[2][8192];

  const int tid = threadIdx.x;
  const int l = tid & 63;
  const int w = tid >> 6;
  const int nrow = M >> 7;
  const int nwg = nrow * (N >> 7);
  const int orig = blockIdx.x;
  const int wg = (orig & 7) * (nwg >> 3) + (orig >> 3);  // XCD swizzle (nwg%8==0)
  const int row0 = (wg % nrow) << 7;
  const int col0 = (wg / nrow) << 7;
  const int wr = (w >> 1) << 6;
  const int wc = (w & 1) << 6;

  const f32x4 fz = {0.f, 0.f, 0.f, 0.f};
  f32x4 acc[4][4];
#pragma unroll
  for (int m = 0; m < 4; ++m)
#pragma unroll
    for (int n = 0; n < 4; ++n) acc[m][n] = fz;

  const int fr = l & 15;
  const int g = l >> 4;

  const int NT = K >> 6;

  auto stage = [&](int t, int b) {
    const int k0 = t << 6;
#pragma unroll
    for (int i = 0; i < 4; ++i) {
      const int u = (w * 4 + i) * 64 + l;
      const int row = u >> 3;
      const int c = (u & 7) ^ (row & 7);
      gload16(Ah + (size_t)(row0 + row) * lda + k0 + c * 8,
              &AhL[b][(w * 4 + i) * 512]);
      gload16(Bh + (size_t)(col0 + row) * K + k0 + c * 8,
              &BhL[b][(w * 4 + i) * 512]);
    }
  };

  stage(0, 0);
  stage(1, 1);

  for (int t = 0; t < NT; ++t) {
    const int cur = t & 1;
    asm volatile("s_waitcnt vmcnt(8)" ::: "memory");
    __builtin_amdgcn_sched_barrier(0);
    __builtin_amdgcn_s_barrier();
    __builtin_amdgcn_sched_barrier(0);
    bf16x8 ah[2][4], bh[2][4];
#pragma unroll
    for (int ks = 0; ks < 2; ++ks)
#pragma unroll
      for (int m = 0; m < 4; ++m) {
        const int sl = (((ks << 2) + g) ^ (fr & 7)) << 3;
        ah[ks][m] = *(const bf16x8*)&AhL[cur][(wr + m * 16 + fr) * 64 + sl];
        bh[ks][m] = *(const bf16x8*)&BhL[cur][(wc + m * 16 + fr) * 64 + sl];
      }
    asm volatile("s_waitcnt lgkmcnt(0)" ::: "memory");
    __builtin_amdgcn_sched_barrier(0);
    __builtin_amdgcn_s_barrier();
    __builtin_amdgcn_sched_barrier(0);
    const int tn = (t + 2 < NT) ? t + 2 : t;
    stage(tn, cur);
    __builtin_amdgcn_sched_barrier(0);
    __builtin_amdgcn_s_setprio(1);
#pragma unroll
    for (int ks = 0; ks < 2; ++ks)
#pragma unroll
      for (int m = 0; m < 4; ++m)
#pragma unroll
        for (int n = 0; n < 4; ++n)
          acc[m][n] = __builtin_amdgcn_mfma_f32_16x16x32_bf16(
              ah[ks][m], bh[ks][n], acc[m][n], 0, 0, 0);
    __builtin_amdgcn_s_setprio(0);
  }

  asm volatile("s_waitcnt vmcnt(0)" ::: "memory");

  float bv[4];
#pragma unroll
  for (int n = 0; n < 4; ++n) bv[n] = bias[col0 + wc + n * 16 + fr];
#pragma unroll
  for (int m = 0; m < 4; ++m)
#pragma unroll
    for (int n = 0; n < 4; ++n)
#pragma unroll
      for (int r = 0; r < 4; ++r) {
        const float v = acc[m][n][r] + bv[n];
        const int row = row0 + wr + m * 16 + (l >> 4) * 4 + r;
        const int col = col0 + wc + n * 16 + fr;
        if (OUTBF)
          ((USHORT*)Cout)[(size_t)row * N + col] = f2bf(v);
        else
          ((float*)Cout)[(size_t)row * N + col] = v;
      }
}

// ---------------------------------------------------------------------------
// RoPE in-place on bf16 qkv (q,k halves). Vectorized: 4 rotation pairs/thread.
// ---------------------------------------------------------------------------
__global__ __launch_bounds__(256) void rope_b(USHORT* __restrict__ qkv,
                                              const float* __restrict__ cosb,
                                              const float* __restrict__ sinb) {
  int idx = blockIdx.x * 256 + threadIdx.x;  // SEQ*HEADS*2*10 total
  const int d4 = (idx % 10) * 4;
  int t = idx / 10;
  const int h = t % HEADS;
  t /= HEADS;
  const int qk = t & 1;
  const int s = t >> 1;
  USHORT* base = qkv + (size_t)s * QKVD + qk * DIM + h * HD;
  const u16x4 x1 = *(const u16x4*)&base[d4];
  const u16x4 x2 = *(const u16x4*)&base[d4 + 40];
  const f32x4 c1 = *(const f32x4*)&cosb[s * HD + d4];
  const f32x4 s1 = *(const f32x4*)&sinb[s * HD + d4];
  const f32x4 c2 = *(const f32x4*)&cosb[s * HD + d4 + 40];
  const f32x4 s2 = *(const f32x4*)&sinb[s * HD + d4 + 40];
  u16x4 o1, o2;
#pragma unroll
  for (int j = 0; j < 4; ++j) {
    const float a = bf2f(x1[j]), b = bf2f(x2[j]);
    o1[j] = f2bf(a * c1[j] - b * s1[j]);
    o2[j] = f2bf(b * c2[j] + a * s2[j]);
  }
  *(u16x4*)&base[d4] = o1;
  *(u16x4*)&base[d4 + 40] = o2;
}

// ---------------------------------------------------------------------------
// 1KB zero region for global_load_lds pad sources.
// ---------------------------------------------------------------------------
__global__ void zero_ws(uint4* z) {
  z[threadIdx.x] = uint4{0u, 0u, 0u, 0u};
}

// ---------------------------------------------------------------------------
// Flash attention v8: r9 core with CONFLICT-FREE V/P LDS layouts.
// Vl: [96 d-rows][64 keys] shorts, XOR-8 swizzle (slot u&7 holds source
//     chunk (u&7)^(row&7); pre-swizzled VtG source; rows 80..95 pad, unread).
// Pl: per-wave [32 q][64 keys], same XOR-8 (write slot (2m+(g>>1))^(fr&7),
//     read slot (4ks+g)^(fr&7)) -> b128 reads match the GEMM's 0-conflict
//     pattern. P values and MFMA k-order unchanged -> bit-identical output.
// ---------------------------------------------------------------------------
__global__ __launch_bounds__(256) void attn_mfma7(const USHORT* __restrict__ qkv,
                                                  const USHORT* __restrict__ VtG,
                                                  const USHORT* __restrict__ zbuf,
                                                  USHORT* __restrict__ aoB) {
  const int h = blockIdx.y;
  const int bx = blockIdx.x;
  const int qb = (bx & 7) * 8 + (bx >> 3);   // seg = bx&7 == XCD (id%8)
  const int s0 = qb * 128;
  const int k0g = (s0 / LSEG) * LSEG;
  const int tid = threadIdx.x;
  const int w = tid >> 6, l = tid & 63;
  const int g = l >> 4, fr = l & 15;
  const int q0 = s0 + w * 32;

  __shared__ __align__(16) USHORT Kl[2][64 * 128];
  __shared__ __align__(16) USHORT Vl[2][96 * 64];
  __shared__ __align__(16) USHORT Pl[4][32 * 64];

  bf16x8 qb_frag[2][3];
#pragma unroll
  for (int nt2 = 0; nt2 < 2; ++nt2)
#pragma unroll
    for (int ks = 0; ks < 3; ++ks)
      qb_frag[nt2][ks] = *(const bf16x8*)
          &qkv[(size_t)(q0 + nt2 * 16 + fr) * QKVD + h * HD + ks * 32 + g * 8];

  const f32x4 fz = {0.f, 0.f, 0.f, 0.f};
  f32x4 oacc[2][5];
#pragma unroll
  for (int m = 0; m < 2; ++m)
#pragma unroll
    for (int n = 0; n < 5; ++n) oacc[m][n] = fz;
  float m_run[2] = {-3e38f, -3e38f};
  float l_run[2] = {0.f, 0.f};

  // stage KV tile kb into buffer b: 7 gload16 per wave (4 K + 3 V)
  auto stageKV = [&](int kb, int b) {
    const size_t krow0 = (size_t)(k0g + kb * 64);
#pragma unroll
    for (int i = 0; i < 4; ++i) {
      const int t = (w * 4 + i) * 64 + l;
      const int row = t >> 4, c2 = t & 15, c = c2 ^ (row & 7);
      const USHORT* src =
          (c < 10) ? &qkv[(krow0 + row) * QKVD + DIM + h * HD + c * 8] : zbuf;
      gload16(src, &Kl[b][(w * 4 + i) * 512]);
    }
#pragma unroll
    for (int i = 0; i < 3; ++i) {
      const int u = (w * 3 + i) * 64 + l;   // chunk index 0..767
      const int row = u >> 3;               // d-dim 0..95
      const int c = (u & 7) ^ (row & 7);
      const USHORT* src = (row < 80)
          ? &VtG[(size_t)(h * HD + row) * SEQ + krow0 + c * 8] : zbuf;
      gload16(src, &Vl[b][(w * 3 + i) * 512]);
    }
  };

  stageKV(0, 0);
  stageKV(1, 1);

  for (int kb = 0; kb < 16; ++kb) {
    const int cur = kb & 1;
    asm volatile("s_waitcnt vmcnt(7)" ::: "memory");
    __builtin_amdgcn_sched_barrier(0);
    __builtin_amdgcn_s_barrier();
    __builtin_amdgcn_sched_barrier(0);

    // ---- QK^T: S^T[64 keys][32 q]; lane holds keys {16m+4g+j}, q=16nt2+fr --
    f32x4 sc[4][2];
#pragma unroll
    for (int m = 0; m < 4; ++m)
#pragma unroll
      for (int nt2 = 0; nt2 < 2; ++nt2) sc[m][nt2] = fz;
#pragma unroll
    for (int ks = 0; ks < 3; ++ks)
#pragma unroll
      for (int m = 0; m < 4; ++m) {
        const bf16x8 kbf = *(const bf16x8*)
            &Kl[cur][(m * 16 + fr) * 128 + ((4 * ks + g) ^ (fr & 7)) * 8];
#pragma unroll
        for (int nt2 = 0; nt2 < 2; ++nt2)
          sc[m][nt2] = __builtin_amdgcn_mfma_f32_16x16x32_bf16(
              kbf, qb_frag[nt2][ks], sc[m][nt2], 0, 0, 0);
      }

    // ---- lane-local online softmax with defer-max ----
    float rmax[2];
#pragma unroll
    for (int nt2 = 0; nt2 < 2; ++nt2) {
      float mx = -3e38f;
#pragma unroll
      for (int m = 0; m < 4; ++m)
#pragma unroll
        for (int j = 0; j < 4; ++j) mx = fmaxf(mx, sc[m][nt2][j]);
      mx = fmaxf(mx, __shfl_xor(mx, 16));
      mx = fmaxf(mx, __shfl_xor(mx, 32));
      rmax[nt2] = mx;
    }
    const bool need =
        (rmax[0] > m_run[0] + DTHR) || (rmax[1] > m_run[1] + DTHR);
    if (__any(need)) {
      float fac[2];
#pragma unroll
      for (int nt2 = 0; nt2 < 2; ++nt2) {
        const float mn = fmaxf(m_run[nt2], rmax[nt2]);
        fac[nt2] = exp2f((m_run[nt2] - mn) * CSF);
        m_run[nt2] = mn;
        l_run[nt2] *= fac[nt2];
      }
#pragma unroll
      for (int mt2 = 0; mt2 < 2; ++mt2)
#pragma unroll
        for (int j = 0; j < 4; ++j) {
          const float fb = __shfl(fac[mt2], 20 * g + j);
#pragma unroll
          for (int nt = 0; nt < 5; ++nt) oacc[mt2][nt][j] *= fb;
        }
    }
#pragma unroll
    for (int nt2 = 0; nt2 < 2; ++nt2) {
      const float mcs = m_run[nt2] * CSF;
      float ps = 0.f;
#pragma unroll
      for (int m = 0; m < 4; ++m) {
        float p[4];
#pragma unroll
        for (int j = 0; j < 4; ++j) {
          p[j] = exp2f(sc[m][nt2][j] * CSF - mcs);
          ps += p[j];
        }
        const uint2v pw = {cvtpk(p[0], p[1]), cvtpk(p[2], p[3])};
        // keys 16m+4g..+3 -> chunk 2m+(g>>1), within-chunk (g&1)*4
        const int chunk = 2 * m + (g >> 1);
        *(uint2v*)&Pl[w][(nt2 * 16 + fr) * 64 + ((chunk ^ (fr & 7)) << 3) +
                         ((g & 1) << 2)] = pw;
      }
      ps += __shfl_xor(ps, 16);
      ps += __shfl_xor(ps, 32);
      l_run[nt2] += ps;
    }

    // ---- PV: O[32q][80d] += P @ V (XOR-slot layouts on both operands) ----
#pragma unroll
    for (int ks = 0; ks < 2; ++ks) {
      const int sl = (((ks << 2) + g) ^ (fr & 7)) << 3;
      bf16x8 pa[2];
#pragma unroll
      for (int mt2 = 0; mt2 < 2; ++mt2)
        pa[mt2] = *(const bf16x8*)&Pl[w][(mt2 * 16 + fr) * 64 + sl];
#pragma unroll
      for (int nt = 0; nt < 5; ++nt) {
        const bf16x8 vb = *(const bf16x8*)&Vl[cur][(nt * 16 + fr) * 64 + sl];
#pragma unroll
        for (int mt2 = 0; mt2 < 2; ++mt2)
          oacc[mt2][nt] = __builtin_amdgcn_mfma_f32_16x16x32_bf16(
              pa[mt2], vb, oacc[mt2][nt], 0, 0, 0);
      }
    }

    __builtin_amdgcn_s_barrier();
    __builtin_amdgcn_sched_barrier(0);
    const int kn = (kb + 2 < 16) ? kb + 2 : kb;
    stageKV(kn, cur);
    __builtin_amdgcn_sched_barrier(0);
  }

  asm volatile("s_waitcnt vmcnt(0)" ::: "memory");

  float linv[2][4];
#pragma unroll
  for (int mt2 = 0; mt2 < 2; ++mt2)
#pragma unroll
    for (int j = 0; j < 4; ++j)
      linv[mt2][j] = 1.f / __shfl(l_run[mt2], 20 * g + j);
#pragma unroll
  for (int mt2 = 0; mt2 < 2; ++mt2)
#pragma unroll
    for (int nt = 0; nt < 5; ++nt)
#pragma unroll
      for (int j = 0; j < 4; ++j) {
        const int row = s0 + w * 32 + mt2 * 16 + g * 4 + j;
        const int col = h * HD + nt * 16 + fr;
        aoB[(size_t)row * QKVD + col] = f2bf(oacc[mt2][nt][j] * linv[mt2][j]);
      }
}

// ---------------------------------------------------------------------------
// ws layout (bytes):
//   [0, 62914560)            qkv bf16 [8192][3840]; during attn, the V-slots
//                            (cols 2560..3839) are dead (V read via VtG) and
//                            receive the attn output bf16 -> proj A (lda=3840)
//   [62914560, 83886080)     hs bf16 [8192][1280]; after GEMM1 reused as
//                            VtG bf16 [1280][8192] (V pre-transposed)
//   [83886080, 93716480)     qkv_w^T bf16 [3840][1280]; first 1KB re-zeroed
//                            after GEMM1 -> zbuf for attn pad sources
//   [93716480, 96993280)     proj_w^T bf16 [1280][1280]
// ---------------------------------------------------------------------------
extern "C" void kernel_launch(void* const* d_in, const int* in_sizes, int n_in,
                              void* d_out, int out_size, void* d_ws,
                              size_t ws_size, hipStream_t stream) {
  const float* hs = (const float*)d_in[0];
  const float* cosb = (const float*)d_in[1];
  const float* sinb = (const float*)d_in[2];
  const float* qkv_w = (const float*)d_in[3];
  const float* qkv_b = (const float*)d_in[4];
  const float* proj_w = (const float*)d_in[5];
  const float* proj_b = (const float*)d_in[6];
  char* ws = (char*)d_ws;

  USHORT* qkvB  = (USHORT*)(ws);
  USHORT* hsB   = (USHORT*)(ws + 62914560u);
  USHORT* qkvwT = (USHORT*)(ws + 83886080u);
  USHORT* pwT   = (USHORT*)(ws + 93716480u);
  USHORT* VtG   = hsB;                        // hsB dead after GEMM1
  USHORT* zbuf  = qkvwT;                      // qkvwT dead after GEMM1
  USHORT* aoB   = qkvB + 2 * DIM;             // attn out -> dead V-slots

  // allow 128 KB dynamic LDS for the 256^2 GEMM (deterministic, no guards)
  hipFuncSetAttribute((const void*)mfma_gemm256,
                      hipFuncAttributeMaxDynamicSharedMemorySize, 131072);

  // input conversions
  conv_f2b<<<SEQ * DIM / 4 / 256, 256, 0, stream>>>(hs, hsB, SEQ * DIM / 4);
  conv_transpose<<<dim3(QKVD / 32, DIM / 32), 256, 0, stream>>>(
      qkv_w, qkvwT, DIM, QKVD);
  conv_transpose<<<dim3(DIM / 32, DIM / 32), 256, 0, stream>>>(
      proj_w, pwT, DIM, DIM);

  // 1) qkv = hs @ qkv_w + b  (bf16 out), 256^2 tile
  mfma_gemm256<<<(SEQ / 256) * (QKVD / 256), 512, 131072, stream>>>(
      hsB, qkvwT, qkv_b, qkvB, SEQ, QKVD, DIM, DIM);
  // 2) RoPE in place (q,k only), vectorized
  rope_b<<<SEQ * HEADS * 2 * 10 / 256, 256, 0, stream>>>(qkvB, cosb, sinb);
  // 2.3) pre-transpose V: VtG[c][s]  (hsB region is dead now)
  vtrans<<<dim3(DIM / 32, SEQ / 32), 256, 0, stream>>>(qkvB, VtG);
  // 2.6) zero pad-source region (qkvwT dead after GEMM1)
  zero_ws<<<1, 64, 0, stream>>>((uint4*)zbuf);
  // 3) attention -> bf16 into qkv's dead V-slots
  attn_mfma7<<<dim3(SEQ / 128, HEADS), 256, 0, stream>>>(qkvB, VtG, zbuf, aoB);
  // 4) out = attn @ proj_w + b  (f32 out) -> d_out   (A stride = QKVD)
  mfma_gemm<0><<<(SEQ / 128) * (DIM / 128), 256, 0, stream>>>(
      aoB, pwT, proj_b, d_out, SEQ, DIM, DIM, QKVD);
}

// Round 12
// 274.832 us; speedup vs baseline: 10.9127x; 1.0375x over previous
//
#include <hip/hip_runtime.h>

#define SEQ   8192
#define DIM   1280
#define HEADS 16
#define HD    80
#define LSEG  1024
#define QKVD  3840

typedef unsigned short USHORT;
typedef __attribute__((ext_vector_type(8))) short bf16x8;
typedef __attribute__((ext_vector_type(4))) float f32x4;
typedef __attribute__((ext_vector_type(4))) USHORT u16x4;
typedef __attribute__((ext_vector_type(4))) int i32x4;

#define CSF  0.16129832f    // (1/sqrt(80)) * log2(e)
#define DTHR 71.554175f     // 8 / (1/sqrt(80)) : defer-max threshold in raw units

__device__ __forceinline__ USHORT f2bf(float x) {
  unsigned u = __float_as_uint(x);
  u += 0x7fffu + ((u >> 16) & 1u);
  return (USHORT)(u >> 16);
}
__device__ __forceinline__ float bf2f(USHORT b) {
  return __uint_as_float(((unsigned)b) << 16);
}
__device__ __forceinline__ void gload16(const void* g, void* l) {
  __builtin_amdgcn_global_load_lds(
      (const __attribute__((address_space(1))) void*)g,
      (__attribute__((address_space(3))) void*)l, 16, 0, 0);
}
// packs {bf16(a) -> [15:0], bf16(b) -> [31:16]}, RNE (same as f2bf)
__device__ __forceinline__ unsigned cvtpk(float a, float b) {
  unsigned d;
  asm("v_cvt_pk_bf16_f32 %0, %1, %2" : "=v"(d) : "v"(a), "v"(b));
  return d;
}

// ---------------------------------------------------------------------------
// f32 -> bf16 elementwise (4 per thread)
// ---------------------------------------------------------------------------
__global__ __launch_bounds__(256) void conv_f2b(const float* __restrict__ in,
                                                USHORT* __restrict__ out, int n4) {
  int i = blockIdx.x * 256 + threadIdx.x;
  if (i >= n4) return;
  float4 v = reinterpret_cast<const float4*>(in)[i];
  USHORT* o = out + (size_t)i * 4;
  o[0] = f2bf(v.x); o[1] = f2bf(v.y); o[2] = f2bf(v.z); o[3] = f2bf(v.w);
}

// ---------------------------------------------------------------------------
// W[K][N] f32 -> Wt[N][K] bf16. 32x32 LDS transpose.
// ---------------------------------------------------------------------------
__global__ __launch_bounds__(256) void conv_transpose(const float* __restrict__ W,
                                                      USHORT* __restrict__ Th,
                                                      int K, int N) {
  __shared__ float t[32][33];
  const int n0 = blockIdx.x * 32, k0 = blockIdx.y * 32;
  const int c = threadIdx.x & 31, r0 = threadIdx.x >> 5;
  for (int r = r0; r < 32; r += 8) t[r][c] = W[(size_t)(k0 + r) * N + n0 + c];
  __syncthreads();
  for (int r = r0; r < 32; r += 8)
    Th[(size_t)(n0 + r) * K + k0 + c] = f2bf(t[c][r]);  // = W[k0+c][n0+r]
}

// ---------------------------------------------------------------------------
// bf16 V-transpose with zero-shuffle key permutation baked in:
// VtG[d][64-block + kinv(p&63)] = V[p][d], where kinv is the inverse of
// kappa(s) = (s&0x23)|((s&4)<<2)|((s&0x18)>>1) (bits 2,3,4 3-cycled).
// Attention then consumes slot s as key kappa(s) -- which is exactly the
// key order of the lane-local packed P registers (no P LDS round-trip).
// ---------------------------------------------------------------------------
__global__ __launch_bounds__(256) void vtrans(const USHORT* __restrict__ qkv,
                                              USHORT* __restrict__ VtG) {
  __shared__ USHORT t[32][33];
  const int c0 = blockIdx.x * 32, s0 = blockIdx.y * 32;
  const int c = threadIdx.x & 31, r0 = threadIdx.x >> 5;
  for (int r = r0; r < 32; r += 8)
    t[r][c] = qkv[(size_t)(s0 + r) * QKVD + 2 * DIM + c0 + c];
  __syncthreads();
  const int pc = (s0 & 32) | c;
  const int sc = (pc & 0x23) | ((pc & 0x10) >> 2) | ((pc & 0x0C) << 1);  // kinv
  const size_t col = (size_t)(s0 & ~63) + sc;
  for (int r = r0; r < 32; r += 8)
    VtG[(size_t)(c0 + r) * SEQ + col] = t[c][r];
}

// ---------------------------------------------------------------------------
// 256x256 MFMA GEMM (bf16 out), depth-2 counted-vmcnt + XOR-8 swizzle
// (r10-proven). 512 threads = 8 waves (2M x 4N); per-wave C = 128x64.
// ---------------------------------------------------------------------------
__global__ __launch_bounds__(512, 2) void mfma_gemm256(
    const USHORT* __restrict__ Ah, const USHORT* __restrict__ Bh,
    const float* __restrict__ bias, USHORT* __restrict__ Cout,
    int M, int N, int K, int lda) {
  extern __shared__ USHORT sm[];  // [0)A0 [16384)A1 [32768)B0 [49152)B1

  const int tid = threadIdx.x;
  const int l = tid & 63;
  const int w = tid >> 6;
  const int fr = l & 15;
  const int g = l >> 4;
  const int nrow = M >> 8;
  const int nwg = nrow * (N >> 8);
  const int orig = blockIdx.x;
  const int wg = (orig & 7) * (nwg >> 3) + (orig >> 3);  // XCD swizzle (nwg%8==0)
  const int row0 = (wg % nrow) << 8;
  const int col0 = (wg / nrow) << 8;
  const int wr = (w >> 2) << 7;   // 0 / 128
  const int wc = (w & 3) << 6;    // 0 / 64 / 128 / 192

  const f32x4 fz = {0.f, 0.f, 0.f, 0.f};
  f32x4 acc[8][4];
#pragma unroll
  for (int m = 0; m < 8; ++m)
#pragma unroll
    for (int n = 0; n < 4; ++n) acc[m][n] = fz;

  const int NT = K >> 6;

  auto stage = [&](int t, int b) {
    const int k0 = t << 6;
#pragma unroll
    for (int i = 0; i < 4; ++i) {
      const int u = i * 512 + tid;
      const int row = u >> 3;
      const int c = (u & 7) ^ (row & 7);
      USHORT* dst = sm + (i * 512 + (w << 6)) * 8;  // + lane*16B implicit
      gload16(Ah + (size_t)(row0 + row) * lda + k0 + c * 8,
              dst + b * 16384);
      gload16(Bh + (size_t)(col0 + row) * K + k0 + c * 8,
              dst + 32768 + b * 16384);
    }
  };

  stage(0, 0);
  stage(1, 1);

  for (int t = 0; t < NT; ++t) {
    const int cur = t & 1;
    asm volatile("s_waitcnt vmcnt(8)" ::: "memory");
    __builtin_amdgcn_sched_barrier(0);
    __builtin_amdgcn_s_barrier();
    __builtin_amdgcn_sched_barrier(0);
    bf16x8 ah[2][8], bh[2][4];
#pragma unroll
    for (int ks = 0; ks < 2; ++ks) {
      const int sl = (((ks << 2) + g) ^ (fr & 7)) << 3;
#pragma unroll
      for (int m = 0; m < 8; ++m)
        ah[ks][m] = *(const bf16x8*)
            &sm[cur * 16384 + (wr + m * 16 + fr) * 64 + sl];
#pragma unroll
      for (int n = 0; n < 4; ++n)
        bh[ks][n] = *(const bf16x8*)
            &sm[32768 + cur * 16384 + (wc + n * 16 + fr) * 64 + sl];
    }
    asm volatile("s_waitcnt lgkmcnt(0)" ::: "memory");
    __builtin_amdgcn_sched_barrier(0);
    __builtin_amdgcn_s_barrier();
    __builtin_amdgcn_sched_barrier(0);
    const int tn = (t + 2 < NT) ? t + 2 : t;
    stage(tn, cur);
    __builtin_amdgcn_sched_barrier(0);
    __builtin_amdgcn_s_setprio(1);
#pragma unroll
    for (int ks = 0; ks < 2; ++ks)
#pragma unroll
      for (int m = 0; m < 8; ++m)
#pragma unroll
        for (int n = 0; n < 4; ++n)
          acc[m][n] = __builtin_amdgcn_mfma_f32_16x16x32_bf16(
              ah[ks][m], bh[ks][n], acc[m][n], 0, 0, 0);
    __builtin_amdgcn_s_setprio(0);
  }

  asm volatile("s_waitcnt vmcnt(0)" ::: "memory");

  float bv[4];
#pragma unroll
  for (int n = 0; n < 4; ++n) bv[n] = bias[col0 + wc + n * 16 + fr];
#pragma unroll
  for (int m = 0; m < 8; ++m)
#pragma unroll
    for (int n = 0; n < 4; ++n)
#pragma unroll
      for (int r = 0; r < 4; ++r) {
        const float v = acc[m][n][r] + bv[n];
        const int row = row0 + wr + m * 16 + g * 4 + r;
        const int col = col0 + wc + n * 16 + fr;
        Cout[(size_t)row * N + col] = f2bf(v);
      }
}

// ---------------------------------------------------------------------------
// 128x128 MFMA GEMM, depth-2 counted-vmcnt + XOR-8 swizzle (r8-proven).
// Used for the proj GEMM (N=1280: 640 blocks beats 160 at 256^2).
// ---------------------------------------------------------------------------
template <int OUTBF>
__global__ __launch_bounds__(256) void mfma_gemm(
    const USHORT* __restrict__ Ah, const USHORT* __restrict__ Bh,
    const float* __restrict__ bias, void* __restrict__ Cout,
    int M, int N, int K, int lda) {
  __shared__ __align__(16) USHORT AhL[2][8192];
  __shared__ __align__(16) USHORT BhL[2][8192];

  const int tid = threadIdx.x;
  const int l = tid & 63;
  const int w = tid >> 6;
  const int nrow = M >> 7;
  const int nwg = nrow * (N >> 7);
  const int orig = blockIdx.x;
  const int wg = (orig & 7) * (nwg >> 3) + (orig >> 3);  // XCD swizzle (nwg%8==0)
  const int row0 = (wg % nrow) << 7;
  const int col0 = (wg / nrow) << 7;
  const int wr = (w >> 1) << 6;
  const int wc = (w & 1) << 6;

  const f32x4 fz = {0.f, 0.f, 0.f, 0.f};
  f32x4 acc[4][4];
#pragma unroll
  for (int m = 0; m < 4; ++m)
#pragma unroll
    for (int n = 0; n < 4; ++n) acc[m][n] = fz;

  const int fr = l & 15;
  const int g = l >> 4;

  const int NT = K >> 6;

  auto stage = [&](int t, int b) {
    const int k0 = t << 6;
#pragma unroll
    for (int i = 0; i < 4; ++i) {
      const int u = (w * 4 + i) * 64 + l;
      const int row = u >> 3;
      const int c = (u & 7) ^ (row & 7);
      gload16(Ah + (size_t)(row0 + row) * lda + k0 + c * 8,
              &AhL[b][(w * 4 + i) * 512]);
      gload16(Bh + (size_t)(col0 + row) * K + k0 + c * 8,
              &BhL[b][(w * 4 + i) * 512]);
    }
  };

  stage(0, 0);
  stage(1, 1);

  for (int t = 0; t < NT; ++t) {
    const int cur = t & 1;
    asm volatile("s_waitcnt vmcnt(8)" ::: "memory");
    __builtin_amdgcn_sched_barrier(0);
    __builtin_amdgcn_s_barrier();
    __builtin_amdgcn_sched_barrier(0);
    bf16x8 ah[2][4], bh[2][4];
#pragma unroll
    for (int ks = 0; ks < 2; ++ks)
#pragma unroll
      for (int m = 0; m < 4; ++m) {
        const int sl = (((ks << 2) + g) ^ (fr & 7)) << 3;
        ah[ks][m] = *(const bf16x8*)&AhL[cur][(wr + m * 16 + fr) * 64 + sl];
        bh[ks][m] = *(const bf16x8*)&BhL[cur][(wc + m * 16 + fr) * 64 + sl];
      }
    asm volatile("s_waitcnt lgkmcnt(0)" ::: "memory");
    __builtin_amdgcn_sched_barrier(0);
    __builtin_amdgcn_s_barrier();
    __builtin_amdgcn_sched_barrier(0);
    const int tn = (t + 2 < NT) ? t + 2 : t;
    stage(tn, cur);
    __builtin_amdgcn_sched_barrier(0);
    __builtin_amdgcn_s_setprio(1);
#pragma unroll
    for (int ks = 0; ks < 2; ++ks)
#pragma unroll
      for (int m = 0; m < 4; ++m)
#pragma unroll
        for (int n = 0; n < 4; ++n)
          acc[m][n] = __builtin_amdgcn_mfma_f32_16x16x32_bf16(
              ah[ks][m], bh[ks][n], acc[m][n], 0, 0, 0);
    __builtin_amdgcn_s_setprio(0);
  }

  asm volatile("s_waitcnt vmcnt(0)" ::: "memory");

  float bv[4];
#pragma unroll
  for (int n = 0; n < 4; ++n) bv[n] = bias[col0 + wc + n * 16 + fr];
#pragma unroll
  for (int m = 0; m < 4; ++m)
#pragma unroll
    for (int n = 0; n < 4; ++n)
#pragma unroll
      for (int r = 0; r < 4; ++r) {
        const float v = acc[m][n][r] + bv[n];
        const int row = row0 + wr + m * 16 + (l >> 4) * 4 + r;
        const int col = col0 + wc + n * 16 + fr;
        if (OUTBF)
          ((USHORT*)Cout)[(size_t)row * N + col] = f2bf(v);
        else
          ((float*)Cout)[(size_t)row * N + col] = v;
      }
}

// ---------------------------------------------------------------------------
// RoPE in-place on bf16 qkv (q,k halves). Vectorized: 4 rotation pairs/thread.
// ---------------------------------------------------------------------------
__global__ __launch_bounds__(256) void rope_b(USHORT* __restrict__ qkv,
                                              const float* __restrict__ cosb,
                                              const float* __restrict__ sinb) {
  int idx = blockIdx.x * 256 + threadIdx.x;  // SEQ*HEADS*2*10 total
  const int d4 = (idx % 10) * 4;
  int t = idx / 10;
  const int h = t % HEADS;
  t /= HEADS;
  const int qk = t & 1;
  const int s = t >> 1;
  USHORT* base = qkv + (size_t)s * QKVD + qk * DIM + h * HD;
  const u16x4 x1 = *(const u16x4*)&base[d4];
  const u16x4 x2 = *(const u16x4*)&base[d4 + 40];
  const f32x4 c1 = *(const f32x4*)&cosb[s * HD + d4];
  const f32x4 s1 = *(const f32x4*)&sinb[s * HD + d4];
  const f32x4 c2 = *(const f32x4*)&cosb[s * HD + d4 + 40];
  const f32x4 s2 = *(const f32x4*)&sinb[s * HD + d4 + 40];
  u16x4 o1, o2;
#pragma unroll
  for (int j = 0; j < 4; ++j) {
    const float a = bf2f(x1[j]), b = bf2f(x2[j]);
    o1[j] = f2bf(a * c1[j] - b * s1[j]);
    o2[j] = f2bf(b * c2[j] + a * s2[j]);
  }
  *(u16x4*)&base[d4] = o1;
  *(u16x4*)&base[d4 + 40] = o2;
}

// ---------------------------------------------------------------------------
// 1KB zero region for global_load_lds pad sources.
// ---------------------------------------------------------------------------
__global__ void zero_ws(uint4* z) {
  z[threadIdx.x] = uint4{0u, 0u, 0u, 0u};
}

// ---------------------------------------------------------------------------
// Flash attention v9: zero-shuffle P (no P LDS!), 52 KB LDS -> 3 blocks/CU.
// - V key-slots permuted in VtG (kappa baked in by vtrans): PV A-frag is
//   exactly the lane's own cvt_pk-packed P registers.
// - Vl [2][80x64] (pad rows dropped): 10 V-gloads split 3/3/2/2 per wave;
//   per-wave counted vmcnt 7/6.
// - staging addresses hoisted (per-lane base + kb*step; zbuf lanes step 0).
// ---------------------------------------------------------------------------
__global__ __launch_bounds__(256, 3) void attn_mfma8(
    const USHORT* __restrict__ qkv, const USHORT* __restrict__ VtG,
    const USHORT* __restrict__ zbuf, USHORT* __restrict__ aoB) {
  const int h = blockIdx.y;
  const int bx = blockIdx.x;
  const int qb = (bx & 7) * 8 + (bx >> 3);   // seg = bx&7 == XCD (id%8)
  const int s0 = qb * 128;
  const int k0g = (s0 / LSEG) * LSEG;
  const int tid = threadIdx.x;
  const int w = tid >> 6, l = tid & 63;
  const int g = l >> 4, fr = l & 15;
  const int q0 = s0 + w * 32;

  __shared__ __align__(16) USHORT Kl[2][64 * 128];   // 32 KB
  __shared__ __align__(16) USHORT Vl[2][80 * 64];    // 20 KB

  bf16x8 qb_frag[2][3];
#pragma unroll
  for (int nt2 = 0; nt2 < 2; ++nt2)
#pragma unroll
    for (int ks = 0; ks < 3; ++ks)
      qb_frag[nt2][ks] = *(const bf16x8*)
          &qkv[(size_t)(q0 + nt2 * 16 + fr) * QKVD + h * HD + ks * 32 + g * 8];

  const f32x4 fz = {0.f, 0.f, 0.f, 0.f};
  f32x4 oacc[2][5];
#pragma unroll
  for (int m = 0; m < 2; ++m)
#pragma unroll
    for (int n = 0; n < 5; ++n) oacc[m][n] = fz;
  float m_run[2] = {-3e38f, -3e38f};
  float l_run[2] = {0.f, 0.f};

  // ---- hoisted per-lane staging sources ----
  const int nV = (w < 2) ? 3 : 2;
  const int vbase = (w < 2) ? w * 3 : 6 + (w - 2) * 2;
  const USHORT* ksrc[4];
  int kstep[4];
#pragma unroll
  for (int i = 0; i < 4; ++i) {
    const int t = (w * 4 + i) * 64 + l;
    const int row = t >> 4, c = (t & 15) ^ (row & 7);
    if (c < 10) {
      ksrc[i] = qkv + (size_t)(k0g + row) * QKVD + DIM + h * HD + c * 8;
      kstep[i] = 64 * QKVD;
    } else {
      ksrc[i] = zbuf;
      kstep[i] = 0;
    }
  }
  const USHORT* vsrc[3] = {zbuf, zbuf, zbuf};
#pragma unroll
  for (int i = 0; i < 3; ++i)
    if (i < nV) {
      const int u = (vbase + i) * 64 + l;
      const int row = u >> 3, c = (u & 7) ^ (row & 7);
      vsrc[i] = VtG + (size_t)(h * HD + row) * SEQ + k0g + c * 8;
    }

  auto stageKV = [&](int kb, int b) {
#pragma unroll
    for (int i = 0; i < 4; ++i)
      gload16(ksrc[i] + (size_t)kb * kstep[i], &Kl[b][(w * 4 + i) * 512]);
#pragma unroll
    for (int i = 0; i < 3; ++i)
      if (i < nV)
        gload16(vsrc[i] + kb * 64, &Vl[b][(vbase + i) * 512]);
  };

  stageKV(0, 0);
  stageKV(1, 1);

  for (int kb = 0; kb < 16; ++kb) {
    const int cur = kb & 1;
    if (w < 2) {
      asm volatile("s_waitcnt vmcnt(7)" ::: "memory");
    } else {
      asm volatile("s_waitcnt vmcnt(6)" ::: "memory");
    }
    __builtin_amdgcn_sched_barrier(0);
    __builtin_amdgcn_s_barrier();
    __builtin_amdgcn_sched_barrier(0);

    // ---- QK^T: S^T[64 keys][32 q]; lane holds keys {16m+4g+j}, q=16nt2+fr --
    f32x4 sc[4][2];
#pragma unroll
    for (int m = 0; m < 4; ++m)
#pragma unroll
      for (int nt2 = 0; nt2 < 2; ++nt2) sc[m][nt2] = fz;
    __builtin_amdgcn_s_setprio(1);
#pragma unroll
    for (int ks = 0; ks < 3; ++ks)
#pragma unroll
      for (int m = 0; m < 4; ++m) {
        const bf16x8 kbf = *(const bf16x8*)
            &Kl[cur][(m * 16 + fr) * 128 + ((4 * ks + g) ^ (fr & 7)) * 8];
#pragma unroll
        for (int nt2 = 0; nt2 < 2; ++nt2)
          sc[m][nt2] = __builtin_amdgcn_mfma_f32_16x16x32_bf16(
              kbf, qb_frag[nt2][ks], sc[m][nt2], 0, 0, 0);
      }
    __builtin_amdgcn_s_setprio(0);

    // ---- lane-local online softmax with defer-max ----
    float rmax[2];
#pragma unroll
    for (int nt2 = 0; nt2 < 2; ++nt2) {
      float mx = -3e38f;
#pragma unroll
      for (int m = 0; m < 4; ++m)
#pragma unroll
        for (int j = 0; j < 4; ++j) mx = fmaxf(mx, sc[m][nt2][j]);
      mx = fmaxf(mx, __shfl_xor(mx, 16));
      mx = fmaxf(mx, __shfl_xor(mx, 32));
      rmax[nt2] = mx;
    }
    const bool need =
        (rmax[0] > m_run[0] + DTHR) || (rmax[1] > m_run[1] + DTHR);
    if (__any(need)) {
      float fac[2];
#pragma unroll
      for (int nt2 = 0; nt2 < 2; ++nt2) {
        const float mn = fmaxf(m_run[nt2], rmax[nt2]);
        fac[nt2] = exp2f((m_run[nt2] - mn) * CSF);
        m_run[nt2] = mn;
        l_run[nt2] *= fac[nt2];
      }
#pragma unroll
      for (int mt2 = 0; mt2 < 2; ++mt2)
#pragma unroll
        for (int j = 0; j < 4; ++j) {
          const float fb = __shfl(fac[mt2], 20 * g + j);
#pragma unroll
          for (int nt = 0; nt < 5; ++nt) oacc[mt2][nt][j] *= fb;
        }
    }
    unsigned pkr[2][4][2];
#pragma unroll
    for (int nt2 = 0; nt2 < 2; ++nt2) {
      const float mcs = m_run[nt2] * CSF;
      float ps = 0.f;
#pragma unroll
      for (int m = 0; m < 4; ++m) {
        float p[4];
#pragma unroll
        for (int j = 0; j < 4; ++j) {
          p[j] = exp2f(sc[m][nt2][j] * CSF - mcs);
          ps += p[j];
        }
        pkr[nt2][m][0] = cvtpk(p[0], p[1]);
        pkr[nt2][m][1] = cvtpk(p[2], p[3]);
      }
      ps += __shfl_xor(ps, 16);
      ps += __shfl_xor(ps, 32);
      l_run[nt2] += ps;
    }

    // ---- PV: O[32q][80d] += P @ V; A-frag is lane-local (kappa-ordered) ----
#pragma unroll
    for (int ks = 0; ks < 2; ++ks) {
      const int sl = (((ks << 2) + g) ^ (fr & 7)) << 3;
      union { bf16x8 v8; i32x4 i4; } pa[2];
#pragma unroll
      for (int mt2 = 0; mt2 < 2; ++mt2) {
        pa[mt2].i4[0] = (int)pkr[mt2][2 * ks][0];
        pa[mt2].i4[1] = (int)pkr[mt2][2 * ks][1];
        pa[mt2].i4[2] = (int)pkr[mt2][2 * ks + 1][0];
        pa[mt2].i4[3] = (int)pkr[mt2][2 * ks + 1][1];
      }
      __builtin_amdgcn_s_setprio(1);
#pragma unroll
      for (int nt = 0; nt < 5; ++nt) {
        const bf16x8 vb = *(const bf16x8*)&Vl[cur][(nt * 16 + fr) * 64 + sl];
#pragma unroll
        for (int mt2 = 0; mt2 < 2; ++mt2)
          oacc[mt2][nt] = __builtin_amdgcn_mfma_f32_16x16x32_bf16(
              pa[mt2].v8, vb, oacc[mt2][nt], 0, 0, 0);
      }
      __builtin_amdgcn_s_setprio(0);
    }

    __builtin_amdgcn_s_barrier();
    __builtin_amdgcn_sched_barrier(0);
    const int kn = (kb + 2 < 16) ? kb + 2 : kb;
    stageKV(kn, cur);
    __builtin_amdgcn_sched_barrier(0);
  }

  asm volatile("s_waitcnt vmcnt(0)" ::: "memory");

  float linv[2][4];
#pragma unroll
  for (int mt2 = 0; mt2 < 2; ++mt2)
#pragma unroll
    for (int j = 0; j < 4; ++j)
      linv[mt2][j] = 1.f / __shfl(l_run[mt2], 20 * g + j);
#pragma unroll
  for (int mt2 = 0; mt2 < 2; ++mt2)
#pragma unroll
    for (int nt = 0; nt < 5; ++nt)
#pragma unroll
      for (int j = 0; j < 4; ++j) {
        const int row = s0 + w * 32 + mt2 * 16 + g * 4 + j;
        const int col = h * HD + nt * 16 + fr;
        aoB[(size_t)row * QKVD + col] = f2bf(oacc[mt2][nt][j] * linv[mt2][j]);
      }
}

// ---------------------------------------------------------------------------
// ws layout (bytes):
//   [0, 62914560)            qkv bf16 [8192][3840]; during attn, the V-slots
//                            (cols 2560..3839) are dead (V read via VtG) and
//                            receive the attn output bf16 -> proj A (lda=3840)
//   [62914560, 83886080)     hs bf16 [8192][1280]; after GEMM1 reused as
//                            VtG bf16 [1280][8192] (V pre-transposed, kappa-
//                            permuted key slots within each 64-block)
//   [83886080, 93716480)     qkv_w^T bf16 [3840][1280]; first 1KB re-zeroed
//                            after GEMM1 -> zbuf for attn pad sources
//   [93716480, 96993280)     proj_w^T bf16 [1280][1280]
// ---------------------------------------------------------------------------
extern "C" void kernel_launch(void* const* d_in, const int* in_sizes, int n_in,
                              void* d_out, int out_size, void* d_ws,
                              size_t ws_size, hipStream_t stream) {
  const float* hs = (const float*)d_in[0];
  const float* cosb = (const float*)d_in[1];
  const float* sinb = (const float*)d_in[2];
  const float* qkv_w = (const float*)d_in[3];
  const float* qkv_b = (const float*)d_in[4];
  const float* proj_w = (const float*)d_in[5];
  const float* proj_b = (const float*)d_in[6];
  char* ws = (char*)d_ws;

  USHORT* qkvB  = (USHORT*)(ws);
  USHORT* hsB   = (USHORT*)(ws + 62914560u);
  USHORT* qkvwT = (USHORT*)(ws + 83886080u);
  USHORT* pwT   = (USHORT*)(ws + 93716480u);
  USHORT* VtG   = hsB;                        // hsB dead after GEMM1
  USHORT* zbuf  = qkvwT;                      // qkvwT dead after GEMM1
  USHORT* aoB   = qkvB + 2 * DIM;             // attn out -> dead V-slots

  // allow 128 KB dynamic LDS for the 256^2 GEMM (deterministic, no guards)
  hipFuncSetAttribute((const void*)mfma_gemm256,
                      hipFuncAttributeMaxDynamicSharedMemorySize, 131072);

  // input conversions
  conv_f2b<<<SEQ * DIM / 4 / 256, 256, 0, stream>>>(hs, hsB, SEQ * DIM / 4);
  conv_transpose<<<dim3(QKVD / 32, DIM / 32), 256, 0, stream>>>(
      qkv_w, qkvwT, DIM, QKVD);
  conv_transpose<<<dim3(DIM / 32, DIM / 32), 256, 0, stream>>>(
      proj_w, pwT, DIM, DIM);

  // 1) qkv = hs @ qkv_w + b  (bf16 out), 256^2 tile
  mfma_gemm256<<<(SEQ / 256) * (QKVD / 256), 512, 131072, stream>>>(
      hsB, qkvwT, qkv_b, qkvB, SEQ, QKVD, DIM, DIM);
  // 2) RoPE in place (q,k only), vectorized
  rope_b<<<SEQ * HEADS * 2 * 10 / 256, 256, 0, stream>>>(qkvB, cosb, sinb);
  // 2.3) pre-transpose V (kappa-permuted): VtG  (hsB region is dead now)
  vtrans<<<dim3(DIM / 32, SEQ / 32), 256, 0, stream>>>(qkvB, VtG);
  // 2.6) zero pad-source region (qkvwT dead after GEMM1)
  zero_ws<<<1, 64, 0, stream>>>((uint4*)zbuf);
  // 3) attention -> bf16 into qkv's dead V-slots
  attn_mfma8<<<dim3(SEQ / 128, HEADS), 256, 0, stream>>>(qkvB, VtG, zbuf, aoB);
  // 4) out = attn @ proj_w + b  (f32 out) -> d_out   (A stride = QKVD)
  mfma_gemm<0><<<(SEQ / 128) * (DIM / 128), 256, 0, stream>>>(
      aoB, pwT, proj_b, d_out, SEQ, DIM, DIM, QKVD);
}

// Round 13
// 264.389 us; speedup vs baseline: 11.3438x; 1.0395x over previous
//
#include <hip/hip_runtime.h>

#define SEQ   8192
#define DIM   1280
#define HEADS 16
#define HD    80
#define LSEG  1024
#define QKVD  3840

typedef unsigned short USHORT;
typedef __attribute__((ext_vector_type(8))) short bf16x8;
typedef __attribute__((ext_vector_type(4))) float f32x4;
typedef __attribute__((ext_vector_type(4))) USHORT u16x4;
typedef __attribute__((ext_vector_type(4))) int i32x4;

#define CSF  0.16129832f    // (1/sqrt(80)) * log2(e)
#define DTHR 71.554175f     // 8 / (1/sqrt(80)) : defer-max threshold in raw units

__device__ __forceinline__ USHORT f2bf(float x) {
  unsigned u = __float_as_uint(x);
  u += 0x7fffu + ((u >> 16) & 1u);
  return (USHORT)(u >> 16);
}
__device__ __forceinline__ float bf2f(USHORT b) {
  return __uint_as_float(((unsigned)b) << 16);
}
__device__ __forceinline__ void gload16(const void* g, void* l) {
  __builtin_amdgcn_global_load_lds(
      (const __attribute__((address_space(1))) void*)g,
      (__attribute__((address_space(3))) void*)l, 16, 0, 0);
}
// packs {bf16(a) -> [15:0], bf16(b) -> [31:16]}, RNE (same as f2bf)
__device__ __forceinline__ unsigned cvtpk(float a, float b) {
  unsigned d;
  asm("v_cvt_pk_bf16_f32 %0, %1, %2" : "=v"(d) : "v"(a), "v"(b));
  return d;
}

// ---------------------------------------------------------------------------
// prep1: fused input conversions (independent jobs, one launch).
//   blocks [0,10240)        : hs f32 -> bf16
//   blocks [10240,15040)    : qkv_w [K][N] -> qkvwT [N][K] bf16
//   blocks [15040,16640)    : proj_w -> pwT bf16
// ---------------------------------------------------------------------------
__global__ __launch_bounds__(256) void prep1(
    const float* __restrict__ hs, USHORT* __restrict__ hsB,
    const float* __restrict__ qkv_w, USHORT* __restrict__ qkvwT,
    const float* __restrict__ proj_w, USHORT* __restrict__ pwT) {
  __shared__ float tb[32][33];
  const int bx = blockIdx.x;
  const int tid = threadIdx.x;
  if (bx < 10240) {
    const int i = bx * 256 + tid;
    const float4 v = reinterpret_cast<const float4*>(hs)[i];
    USHORT* o = hsB + (size_t)i * 4;
    o[0] = f2bf(v.x); o[1] = f2bf(v.y); o[2] = f2bf(v.z); o[3] = f2bf(v.w);
    return;
  }
  const float* W; USHORT* T; int K, N, n0, k0;
  if (bx < 15040) {
    const int b = bx - 10240;
    W = qkv_w; T = qkvwT; K = DIM; N = QKVD;
    n0 = (b % 120) * 32; k0 = (b / 120) * 32;
  } else {
    const int b = bx - 15040;
    W = proj_w; T = pwT; K = DIM; N = DIM;
    n0 = (b % 40) * 32; k0 = (b / 40) * 32;
  }
  const int c = tid & 31, r0 = tid >> 5;
  for (int r = r0; r < 32; r += 8) tb[r][c] = W[(size_t)(k0 + r) * N + n0 + c];
  __syncthreads();
  for (int r = r0; r < 32; r += 8)
    T[(size_t)(n0 + r) * K + k0 + c] = f2bf(tb[c][r]);  // = W[k0+c][n0+r]
}

// ---------------------------------------------------------------------------
// prep2: fused post-GEMM1 passes (independent jobs).
//   blocks [0,10240)     : RoPE in-place on q,k (vectorized, 4 pairs/thread)
//   blocks [10240,20480) : V-transpose with kappa key-permutation -> VtG
//   block  20480         : zero 1KB pad-source region
// ---------------------------------------------------------------------------
__global__ __launch_bounds__(256) void prep2(
    USHORT* __restrict__ qkv, const float* __restrict__ cosb,
    const float* __restrict__ sinb, USHORT* __restrict__ VtG,
    uint4* __restrict__ zb) {
  __shared__ USHORT tu[32][33];
  const int bx = blockIdx.x;
  const int tid = threadIdx.x;
  if (bx < 10240) {
    int idx = bx * 256 + tid;
    const int d4 = (idx % 10) * 4;
    int t = idx / 10;
    const int h = t % HEADS;
    t /= HEADS;
    const int qk = t & 1;
    const int s = t >> 1;
    USHORT* base = qkv + (size_t)s * QKVD + qk * DIM + h * HD;
    const u16x4 x1 = *(const u16x4*)&base[d4];
    const u16x4 x2 = *(const u16x4*)&base[d4 + 40];
    const f32x4 c1 = *(const f32x4*)&cosb[s * HD + d4];
    const f32x4 s1 = *(const f32x4*)&sinb[s * HD + d4];
    const f32x4 c2 = *(const f32x4*)&cosb[s * HD + d4 + 40];
    const f32x4 s2 = *(const f32x4*)&sinb[s * HD + d4 + 40];
    u16x4 o1, o2;
#pragma unroll
    for (int j = 0; j < 4; ++j) {
      const float a = bf2f(x1[j]), b = bf2f(x2[j]);
      o1[j] = f2bf(a * c1[j] - b * s1[j]);
      o2[j] = f2bf(b * c2[j] + a * s2[j]);
    }
    *(u16x4*)&base[d4] = o1;
    *(u16x4*)&base[d4 + 40] = o2;
    return;
  }
  if (bx < 20480) {
    const int b = bx - 10240;
    const int c0 = (b % 40) * 32, s0 = (b / 40) * 32;
    const int c = tid & 31, r0 = tid >> 5;
    for (int r = r0; r < 32; r += 8)
      tu[r][c] = qkv[(size_t)(s0 + r) * QKVD + 2 * DIM + c0 + c];
    __syncthreads();
    // kappa-inverse column permutation within each 64-block of keys
    const int pc = (s0 & 32) | c;
    const int sc = (pc & 0x23) | ((pc & 0x10) >> 2) | ((pc & 0x0C) << 1);
    const size_t col = (size_t)(s0 & ~63) + sc;
    for (int r = r0; r < 32; r += 8)
      VtG[(size_t)(c0 + r) * SEQ + col] = tu[c][r];
    return;
  }
  if (tid < 64) zb[tid] = uint4{0u, 0u, 0u, 0u};
}

// ---------------------------------------------------------------------------
// 256x256 MFMA GEMM (bf16 out), depth-2 counted-vmcnt + XOR-8 swizzle,
// with hoisted stage pointers (+64/iter, clamped tail) and hoisted frag
// LDS bases (immediate m/n offsets). Arithmetic identical to r10-proven.
// ---------------------------------------------------------------------------
__global__ __launch_bounds__(512, 2) void mfma_gemm256(
    const USHORT* __restrict__ Ah, const USHORT* __restrict__ Bh,
    const float* __restrict__ bias, USHORT* __restrict__ Cout,
    int M, int N, int K, int lda) {
  extern __shared__ USHORT sm[];  // [0)A0 [16384)A1 [32768)B0 [49152)B1

  const int tid = threadIdx.x;
  const int l = tid & 63;
  const int w = tid >> 6;
  const int fr = l & 15;
  const int g = l >> 4;
  const int nrow = M >> 8;
  const int nwg = nrow * (N >> 8);
  const int orig = blockIdx.x;
  const int wg = (orig & 7) * (nwg >> 3) + (orig >> 3);  // XCD swizzle (nwg%8==0)
  const int row0 = (wg % nrow) << 8;
  const int col0 = (wg / nrow) << 8;
  const int wr = (w >> 2) << 7;   // 0 / 128
  const int wc = (w & 3) << 6;    // 0 / 64 / 128 / 192

  const f32x4 fz = {0.f, 0.f, 0.f, 0.f};
  f32x4 acc[8][4];
#pragma unroll
  for (int m = 0; m < 8; ++m)
#pragma unroll
    for (int n = 0; n < 4; ++n) acc[m][n] = fz;

  const int NT = K >> 6;

  // hoisted stage sources (advance +64 shorts per K-tile)
  const USHORT* asrc[4];
  const USHORT* bsrc[4];
#pragma unroll
  for (int i = 0; i < 4; ++i) {
    const int u = i * 512 + tid;
    const int row = u >> 3;
    const int c = (u & 7) ^ (row & 7);
    asrc[i] = Ah + (size_t)(row0 + row) * lda + c * 8;
    bsrc[i] = Bh + (size_t)(col0 + row) * K + c * 8;
  }
  auto stage = [&](int b) {
#pragma unroll
    for (int i = 0; i < 4; ++i) {
      USHORT* dst = sm + (i * 512 + (w << 6)) * 8 + b * 16384;
      gload16(asrc[i], dst);
      gload16(bsrc[i], dst + 32768);
    }
  };
  auto advance = [&]() {
#pragma unroll
    for (int i = 0; i < 4; ++i) { asrc[i] += 64; bsrc[i] += 64; }
  };

  // hoisted frag LDS offsets (shorts, buffer 0)
  const int fb = fr & 7;
  int aOff[2], bOff[2];
#pragma unroll
  for (int ks = 0; ks < 2; ++ks) {
    const int sl = (((ks << 2) + g) ^ fb) << 3;
    aOff[ks] = (wr + fr) * 64 + sl;
    bOff[ks] = 32768 + (wc + fr) * 64 + sl;
  }

  stage(0); advance();
  stage(1); advance();

  for (int t = 0; t < NT; ++t) {
    const int cur = t & 1;
    asm volatile("s_waitcnt vmcnt(8)" ::: "memory");
    __builtin_amdgcn_sched_barrier(0);
    __builtin_amdgcn_s_barrier();
    __builtin_amdgcn_sched_barrier(0);
    const int cb = cur << 14;
    bf16x8 ah[2][8], bh[2][4];
#pragma unroll
    for (int ks = 0; ks < 2; ++ks) {
#pragma unroll
      for (int m = 0; m < 8; ++m)
        ah[ks][m] = *(const bf16x8*)(sm + cb + aOff[ks] + m * 1024);
#pragma unroll
      for (int n = 0; n < 4; ++n)
        bh[ks][n] = *(const bf16x8*)(sm + cb + bOff[ks] + n * 1024);
    }
    asm volatile("s_waitcnt lgkmcnt(0)" ::: "memory");
    __builtin_amdgcn_sched_barrier(0);
    __builtin_amdgcn_s_barrier();
    __builtin_amdgcn_sched_barrier(0);
    stage(cur);                      // stages tile min(t+2, NT-1)
    if (t < NT - 3) advance();
    __builtin_amdgcn_sched_barrier(0);
    __builtin_amdgcn_s_setprio(1);
#pragma unroll
    for (int ks = 0; ks < 2; ++ks)
#pragma unroll
      for (int m = 0; m < 8; ++m)
#pragma unroll
        for (int n = 0; n < 4; ++n)
          acc[m][n] = __builtin_amdgcn_mfma_f32_16x16x32_bf16(
              ah[ks][m], bh[ks][n], acc[m][n], 0, 0, 0);
    __builtin_amdgcn_s_setprio(0);
  }

  asm volatile("s_waitcnt vmcnt(0)" ::: "memory");

  float bv[4];
#pragma unroll
  for (int n = 0; n < 4; ++n) bv[n] = bias[col0 + wc + n * 16 + fr];
#pragma unroll
  for (int m = 0; m < 8; ++m)
#pragma unroll
    for (int n = 0; n < 4; ++n)
#pragma unroll
      for (int r = 0; r < 4; ++r) {
        const float v = acc[m][n][r] + bv[n];
        const int row = row0 + wr + m * 16 + g * 4 + r;
        const int col = col0 + wc + n * 16 + fr;
        Cout[(size_t)row * N + col] = f2bf(v);
      }
}

// ---------------------------------------------------------------------------
// 128x128 MFMA GEMM, depth-2 counted-vmcnt + XOR-8 swizzle, hoisted
// addresses (same scheme). Used for proj (N=1280 -> 640 blocks).
// ---------------------------------------------------------------------------
template <int OUTBF>
__global__ __launch_bounds__(256) void mfma_gemm(
    const USHORT* __restrict__ Ah, const USHORT* __restrict__ Bh,
    const float* __restrict__ bias, void* __restrict__ Cout,
    int M, int N, int K, int lda) {
  __shared__ __align__(16) USHORT AhL[2][8192];
  __shared__ __align__(16) USHORT BhL[2][8192];

  const int tid = threadIdx.x;
  const int l = tid & 63;
  const int w = tid >> 6;
  const int nrow = M >> 7;
  const int nwg = nrow * (N >> 7);
  const int orig = blockIdx.x;
  const int wg = (orig & 7) * (nwg >> 3) + (orig >> 3);  // XCD swizzle (nwg%8==0)
  const int row0 = (wg % nrow) << 7;
  const int col0 = (wg / nrow) << 7;
  const int wr = (w >> 1) << 6;
  const int wc = (w & 1) << 6;

  const f32x4 fz = {0.f, 0.f, 0.f, 0.f};
  f32x4 acc[4][4];
#pragma unroll
  for (int m = 0; m < 4; ++m)
#pragma unroll
    for (int n = 0; n < 4; ++n) acc[m][n] = fz;

  const int fr = l & 15;
  const int g = l >> 4;
  const int NT = K >> 6;

  const USHORT* asrc[4];
  const USHORT* bsrc[4];
#pragma unroll
  for (int i = 0; i < 4; ++i) {
    const int u = (w * 4 + i) * 64 + l;
    const int row = u >> 3;
    const int c = (u & 7) ^ (row & 7);
    asrc[i] = Ah + (size_t)(row0 + row) * lda + c * 8;
    bsrc[i] = Bh + (size_t)(col0 + row) * K + c * 8;
  }
  auto stage = [&](int b) {
#pragma unroll
    for (int i = 0; i < 4; ++i) {
      gload16(asrc[i], &AhL[b][(w * 4 + i) * 512]);
      gload16(bsrc[i], &BhL[b][(w * 4 + i) * 512]);
    }
  };
  auto advance = [&]() {
#pragma unroll
    for (int i = 0; i < 4; ++i) { asrc[i] += 64; bsrc[i] += 64; }
  };

  const int fb = fr & 7;
  int aOff[2], bOff[2];
#pragma unroll
  for (int ks = 0; ks < 2; ++ks) {
    const int sl = (((ks << 2) + g) ^ fb) << 3;
    aOff[ks] = (wr + fr) * 64 + sl;
    bOff[ks] = (wc + fr) * 64 + sl;
  }
  const USHORT* AB = &AhL[0][0];
  const USHORT* BB = &BhL[0][0];

  stage(0); advance();
  stage(1); advance();

  for (int t = 0; t < NT; ++t) {
    const int cur = t & 1;
    asm volatile("s_waitcnt vmcnt(8)" ::: "memory");
    __builtin_amdgcn_sched_barrier(0);
    __builtin_amdgcn_s_barrier();
    __builtin_amdgcn_sched_barrier(0);
    const int cb = cur << 13;
    bf16x8 ah[2][4], bh[2][4];
#pragma unroll
    for (int ks = 0; ks < 2; ++ks)
#pragma unroll
      for (int m = 0; m < 4; ++m) {
        ah[ks][m] = *(const bf16x8*)(AB + cb + aOff[ks] + m * 1024);
        bh[ks][m] = *(const bf16x8*)(BB + cb + bOff[ks] + m * 1024);
      }
    asm volatile("s_waitcnt lgkmcnt(0)" ::: "memory");
    __builtin_amdgcn_sched_barrier(0);
    __builtin_amdgcn_s_barrier();
    __builtin_amdgcn_sched_barrier(0);
    stage(cur);
    if (t < NT - 3) advance();
    __builtin_amdgcn_sched_barrier(0);
    __builtin_amdgcn_s_setprio(1);
#pragma unroll
    for (int ks = 0; ks < 2; ++ks)
#pragma unroll
      for (int m = 0; m < 4; ++m)
#pragma unroll
        for (int n = 0; n < 4; ++n)
          acc[m][n] = __builtin_amdgcn_mfma_f32_16x16x32_bf16(
              ah[ks][m], bh[ks][n], acc[m][n], 0, 0, 0);
    __builtin_amdgcn_s_setprio(0);
  }

  asm volatile("s_waitcnt vmcnt(0)" ::: "memory");

  float bv[4];
#pragma unroll
  for (int n = 0; n < 4; ++n) bv[n] = bias[col0 + wc + n * 16 + fr];
#pragma unroll
  for (int m = 0; m < 4; ++m)
#pragma unroll
    for (int n = 0; n < 4; ++n)
#pragma unroll
      for (int r = 0; r < 4; ++r) {
        const float v = acc[m][n][r] + bv[n];
        const int row = row0 + wr + m * 16 + (l >> 4) * 4 + r;
        const int col = col0 + wc + n * 16 + fr;
        if (OUTBF)
          ((USHORT*)Cout)[(size_t)row * N + col] = f2bf(v);
        else
          ((float*)Cout)[(size_t)row * N + col] = v;
      }
}

// ---------------------------------------------------------------------------
// Flash attention (r12-proven): zero-shuffle P, 52 KB LDS (3 blocks/CU),
// segment-affine XCD swizzle, depth-2 counted-vmcnt, hoisted staging
// addresses; NOW also hoisted K/V frag LDS offsets.
// ---------------------------------------------------------------------------
__global__ __launch_bounds__(256, 3) void attn_mfma8(
    const USHORT* __restrict__ qkv, const USHORT* __restrict__ VtG,
    const USHORT* __restrict__ zbuf, USHORT* __restrict__ aoB) {
  const int h = blockIdx.y;
  const int bx = blockIdx.x;
  const int qb = (bx & 7) * 8 + (bx >> 3);   // seg = bx&7 == XCD (id%8)
  const int s0 = qb * 128;
  const int k0g = (s0 / LSEG) * LSEG;
  const int tid = threadIdx.x;
  const int w = tid >> 6, l = tid & 63;
  const int g = l >> 4, fr = l & 15;
  const int q0 = s0 + w * 32;

  __shared__ __align__(16) USHORT Kl[2][64 * 128];   // 32 KB
  __shared__ __align__(16) USHORT Vl[2][80 * 64];    // 20 KB

  bf16x8 qb_frag[2][3];
#pragma unroll
  for (int nt2 = 0; nt2 < 2; ++nt2)
#pragma unroll
    for (int ks = 0; ks < 3; ++ks)
      qb_frag[nt2][ks] = *(const bf16x8*)
          &qkv[(size_t)(q0 + nt2 * 16 + fr) * QKVD + h * HD + ks * 32 + g * 8];

  const f32x4 fz = {0.f, 0.f, 0.f, 0.f};
  f32x4 oacc[2][5];
#pragma unroll
  for (int m = 0; m < 2; ++m)
#pragma unroll
    for (int n = 0; n < 5; ++n) oacc[m][n] = fz;
  float m_run[2] = {-3e38f, -3e38f};
  float l_run[2] = {0.f, 0.f};

  // ---- hoisted per-lane staging sources ----
  const int nV = (w < 2) ? 3 : 2;
  const int vbase = (w < 2) ? w * 3 : 6 + (w - 2) * 2;
  const USHORT* ksrc[4];
  int kstep[4];
#pragma unroll
  for (int i = 0; i < 4; ++i) {
    const int t = (w * 4 + i) * 64 + l;
    const int row = t >> 4, c = (t & 15) ^ (row & 7);
    if (c < 10) {
      ksrc[i] = qkv + (size_t)(k0g + row) * QKVD + DIM + h * HD + c * 8;
      kstep[i] = 64 * QKVD;
    } else {
      ksrc[i] = zbuf;
      kstep[i] = 0;
    }
  }
  const USHORT* vsrc[3] = {zbuf, zbuf, zbuf};
#pragma unroll
  for (int i = 0; i < 3; ++i)
    if (i < nV) {
      const int u = (vbase + i) * 64 + l;
      const int row = u >> 3, c = (u & 7) ^ (row & 7);
      vsrc[i] = VtG + (size_t)(h * HD + row) * SEQ + k0g + c * 8;
    }

  auto stageKV = [&](int kb, int b) {
#pragma unroll
    for (int i = 0; i < 4; ++i)
      gload16(ksrc[i] + (size_t)kb * kstep[i], &Kl[b][(w * 4 + i) * 512]);
#pragma unroll
    for (int i = 0; i < 3; ++i)
      if (i < nV)
        gload16(vsrc[i] + kb * 64, &Vl[b][(vbase + i) * 512]);
  };

  // ---- hoisted frag LDS offsets ----
  const int fb = fr & 7;
  int kOff[3], vOff[2];
#pragma unroll
  for (int ks = 0; ks < 3; ++ks)
    kOff[ks] = fr * 128 + ((((ks << 2) + g) ^ fb) << 3);
#pragma unroll
  for (int ks = 0; ks < 2; ++ks)
    vOff[ks] = fr * 64 + ((((ks << 2) + g) ^ fb) << 3);
  const USHORT* KB = &Kl[0][0];
  const USHORT* VB = &Vl[0][0];

  stageKV(0, 0);
  stageKV(1, 1);

  for (int kb = 0; kb < 16; ++kb) {
    const int cur = kb & 1;
    if (w < 2) {
      asm volatile("s_waitcnt vmcnt(7)" ::: "memory");
    } else {
      asm volatile("s_waitcnt vmcnt(6)" ::: "memory");
    }
    __builtin_amdgcn_sched_barrier(0);
    __builtin_amdgcn_s_barrier();
    __builtin_amdgcn_sched_barrier(0);
    const int kcb = cur << 13;
    const int vcb = cur * 5120;

    // ---- QK^T: S^T[64 keys][32 q]; lane holds keys {16m+4g+j}, q=16nt2+fr --
    f32x4 sc[4][2];
#pragma unroll
    for (int m = 0; m < 4; ++m)
#pragma unroll
      for (int nt2 = 0; nt2 < 2; ++nt2) sc[m][nt2] = fz;
    __builtin_amdgcn_s_setprio(1);
#pragma unroll
    for (int ks = 0; ks < 3; ++ks)
#pragma unroll
      for (int m = 0; m < 4; ++m) {
        const bf16x8 kbf = *(const bf16x8*)(KB + kcb + kOff[ks] + m * 2048);
#pragma unroll
        for (int nt2 = 0; nt2 < 2; ++nt2)
          sc[m][nt2] = __builtin_amdgcn_mfma_f32_16x16x32_bf16(
              kbf, qb_frag[nt2][ks], sc[m][nt2], 0, 0, 0);
      }
    __builtin_amdgcn_s_setprio(0);

    // ---- lane-local online softmax with defer-max ----
    float rmax[2];
#pragma unroll
    for (int nt2 = 0; nt2 < 2; ++nt2) {
      float mx = -3e38f;
#pragma unroll
      for (int m = 0; m < 4; ++m)
#pragma unroll
        for (int j = 0; j < 4; ++j) mx = fmaxf(mx, sc[m][nt2][j]);
      mx = fmaxf(mx, __shfl_xor(mx, 16));
      mx = fmaxf(mx, __shfl_xor(mx, 32));
      rmax[nt2] = mx;
    }
    const bool need =
        (rmax[0] > m_run[0] + DTHR) || (rmax[1] > m_run[1] + DTHR);
    if (__any(need)) {
      float fac[2];
#pragma unroll
      for (int nt2 = 0; nt2 < 2; ++nt2) {
        const float mn = fmaxf(m_run[nt2], rmax[nt2]);
        fac[nt2] = exp2f((m_run[nt2] - mn) * CSF);
        m_run[nt2] = mn;
        l_run[nt2] *= fac[nt2];
      }
#pragma unroll
      for (int mt2 = 0; mt2 < 2; ++mt2)
#pragma unroll
        for (int j = 0; j < 4; ++j) {
          const float fb2 = __shfl(fac[mt2], 20 * g + j);
#pragma unroll
          for (int nt = 0; nt < 5; ++nt) oacc[mt2][nt][j] *= fb2;
        }
    }
    unsigned pkr[2][4][2];
#pragma unroll
    for (int nt2 = 0; nt2 < 2; ++nt2) {
      const float mcs = m_run[nt2] * CSF;
      float ps = 0.f;
#pragma unroll
      for (int m = 0; m < 4; ++m) {
        float p[4];
#pragma unroll
        for (int j = 0; j < 4; ++j) {
          p[j] = exp2f(sc[m][nt2][j] * CSF - mcs);
          ps += p[j];
        }
        pkr[nt2][m][0] = cvtpk(p[0], p[1]);
        pkr[nt2][m][1] = cvtpk(p[2], p[3]);
      }
      ps += __shfl_xor(ps, 16);
      ps += __shfl_xor(ps, 32);
      l_run[nt2] += ps;
    }

    // ---- PV: O[32q][80d] += P @ V; A-frag is lane-local (kappa-ordered) ----
#pragma unroll
    for (int ks = 0; ks < 2; ++ks) {
      union { bf16x8 v8; i32x4 i4; } pa[2];
#pragma unroll
      for (int mt2 = 0; mt2 < 2; ++mt2) {
        pa[mt2].i4[0] = (int)pkr[mt2][2 * ks][0];
        pa[mt2].i4[1] = (int)pkr[mt2][2 * ks][1];
        pa[mt2].i4[2] = (int)pkr[mt2][2 * ks + 1][0];
        pa[mt2].i4[3] = (int)pkr[mt2][2 * ks + 1][1];
      }
      __builtin_amdgcn_s_setprio(1);
#pragma unroll
      for (int nt = 0; nt < 5; ++nt) {
        const bf16x8 vb = *(const bf16x8*)(VB + vcb + vOff[ks] + nt * 1024);
#pragma unroll
        for (int mt2 = 0; mt2 < 2; ++mt2)
          oacc[mt2][nt] = __builtin_amdgcn_mfma_f32_16x16x32_bf16(
              pa[mt2].v8, vb, oacc[mt2][nt], 0, 0, 0);
      }
      __builtin_amdgcn_s_setprio(0);
    }

    __builtin_amdgcn_s_barrier();
    __builtin_amdgcn_sched_barrier(0);
    const int kn = (kb + 2 < 16) ? kb + 2 : kb;
    stageKV(kn, cur);
    __builtin_amdgcn_sched_barrier(0);
  }

  asm volatile("s_waitcnt vmcnt(0)" ::: "memory");

  float linv[2][4];
#pragma unroll
  for (int mt2 = 0; mt2 < 2; ++mt2)
#pragma unroll
    for (int j = 0; j < 4; ++j)
      linv[mt2][j] = 1.f / __shfl(l_run[mt2], 20 * g + j);
#pragma unroll
  for (int mt2 = 0; mt2 < 2; ++mt2)
#pragma unroll
    for (int nt = 0; nt < 5; ++nt)
#pragma unroll
      for (int j = 0; j < 4; ++j) {
        const int row = s0 + w * 32 + mt2 * 16 + g * 4 + j;
        const int col = h * HD + nt * 16 + fr;
        aoB[(size_t)row * QKVD + col] = f2bf(oacc[mt2][nt][j] * linv[mt2][j]);
      }
}

// ---------------------------------------------------------------------------
// ws layout (bytes):
//   [0, 62914560)            qkv bf16 [8192][3840]; during attn, the V-slots
//                            (cols 2560..3839) are dead (V read via VtG) and
//                            receive the attn output bf16 -> proj A (lda=3840)
//   [62914560, 83886080)     hs bf16 [8192][1280]; after GEMM1 reused as
//                            VtG bf16 [1280][8192] (V pre-transposed, kappa-
//                            permuted key slots within each 64-block)
//   [83886080, 93716480)     qkv_w^T bf16 [3840][1280]; first 1KB re-zeroed
//                            after GEMM1 -> zbuf for attn pad sources
//   [93716480, 96993280)     proj_w^T bf16 [1280][1280]
// ---------------------------------------------------------------------------
extern "C" void kernel_launch(void* const* d_in, const int* in_sizes, int n_in,
                              void* d_out, int out_size, void* d_ws,
                              size_t ws_size, hipStream_t stream) {
  const float* hs = (const float*)d_in[0];
  const float* cosb = (const float*)d_in[1];
  const float* sinb = (const float*)d_in[2];
  const float* qkv_w = (const float*)d_in[3];
  const float* qkv_b = (const float*)d_in[4];
  const float* proj_w = (const float*)d_in[5];
  const float* proj_b = (const float*)d_in[6];
  char* ws = (char*)d_ws;

  USHORT* qkvB  = (USHORT*)(ws);
  USHORT* hsB   = (USHORT*)(ws + 62914560u);
  USHORT* qkvwT = (USHORT*)(ws + 83886080u);
  USHORT* pwT   = (USHORT*)(ws + 93716480u);
  USHORT* VtG   = hsB;                        // hsB dead after GEMM1
  USHORT* zbuf  = qkvwT;                      // qkvwT dead after GEMM1
  USHORT* aoB   = qkvB + 2 * DIM;             // attn out -> dead V-slots

  // allow 128 KB dynamic LDS for the 256^2 GEMM (deterministic, no guards)
  hipFuncSetAttribute((const void*)mfma_gemm256,
                      hipFuncAttributeMaxDynamicSharedMemorySize, 131072);

  // 0) fused input conversions
  prep1<<<16640, 256, 0, stream>>>(hs, hsB, qkv_w, qkvwT, proj_w, pwT);
  // 1) qkv = hs @ qkv_w + b  (bf16 out), 256^2 tile
  mfma_gemm256<<<(SEQ / 256) * (QKVD / 256), 512, 131072, stream>>>(
      hsB, qkvwT, qkv_b, qkvB, SEQ, QKVD, DIM, DIM);
  // 2) fused: RoPE (q,k) + kappa-permuted V-transpose + zbuf zeroing
  prep2<<<20481, 256, 0, stream>>>(qkvB, cosb, sinb, VtG, (uint4*)zbuf);
  // 3) attention -> bf16 into qkv's dead V-slots
  attn_mfma8<<<dim3(SEQ / 128, HEADS), 256, 0, stream>>>(qkvB, VtG, zbuf, aoB);
  // 4) out = attn @ proj_w + b  (f32 out) -> d_out   (A stride = QKVD)
  mfma_gemm<0><<<(SEQ / 128) * (DIM / 128), 256, 0, stream>>>(
      aoB, pwT, proj_b, d_out, SEQ, DIM, DIM, QKVD);
}